// Round 2
// baseline (780.259 us; speedup 1.0000x reference)
//
#include <hip/hip_runtime.h>
#include <hip/hip_bf16.h>

typedef __hip_bfloat16 bf16;
typedef short short8 __attribute__((ext_vector_type(8)));
typedef float f32x4 __attribute__((ext_vector_type(4)));

#define NB 2
#define NC 256
#define NH 120
#define NW 240
#define NHW (NH*NW)      // 28800
#define NSP 16384        // padded spectral pixels per image (128*128)
#define NHID 512
#define NPT 450          // pixel tiles of 64
#define REPS 1e-5f
#define SC_W 0.06454972243679028f   // 1/sqrt(240)
#define SC_H 0.09128709291752769f   // 1/sqrt(120)
#define PI2 6.283185307179586f

__device__ __forceinline__ float gelu_f(float x){ return 0.5f*x*(1.f+erff(x*0.7071067811865476f)); }
__device__ __forceinline__ float us2f(ushort u){ union{float f; uint v;} c; c.v=((uint)u)<<16; return c.f; }
__device__ __forceinline__ ushort f2us(float f){ bf16 b=__float2bfloat16(f); return *(ushort*)&b; }

// ---- workspace float offsets ----
#define OFF_A0   0
#define OFF_D0   512
#define OFF_A1c  1024
#define OFF_D1c  1536
#define OFF_TWF  2048       // bf16[256][256] fwd-W DFT
#define OFF_THF  34816      // bf16[256][256] fwd-H
#define OFF_THI  67584      // bf16[256][256] inv-H
#define OFF_TWI  100352     // bf16[256][256] inv-W real
#define OFF_WRT  133120     // bf16[256][256] w_spec_r^T [o][i]
#define OFF_WIT  165888     // bf16[256][256] w_spec_i^T
#define OFF_IWB  198656     // bf16[256][256] inner_w [o][i]
#define OFF_W2B  231424     // bf16[256][512]  hid-permuted (see k_setup)
#define OFF_W1P  296960     // bf16[2][512][256]  a1-folded mlp_w1
#define OFF_B1P  428032     // f32[2][512]        folded bias1
#define OFF_PS   429056     // f32[2][450][512]   stats partials (sum | sumsq)
#define OFF_RA   889856     // 8388608 floats ping A
#define OFF_RB   9278464    // 8388608 floats ping B
#define WS_FLOATS 17667072ULL   // 70.7 MB

#define RA0 OFF_RA
#define RA1 (OFF_RA+4194304)
#define RB0 OFF_RB
#define RB1 (OFF_RB+4194304)
#define OFF_FRE RB0
#define OFF_FIM (RB0+3932160)

// ---------------- setup: DFT matrices + weight casts ----------------
__global__ __launch_bounds__(256) void k_setup(float* ws, const float* wsr, const float* wsi,
                                               const float* iw, const float* w2){
  int t = blockIdx.x*256 + threadIdx.x;
  if (t < 65536){ // TWF [n][w]
    int n=t>>8, w=t&255; float v=0.f;
    if(w<NW){
      if(n<121){ v = cosf(PI2*(float)((n*w)%NW)/(float)NW)*SC_W; }
      else if(n>=128 && n<249){ int k=n-128; v = -sinf(PI2*(float)((k*w)%NW)/(float)NW)*SC_W; }
    }
    ((ushort*)(ws+OFF_TWF))[t]=f2us(v); return;
  } t-=65536;
  if (t < 65536){ // THF
    int n=t>>8, j=t&255; float v=0.f;
    int h = j&127; bool im = (j>=128);
    if(h<NH){
      if(n<128){ int m=n; if(m<NH){ float sn,cs; sincosf(PI2*(float)((m*h)%NH)/(float)NH,&sn,&cs);
        v = (im? sn : cs)*SC_H; } }
      else { int m=n-128; if(m<NH){ float sn,cs; sincosf(PI2*(float)((m*h)%NH)/(float)NH,&sn,&cs);
        v = (im? cs : -sn)*SC_H; } }
    }
    ((ushort*)(ws+OFF_THF))[t]=f2us(v); return;
  } t-=65536;
  if (t < 65536){ // THI
    int n=t>>8, j=t&255; float v=0.f;
    int m = j&127; bool im = (j>=128);
    if(m<NH){
      if(n<128){ int h=n; if(h<NH){ float sn,cs; sincosf(PI2*(float)((h*m)%NH)/(float)NH,&sn,&cs);
        v = (im? -sn : cs)*SC_H; } }
      else { int h=n-128; if(h<NH){ float sn,cs; sincosf(PI2*(float)((h*m)%NH)/(float)NH,&sn,&cs);
        v = (im? cs : sn)*SC_H; } }
    }
    ((ushort*)(ws+OFF_THI))[t]=f2us(v); return;
  } t-=65536;
  if (t < 65536){ // TWI
    int w=t>>8, j=t&255; float v=0.f;
    if(w<NW){
      int k = j&127; bool im = (j>=128);
      if(k<121){
        float ck = (k==0||k==120)? 1.f : 2.f;
        float sn,cs; sincosf(PI2*(float)((w*k)%NW)/(float)NW,&sn,&cs);
        v = ck*(im? -sn : cs)*SC_W;
      }
    }
    ((ushort*)(ws+OFF_TWI))[t]=f2us(v); return;
  } t-=65536;
  if (t < 65536){ int o=t>>8,i=t&255; ((ushort*)(ws+OFF_WRT))[t]=f2us(wsr[i*NC+o]); return; } t-=65536;
  if (t < 65536){ int o=t>>8,i=t&255; ((ushort*)(ws+OFF_WIT))[t]=f2us(wsi[i*NC+o]); return; } t-=65536;
  if (t < 65536){ ((ushort*)(ws+OFF_IWB))[t]=f2us(iw[t]); return; } t-=65536;
  if (t < 131072){
    // W2 with hid-permuted columns: slot k at (c,lq,j) reads physical hid
    // pi(k) = c*32 + (j>>2)*16 + lq*4 + (j&3). This makes GEMM1's accumulator
    // layout in k_mlp directly usable as GEMM2's B fragment (zero shuffles).
    int o = t>>9, k = t&511;
    int kp = (k & ~31) | ((k&4)<<2) | ((k>>1)&12) | (k&3);
    ((ushort*)(ws+OFF_W2B))[t]=f2us(w2[(o<<9)+kp]);
    return;
  }
}

// ---------------- instance-norm stats on x ----------------
__global__ __launch_bounds__(256) void k_stats0(const float* x, const float* n0w, const float* n0b, float* ws){
  int g = blockIdx.x, c = g & (NC-1);
  const float4* xp = (const float4*)(x + (size_t)g*NHW);
  float s=0.f, q=0.f;
  for(int i=threadIdx.x;i<NHW/4;i+=256){
    float4 v=xp[i];
    s+=v.x+v.y+v.z+v.w;
    q=fmaf(v.x,v.x,fmaf(v.y,v.y,fmaf(v.z,v.z,fmaf(v.w,v.w,q))));
  }
  __shared__ float ls[4], lq[4];
  #pragma unroll
  for(int o=32;o>0;o>>=1){ s+=__shfl_down(s,o,64); q+=__shfl_down(q,o,64); }
  int lane=threadIdx.x&63, wid=threadIdx.x>>6;
  if(!lane){ ls[wid]=s; lq[wid]=q; }
  __syncthreads();
  if(!threadIdx.x){
    s=ls[0]+ls[1]+ls[2]+ls[3]; q=lq[0]+lq[1]+lq[2]+lq[3];
    float m=s*(1.f/NHW), var=q*(1.f/NHW)-m*m;
    float r=rsqrtf(var+REPS);
    float a=r*n0w[c];
    ws[OFF_A0+g]=a; ws[OFF_D0+g]=fmaf(-m,a,n0b[c]);
  }
}

// ---------------- norm+cast: x -> A1 bf16 [g][h][256] ----------------
__global__ __launch_bounds__(256) void k_norm(const float* x, float* ws){
  int h = blockIdx.x, g = blockIdx.y, t = threadIdx.x;
  float a = ws[OFF_A0+g], d = ws[OFF_D0+g];
  ushort v = 0;
  if(t < NW) v = f2us(fmaf(a, x[(size_t)g*NHW + (size_t)h*NW + t], d));
  ((ushort*)(ws+RA0))[(size_t)g*30720 + (size_t)h*256 + t] = v;
}

// ---------------- spectral GEMM ----------------
template<int SPLIT, int EPI>
__global__ __launch_bounds__(256) void k_sgemm(const ushort* Ap0, const ushort* Ap1, const ushort* Bm,
                                               ushort* O0, ushort* O1, ushort* Ub){
  int nb = blockIdx.x*64, mb = blockIdx.y*256;
  int tid = threadIdx.x, w = tid>>6, l = tid&63, lq = l>>4, lr = l&15;
  const ushort* ar0[4]; const ushort* ar1[4]; const ushort* br[4];
  #pragma unroll
  for(int mt=0;mt<4;mt++){
    size_t r = mb + w*64 + mt*16 + lr;
    ar0[mt] = Ap0 + r*(SPLIT?128:256) + lq*8;
    ar1[mt] = SPLIT ? (Ap1 + r*128 + lq*8) : ar0[mt];
  }
  #pragma unroll
  for(int nt=0;nt<4;nt++) br[nt] = Bm + (size_t)(nb + nt*16 + lr)*256 + lq*8;
  f32x4 acc[4][4] = {};
  #pragma unroll
  for(int kk=0;kk<8;kk++){
    int k = kk*32;
    short8 af[4], bfr[4];
    #pragma unroll
    for(int mt=0;mt<4;mt++){
      const ushort* p = SPLIT ? ((k<128 ? ar0[mt] : ar1[mt]) + (k&127)) : (ar0[mt] + k);
      af[mt] = *(const short8*)p;
    }
    #pragma unroll
    for(int nt=0;nt<4;nt++) bfr[nt] = *(const short8*)(br[nt]+k);
    #pragma unroll
    for(int mt=0;mt<4;mt++)
      #pragma unroll
      for(int nt=0;nt<4;nt++)
        acc[mt][nt] = __builtin_amdgcn_mfma_f32_16x16x32_bf16(af[mt], bfr[nt], acc[mt][nt], 0,0,0);
  }
  #pragma unroll
  for(int mt=0;mt<4;mt++){
    #pragma unroll
    for(int r=0;r<4;r++){
      int m = mb + w*64 + mt*16 + lq*4 + r;
      #pragma unroll
      for(int nt=0;nt<4;nt++){
        int n = nb + nt*16 + lr;
        float v = acc[mt][nt][r];
        if (EPI==0){
          if(n<128) O0[(size_t)m*128+n] = f2us(v);
          else      O1[(size_t)m*128+n-128] = f2us(v);
        } else {
          int g = m>>7, h = m&127;
          if(h<NH && n<NW) Ub[(size_t)g*NHW + (size_t)h*NW + n] = f2us(v);
        }
      }
    }
  }
}

// ---------------- 64x64 bf16 transpose within 128-stride planes ----------------
__global__ __launch_bounds__(256) void k_t64(const ushort* src, ushort* dst, int srows, int sgstr){
  __shared__ ushort lt[64][72];
  int g=blockIdx.z, i0=blockIdx.y*64, p0=blockIdx.x*64;
  int t=threadIdx.x, r=t>>2, q=t&3;
  int row = i0 + r;
  uint4 u0=make_uint4(0,0,0,0), u1=u0;
  if(row < srows){
    const ushort* sp = src + (size_t)g*sgstr + (size_t)row*128 + p0 + q*16;
    u0=*(const uint4*)sp; u1=*(const uint4*)(sp+8);
  }
  *(uint4*)&lt[r][q*16]=u0; *(uint4*)&lt[r][q*16+8]=u1;
  __syncthreads();
  int pr=t>>2, q2=t&3;
  union { ushort s[8]; uint4 u; } o0, o1;
  #pragma unroll
  for(int e=0;e<8;e++){ o0.s[e]=lt[q2*16+e][pr]; o1.s[e]=lt[q2*16+8+e][pr]; }
  ushort* dp = dst + (size_t)g*NSP + (size_t)(p0+pr)*128 + i0 + q2*16;
  *(uint4*)dp = o0.u; *(uint4*)(dp+8) = o1.u;
}

// ---------------- pixel transpose: [b][c:256][NSP] -> [b][NSP][c] ----------------
__global__ __launch_bounds__(256) void k_tP(const ushort* src, ushort* dst){
  __shared__ ushort lt[64][72];
  int b=blockIdx.z, i0=blockIdx.y*64, p0=blockIdx.x*64;
  int t=threadIdx.x, r=t>>2, q=t&3;
  const ushort* sp = src + (size_t)(b*NC+i0+r)*NSP + p0 + q*16;
  uint4 u0=*(const uint4*)sp, u1=*(const uint4*)(sp+8);
  *(uint4*)&lt[r][q*16]=u0; *(uint4*)&lt[r][q*16+8]=u1;
  __syncthreads();
  int pr=t>>2, q2=t&3;
  union { ushort s[8]; uint4 u; } o0, o1;
  #pragma unroll
  for(int e=0;e<8;e++){ o0.s[e]=lt[q2*16+e][pr]; o1.s[e]=lt[q2*16+8+e][pr]; }
  ushort* dp = dst + ((size_t)b*NSP + p0 + pr)*NC + i0 + q2*16;
  *(uint4*)dp = o0.u; *(uint4*)(dp+8) = o1.u;
}

// ---------------- complex spectral mix via MFMA ----------------
__global__ __launch_bounds__(256) void k_mixg(float* ws){
  int b = blockIdx.z, p0 = blockIdx.x*32;
  int tid = threadIdx.x, w = tid>>6, l = tid&63, lq = l>>4, lr = l&15;
  const ushort* Wr = (const ushort*)(ws+OFF_WRT);
  const ushort* Wi = (const ushort*)(ws+OFF_WIT);
  const ushort* Gr = (const ushort*)(ws+RA0) + (size_t)b*NSP*NC;
  const ushort* Gi = (const ushort*)(ws+RA1) + (size_t)b*NSP*NC;
  const ushort *wrr[4], *wir[4], *brr[2], *bir[2];
  #pragma unroll
  for(int mt=0;mt<4;mt++){ size_t ro=(size_t)(w*64+mt*16+lr)*NC+lq*8; wrr[mt]=Wr+ro; wir[mt]=Wi+ro; }
  #pragma unroll
  for(int nt=0;nt<2;nt++){ size_t ro=(size_t)(p0+nt*16+lr)*NC+lq*8; brr[nt]=Gr+ro; bir[nt]=Gi+ro; }
  f32x4 aR[4][2]={}, aI[4][2]={};
  for(int k=0;k<256;k+=32){
    short8 fr[4], fi[4], fin[4], gr[2], gi[2];
    #pragma unroll
    for(int mt=0;mt<4;mt++){
      fr[mt]=*(const short8*)(wrr[mt]+k);
      fi[mt]=*(const short8*)(wir[mt]+k);
      union { short8 s; uint u[4]; } nv; nv.s=fi[mt];
      nv.u[0]^=0x80008000u; nv.u[1]^=0x80008000u; nv.u[2]^=0x80008000u; nv.u[3]^=0x80008000u;
      fin[mt]=nv.s;
    }
    #pragma unroll
    for(int nt=0;nt<2;nt++){ gr[nt]=*(const short8*)(brr[nt]+k); gi[nt]=*(const short8*)(bir[nt]+k); }
    #pragma unroll
    for(int mt=0;mt<4;mt++)
      #pragma unroll
      for(int nt=0;nt<2;nt++){
        aR[mt][nt]=__builtin_amdgcn_mfma_f32_16x16x32_bf16(fr[mt], gr[nt], aR[mt][nt],0,0,0);
        aR[mt][nt]=__builtin_amdgcn_mfma_f32_16x16x32_bf16(fin[mt],gi[nt], aR[mt][nt],0,0,0);
        aI[mt][nt]=__builtin_amdgcn_mfma_f32_16x16x32_bf16(fi[mt], gr[nt], aI[mt][nt],0,0,0);
        aI[mt][nt]=__builtin_amdgcn_mfma_f32_16x16x32_bf16(fr[mt], gi[nt], aI[mt][nt],0,0,0);
      }
  }
  ushort* Yre = (ushort*)(ws+RB0);
  ushort* Yim = (ushort*)(ws+RB1);
  #pragma unroll
  for(int mt=0;mt<4;mt++){
    #pragma unroll
    for(int r=0;r<4;r++){
      int m = w*64 + mt*16 + lq*4 + r;
      #pragma unroll
      for(int nt=0;nt<2;nt++){
        int n = p0 + nt*16 + lr;
        size_t ad = (size_t)(b*NC+m)*NSP + n;
        Yre[ad] = f2us(aR[mt][nt][r]);
        Yim[ad] = f2us(aI[mt][nt][r]);
      }
    }
  }
}

// ---------------- Phase A: fused x-transpose + inner conv + gelu + stats + U' ----------------
__global__ __launch_bounds__(256,2) void k_inner(float* ws, const float* x, const float* ib){
  __shared__ ushort xt[64][264];
  int b = blockIdx.z, blk = blockIdx.x, p0 = blk*64;
  int t = threadIdx.x, w = t>>6, l = t&63, lq = l>>4, lr = l&15;
  // load + transpose x tile -> xt[p][c] bf16
  #pragma unroll 4
  for(int cc=0; cc<16; cc++){
    int c = cc*16 + (t>>4);
    int p4 = (t&15)*4;
    float4 v = *(const float4*)(x + ((size_t)(b*NC+c))*NHW + p0 + p4);
    xt[p4  ][c]=f2us(v.x); xt[p4+1][c]=f2us(v.y);
    xt[p4+2][c]=f2us(v.z); xt[p4+3][c]=f2us(v.w);
  }
  __syncthreads();
  const ushort* W = (const ushort*)(ws+OFF_IWB);
  const ushort* ar[4];
  #pragma unroll
  for(int mt=0;mt<4;mt++) ar[mt] = W + (size_t)(w*64+mt*16+lr)*256 + lq*8;
  f32x4 acc[4][4] = {};
  #pragma unroll
  for(int kk=0;kk<8;kk++){
    int k = kk*32;
    short8 af[4], bfr[4];
    #pragma unroll
    for(int mt=0;mt<4;mt++) af[mt] = *(const short8*)(ar[mt]+k);
    #pragma unroll
    for(int nt=0;nt<4;nt++) bfr[nt] = *(const short8*)&xt[nt*16+lr][k+lq*8];
    #pragma unroll
    for(int mt=0;mt<4;mt++)
      #pragma unroll
      for(int nt=0;nt<4;nt++)
        acc[mt][nt] = __builtin_amdgcn_mfma_f32_16x16x32_bf16(af[mt], bfr[nt], acc[mt][nt], 0,0,0);
  }
  __syncthreads();   // all waves done reading xt; reuse as output transpose buffer
  const ushort* Usp = (const ushort*)(ws+OFF_RA);
  float* PS = ws + OFF_PS + ((size_t)(b*NPT+blk))*512;
  #pragma unroll
  for(int mt=0;mt<4;mt++){
    #pragma unroll
    for(int r=0;r<4;r++){
      int m = w*64 + mt*16 + lq*4 + r;
      float bb = ib[m];
      float ss = 0.f, sq = 0.f;
      #pragma unroll
      for(int nt=0;nt<4;nt++){
        int n = p0 + nt*16 + lr;
        float uv = us2f(Usp[((size_t)(b*NC+m))*NHW + n]);
        float g = gelu_f(acc[mt][nt][r] + bb + uv);
        xt[nt*16+lr][m] = f2us(g);
        ss += g; sq = fmaf(g,g,sq);
      }
      #pragma unroll
      for(int ofs=1; ofs<16; ofs<<=1){ ss += __shfl_xor(ss, ofs, 64); sq += __shfl_xor(sq, ofs, 64); }
      if(lr==0){ PS[m] = ss; PS[256+m] = sq; }
    }
  }
  __syncthreads();
  ushort* Up = (ushort*)(ws+OFF_RB);
  #pragma unroll
  for(int pp=0; pp<4; pp++){
    int p = pp*16 + (t>>4);
    int c0 = (t&15)*16;
    uint4 w0 = *(uint4*)&xt[p][c0];
    uint4 w1v = *(uint4*)&xt[p][c0+8];
    ushort* dp = Up + ((size_t)(b*NHW + p0 + p))*256 + c0;
    *(uint4*)dp = w0; *(uint4*)(dp+8) = w1v;
  }
}

// ---------------- stats1: reduce partials -> a1,d1 (FiLM folded) ----------------
__global__ __launch_bounds__(256) void k_stats1p(const float* gamma, const float* beta,
                                                 const float* n1w, const float* n1b, float* ws){
  int g = blockIdx.x, b = g>>8, c = g&255;
  float s=0.f, q=0.f;
  for(int i=threadIdx.x;i<NPT;i+=256){
    const float* P = ws + OFF_PS + ((size_t)(b*NPT+i))*512;
    s += P[c]; q += P[256+c];
  }
  __shared__ float ls[4], lq2[4];
  #pragma unroll
  for(int o=32;o>0;o>>=1){ s+=__shfl_down(s,o,64); q+=__shfl_down(q,o,64); }
  int lane=threadIdx.x&63, wid=threadIdx.x>>6;
  if(!lane){ ls[wid]=s; lq2[wid]=q; }
  __syncthreads();
  if(!threadIdx.x){
    s=ls[0]+ls[1]+ls[2]+ls[3]; q=lq2[0]+lq2[1]+lq2[2]+lq2[3];
    float m=s*(1.f/NHW), var=q*(1.f/NHW)-m*m;
    float r=rsqrtf(var+REPS);
    float gp1 = 1.f + gamma[c];
    float wv = n1w[c];
    ws[OFF_A1c+g] = gp1*wv*r;
    ws[OFF_D1c+g] = gp1*(n1b[c] - m*r*wv) + beta[c];
  }
}

// ---------------- fold a1/d1 into W1: W1'[b]=W1*diag(a1), b1'=W1*d1+b1 ----------------
__global__ __launch_bounds__(64) void k_fold(float* ws, const float* w1, const float* b1){
  int o = blockIdx.x, b = blockIdx.y, t = threadIdx.x;
  float acc = 0.f;
  ushort* W1p = (ushort*)(ws+OFF_W1P);
  #pragma unroll
  for(int ii=0; ii<4; ii++){
    int i = ii*64 + t;
    float wv = w1[o*256+i];
    W1p[((size_t)(b*NHID+o))*256 + i] = f2us(wv * ws[OFF_A1c + b*NC + i]);
    acc = fmaf(wv, ws[OFF_D1c + b*NC + i], acc);
  }
  #pragma unroll
  for(int ofs=32; ofs; ofs>>=1) acc += __shfl_down(acc, ofs, 64);
  if(!t) ws[OFF_B1P + b*NHID + o] = acc + b1[o];
}

// ---------------- Phase C: fused mlp1+gelu+mlp2+residual (wave-private, LDS-free) ----------------
// Each wave owns 16 pixels; hid processed in 16 chunks of 32.
// GEMM1 acc (mid) layout: lane(lq,lr) holds hid-position = c*32 + tile*16 + lq*4 + r, pixel = lr.
// GEMM2 B-frag needs:     lane(lq,lr) holds k-slot      = c*32 + lq*8 + j,            pixel = lr.
// hid is a pure contraction axis, so we permute W2's columns at setup time with
//   pi(c*32 + lq*8 + j) = c*32 + (j>>2)*16 + lq*4 + (j&3)
// which makes the needed B fragment EXACTLY this lane's own packed GEMM1 outputs:
//   u[0]=pack(r0,r1 of tile0), u[1]=pack(r2,r3 of tile0), u[2]=tile1 r0,r1, u[3]=tile1 r2,r3.
// Zero LDS, zero barriers, zero cross-lane ops between the two GEMMs.
__global__ __launch_bounds__(256,4) void k_mlp(float* ws, const float* x, const float* b2, float* out){
  int b = blockIdx.z, p0 = blockIdx.x*64;
  int t = threadIdx.x, w = t>>6, l = t&63, lq = l>>4, lr = l&15;
  int pw = p0 + w*16 + lr;   // this lane's pixel (the MFMA "n" column)
  const ushort* W1p = (const ushort*)(ws+OFF_W1P) + (size_t)b*NHID*256;
  const ushort* Up  = (const ushort*)(ws+OFF_RB);
  const float*  b1p = ws + OFF_B1P + b*NHID;
  const ushort* up  = Up + ((size_t)(b*NHW) + pw)*256 + lq*8;          // B-frag rows for GEMM1
  const ushort* w2r = (const ushort*)(ws+OFF_W2B) + (size_t)lr*512 + lq*8;  // A-frag rows for GEMM2
  f32x4 acc2[16] = {};
  for(int c=0;c<16;c++){
    // ---- GEMM1 chunk: mid[c*32 .. c*32+31][16 px], K = 256 input channels ----
    const ushort* w1r = W1p + (size_t)(c*32 + lr)*256 + lq*8;
    f32x4 a1[2] = {};
    #pragma unroll
    for(int kk=0;kk<8;kk++){
      short8 bu  = *(const short8*)(up  + kk*32);
      short8 a0  = *(const short8*)(w1r + kk*32);
      short8 a1f = *(const short8*)(w1r + 16*256 + kk*32);
      a1[0] = __builtin_amdgcn_mfma_f32_16x16x32_bf16(a0,  bu, a1[0], 0,0,0);
      a1[1] = __builtin_amdgcn_mfma_f32_16x16x32_bf16(a1f, bu, a1[1], 0,0,0);
    }
    // ---- bias + gelu + pack to bf16 pairs: this IS the GEMM2 B fragment ----
    float4 bb0 = *(const float4*)(b1p + c*32      + lq*4);
    float4 bb1 = *(const float4*)(b1p + c*32 + 16 + lq*4);
    union { short8 s8; uint u[4]; } bf;
    bf.u[0] = (uint)f2us(gelu_f(a1[0][0]+bb0.x)) | ((uint)f2us(gelu_f(a1[0][1]+bb0.y))<<16);
    bf.u[1] = (uint)f2us(gelu_f(a1[0][2]+bb0.z)) | ((uint)f2us(gelu_f(a1[0][3]+bb0.w))<<16);
    bf.u[2] = (uint)f2us(gelu_f(a1[1][0]+bb1.x)) | ((uint)f2us(gelu_f(a1[1][1]+bb1.y))<<16);
    bf.u[3] = (uint)f2us(gelu_f(a1[1][2]+bb1.z)) | ((uint)f2us(gelu_f(a1[1][3]+bb1.w))<<16);
    // ---- GEMM2 partial: all 256 out channels x this 32-k block (W2 cols pre-permuted) ----
    #pragma unroll
    for(int mt=0;mt<16;mt++){
      short8 a2 = *(const short8*)(w2r + (size_t)mt*16*512 + c*32);
      acc2[mt] = __builtin_amdgcn_mfma_f32_16x16x32_bf16(a2, bf.s8, acc2[mt], 0,0,0);
    }
  }
  // ---- epilogue: + b2 + residual ----
  #pragma unroll
  for(int mt=0;mt<16;mt++){
    float4 bb = *(const float4*)(b2 + mt*16 + lq*4);
    float bbv[4] = {bb.x, bb.y, bb.z, bb.w};
    #pragma unroll
    for(int r=0;r<4;r++){
      int om = mt*16 + lq*4 + r;
      size_t ad = ((size_t)(b*NC+om))*NHW + pw;
      out[ad] = acc2[mt][r] + bbv[r] + x[ad];
    }
  }
}

extern "C" void kernel_launch(void* const* d_in, const int* in_sizes, int n_in,
                              void* d_out, int out_size, void* d_ws, size_t ws_size,
                              hipStream_t stream) {
  const float* x     = (const float*)d_in[0];
  const float* gamma = (const float*)d_in[1];
  const float* beta  = (const float*)d_in[2];
  const float* n0w   = (const float*)d_in[3];
  const float* n0b   = (const float*)d_in[4];
  const float* n1w   = (const float*)d_in[5];
  const float* n1b   = (const float*)d_in[6];
  const float* wsr   = (const float*)d_in[7];
  const float* wsi   = (const float*)d_in[8];
  const float* iw    = (const float*)d_in[9];
  const float* ib    = (const float*)d_in[10];
  const float* w1    = (const float*)d_in[11];
  const float* b1    = (const float*)d_in[12];
  const float* w2    = (const float*)d_in[13];
  const float* b2    = (const float*)d_in[14];
  float* ws = (float*)d_ws;
  float* out = (float*)d_out;
  if (ws_size < WS_FLOATS*4ULL) return;

  k_setup <<<dim3(2304), dim3(256), 0, stream>>>(ws, wsr, wsi, iw, w2);
  k_stats0<<<dim3(512),  dim3(256), 0, stream>>>(x, n0w, n0b, ws);
  k_norm  <<<dim3(120,512), dim3(256), 0, stream>>>(x, ws);
  // GEMM1: A1(RA) -> F(RB planes)
  k_sgemm<0,0><<<dim3(4,240), dim3(256), 0, stream>>>((const ushort*)(ws+RA0), (const ushort*)(ws+RA0),
      (const ushort*)(ws+OFF_TWF), (ushort*)(ws+OFF_FRE), (ushort*)(ws+OFF_FIM), nullptr);
  // T1: F(RB) -> Ft(RA)
  k_t64 <<<dim3(2,2,512), dim3(256), 0, stream>>>((const ushort*)(ws+OFF_FRE), (ushort*)(ws+RA0), NH, NH*128);
  k_t64 <<<dim3(2,2,512), dim3(256), 0, stream>>>((const ushort*)(ws+OFF_FIM), (ushort*)(ws+RA1), NH, NH*128);
  // GEMM2: Ft(RA) -> G(RB)
  k_sgemm<1,0><<<dim3(4,256), dim3(256), 0, stream>>>((const ushort*)(ws+RA0), (const ushort*)(ws+RA1),
      (const ushort*)(ws+OFF_THF), (ushort*)(ws+RB0), (ushort*)(ws+RB1), nullptr);
  // T2: G(RB) -> Gt(RA) [b][p][c]
  k_tP <<<dim3(256,4,2), dim3(256), 0, stream>>>((const ushort*)(ws+RB0), (ushort*)(ws+RA0));
  k_tP <<<dim3(256,4,2), dim3(256), 0, stream>>>((const ushort*)(ws+RB1), (ushort*)(ws+RA1));
  // mix: Gt(RA) -> Y(RB)
  k_mixg <<<dim3(512,1,2), dim3(256), 0, stream>>>(ws);
  // GEMM4: Y(RB) -> Z(RA)
  k_sgemm<1,0><<<dim3(4,256), dim3(256), 0, stream>>>((const ushort*)(ws+RB0), (const ushort*)(ws+RB1),
      (const ushort*)(ws+OFF_THI), (ushort*)(ws+RA0), (ushort*)(ws+RA1), nullptr);
  // T3: Z(RA) -> Zt(RB)
  k_t64 <<<dim3(2,2,512), dim3(256), 0, stream>>>((const ushort*)(ws+RA0), (ushort*)(ws+RB0), 128, NSP);
  k_t64 <<<dim3(2,2,512), dim3(256), 0, stream>>>((const ushort*)(ws+RA1), (ushort*)(ws+RB1), 128, NSP);
  // GEMM5: Zt(RB) -> U spectral bf16 channel-major (RA)
  k_sgemm<1,1><<<dim3(4,256), dim3(256), 0, stream>>>((const ushort*)(ws+RB0), (const ushort*)(ws+RB1),
      (const ushort*)(ws+OFF_TWI), nullptr, nullptr, (ushort*)(ws+RA0));
  // Phase A: inner conv fused (x + Usp -> U' pixel-major bf16 in RB, + stats partials)
  k_inner <<<dim3(NPT,1,2), dim3(256), 0, stream>>>(ws, x, ib);
  k_stats1p<<<dim3(512), dim3(256), 0, stream>>>(gamma, beta, n1w, n1b, ws);
  k_fold  <<<dim3(512,2), dim3(64), 0, stream>>>(ws, w1, b1);
  // Phase C: fused MLP (wave-private, LDS-free, permuted-W2 in-register mid handoff)
  k_mlp   <<<dim3(NPT,1,2), dim3(256), 0, stream>>>(ws, x, b2, out);
}

// Round 3
// 678.583 us; speedup vs baseline: 1.1498x; 1.1498x over previous
//
#include <hip/hip_runtime.h>
#include <hip/hip_bf16.h>

typedef __hip_bfloat16 bf16;
typedef short short8 __attribute__((ext_vector_type(8)));
typedef float f32x4 __attribute__((ext_vector_type(4)));

#define NB 2
#define NC 256
#define NH 120
#define NW 240
#define NHW (NH*NW)      // 28800
#define NSP 16384        // padded spectral pixels per image (128*128)
#define NHID 512
#define NPT 450          // pixel tiles of 64
#define REPS 1e-5f
#define SC_W 0.06454972243679028f   // 1/sqrt(240)
#define SC_H 0.09128709291752769f   // 1/sqrt(120)
#define PI2 6.283185307179586f

__device__ __forceinline__ float gelu_f(float x){ return 0.5f*x*(1.f+erff(x*0.7071067811865476f)); }
__device__ __forceinline__ float us2f(ushort u){ union{float f; uint v;} c; c.v=((uint)u)<<16; return c.f; }
__device__ __forceinline__ ushort f2us(float f){ bf16 b=__float2bfloat16(f); return *(ushort*)&b; }

// ---- workspace float offsets ----
#define OFF_A0   0
#define OFF_D0   512
#define OFF_A1c  1024
#define OFF_D1c  1536
#define OFF_TWF  2048       // bf16[256][256] fwd-W DFT
#define OFF_THF  34816      // bf16[256][256] fwd-H
#define OFF_THI  67584      // bf16[256][256] inv-H
#define OFF_TWI  100352     // bf16[256][256] inv-W real
#define OFF_WRT  133120     // bf16[256][256] w_spec_r^T [o][i]
#define OFF_WIT  165888     // bf16[256][256] w_spec_i^T
#define OFF_IWB  198656     // bf16[256][256] inner_w [o][i]
#define OFF_W2B  231424     // bf16[256][512]  natural layout
#define OFF_W1P  296960     // bf16[2][512][256]  a1-folded mlp_w1
#define OFF_B1P  428032     // f32[2][512]        folded bias1
#define OFF_PS   429056     // f32[2][450][512]   stats partials (sum | sumsq)
#define OFF_RA   889856     // 8388608 floats ping A
#define OFF_RB   9278464    // 8388608 floats ping B
#define WS_FLOATS 17667072ULL   // 70.7 MB

#define RA0 OFF_RA
#define RA1 (OFF_RA+4194304)
#define RB0 OFF_RB
#define RB1 (OFF_RB+4194304)
#define OFF_FRE RB0
#define OFF_FIM (RB0+3932160)

// ---------------- setup: DFT matrices + weight casts ----------------
__global__ __launch_bounds__(256) void k_setup(float* ws, const float* wsr, const float* wsi,
                                               const float* iw, const float* w2){
  int t = blockIdx.x*256 + threadIdx.x;
  if (t < 65536){ // TWF [n][w]
    int n=t>>8, w=t&255; float v=0.f;
    if(w<NW){
      if(n<121){ v = cosf(PI2*(float)((n*w)%NW)/(float)NW)*SC_W; }
      else if(n>=128 && n<249){ int k=n-128; v = -sinf(PI2*(float)((k*w)%NW)/(float)NW)*SC_W; }
    }
    ((ushort*)(ws+OFF_TWF))[t]=f2us(v); return;
  } t-=65536;
  if (t < 65536){ // THF
    int n=t>>8, j=t&255; float v=0.f;
    int h = j&127; bool im = (j>=128);
    if(h<NH){
      if(n<128){ int m=n; if(m<NH){ float sn,cs; sincosf(PI2*(float)((m*h)%NH)/(float)NH,&sn,&cs);
        v = (im? sn : cs)*SC_H; } }
      else { int m=n-128; if(m<NH){ float sn,cs; sincosf(PI2*(float)((m*h)%NH)/(float)NH,&sn,&cs);
        v = (im? cs : -sn)*SC_H; } }
    }
    ((ushort*)(ws+OFF_THF))[t]=f2us(v); return;
  } t-=65536;
  if (t < 65536){ // THI
    int n=t>>8, j=t&255; float v=0.f;
    int m = j&127; bool im = (j>=128);
    if(m<NH){
      if(n<128){ int h=n; if(h<NH){ float sn,cs; sincosf(PI2*(float)((h*m)%NH)/(float)NH,&sn,&cs);
        v = (im? -sn : cs)*SC_H; } }
      else { int h=n-128; if(h<NH){ float sn,cs; sincosf(PI2*(float)((h*m)%NH)/(float)NH,&sn,&cs);
        v = (im? cs : sn)*SC_H; } }
    }
    ((ushort*)(ws+OFF_THI))[t]=f2us(v); return;
  } t-=65536;
  if (t < 65536){ // TWI
    int w=t>>8, j=t&255; float v=0.f;
    if(w<NW){
      int k = j&127; bool im = (j>=128);
      if(k<121){
        float ck = (k==0||k==120)? 1.f : 2.f;
        float sn,cs; sincosf(PI2*(float)((w*k)%NW)/(float)NW,&sn,&cs);
        v = ck*(im? -sn : cs)*SC_W;
      }
    }
    ((ushort*)(ws+OFF_TWI))[t]=f2us(v); return;
  } t-=65536;
  if (t < 65536){ int o=t>>8,i=t&255; ((ushort*)(ws+OFF_WRT))[t]=f2us(wsr[i*NC+o]); return; } t-=65536;
  if (t < 65536){ int o=t>>8,i=t&255; ((ushort*)(ws+OFF_WIT))[t]=f2us(wsi[i*NC+o]); return; } t-=65536;
  if (t < 65536){ ((ushort*)(ws+OFF_IWB))[t]=f2us(iw[t]); return; } t-=65536;
  if (t < 131072){ ((ushort*)(ws+OFF_W2B))[t]=f2us(w2[t]); return; }
}

// ---------------- instance-norm stats on x ----------------
__global__ __launch_bounds__(256) void k_stats0(const float* x, const float* n0w, const float* n0b, float* ws){
  int g = blockIdx.x, c = g & (NC-1);
  const float4* xp = (const float4*)(x + (size_t)g*NHW);
  float s=0.f, q=0.f;
  for(int i=threadIdx.x;i<NHW/4;i+=256){
    float4 v=xp[i];
    s+=v.x+v.y+v.z+v.w;
    q=fmaf(v.x,v.x,fmaf(v.y,v.y,fmaf(v.z,v.z,fmaf(v.w,v.w,q))));
  }
  __shared__ float ls[4], lq[4];
  #pragma unroll
  for(int o=32;o>0;o>>=1){ s+=__shfl_down(s,o,64); q+=__shfl_down(q,o,64); }
  int lane=threadIdx.x&63, wid=threadIdx.x>>6;
  if(!lane){ ls[wid]=s; lq[wid]=q; }
  __syncthreads();
  if(!threadIdx.x){
    s=ls[0]+ls[1]+ls[2]+ls[3]; q=lq[0]+lq[1]+lq[2]+lq[3];
    float m=s*(1.f/NHW), var=q*(1.f/NHW)-m*m;
    float r=rsqrtf(var+REPS);
    float a=r*n0w[c];
    ws[OFF_A0+g]=a; ws[OFF_D0+g]=fmaf(-m,a,n0b[c]);
  }
}

// ---------------- norm+cast: x -> A1 bf16 [g][h][256] ----------------
__global__ __launch_bounds__(256) void k_norm(const float* x, float* ws){
  int h = blockIdx.x, g = blockIdx.y, t = threadIdx.x;
  float a = ws[OFF_A0+g], d = ws[OFF_D0+g];
  ushort v = 0;
  if(t < NW) v = f2us(fmaf(a, x[(size_t)g*NHW + (size_t)h*NW + t], d));
  ((ushort*)(ws+RA0))[(size_t)g*30720 + (size_t)h*256 + t] = v;
}

// ---------------- spectral GEMM ----------------
template<int SPLIT, int EPI>
__global__ __launch_bounds__(256) void k_sgemm(const ushort* Ap0, const ushort* Ap1, const ushort* Bm,
                                               ushort* O0, ushort* O1, ushort* Ub){
  int nb = blockIdx.x*64, mb = blockIdx.y*256;
  int tid = threadIdx.x, w = tid>>6, l = tid&63, lq = l>>4, lr = l&15;
  const ushort* ar0[4]; const ushort* ar1[4]; const ushort* br[4];
  #pragma unroll
  for(int mt=0;mt<4;mt++){
    size_t r = mb + w*64 + mt*16 + lr;
    ar0[mt] = Ap0 + r*(SPLIT?128:256) + lq*8;
    ar1[mt] = SPLIT ? (Ap1 + r*128 + lq*8) : ar0[mt];
  }
  #pragma unroll
  for(int nt=0;nt<4;nt++) br[nt] = Bm + (size_t)(nb + nt*16 + lr)*256 + lq*8;
  f32x4 acc[4][4] = {};
  #pragma unroll
  for(int kk=0;kk<8;kk++){
    int k = kk*32;
    short8 af[4], bfr[4];
    #pragma unroll
    for(int mt=0;mt<4;mt++){
      const ushort* p = SPLIT ? ((k<128 ? ar0[mt] : ar1[mt]) + (k&127)) : (ar0[mt] + k);
      af[mt] = *(const short8*)p;
    }
    #pragma unroll
    for(int nt=0;nt<4;nt++) bfr[nt] = *(const short8*)(br[nt]+k);
    #pragma unroll
    for(int mt=0;mt<4;mt++)
      #pragma unroll
      for(int nt=0;nt<4;nt++)
        acc[mt][nt] = __builtin_amdgcn_mfma_f32_16x16x32_bf16(af[mt], bfr[nt], acc[mt][nt], 0,0,0);
  }
  #pragma unroll
  for(int mt=0;mt<4;mt++){
    #pragma unroll
    for(int r=0;r<4;r++){
      int m = mb + w*64 + mt*16 + lq*4 + r;
      #pragma unroll
      for(int nt=0;nt<4;nt++){
        int n = nb + nt*16 + lr;
        float v = acc[mt][nt][r];
        if (EPI==0){
          if(n<128) O0[(size_t)m*128+n] = f2us(v);
          else      O1[(size_t)m*128+n-128] = f2us(v);
        } else {
          int g = m>>7, h = m&127;
          if(h<NH && n<NW) Ub[(size_t)g*NHW + (size_t)h*NW + n] = f2us(v);
        }
      }
    }
  }
}

// ---------------- 64x64 bf16 transpose within 128-stride planes ----------------
__global__ __launch_bounds__(256) void k_t64(const ushort* src, ushort* dst, int srows, int sgstr){
  __shared__ ushort lt[64][72];
  int g=blockIdx.z, i0=blockIdx.y*64, p0=blockIdx.x*64;
  int t=threadIdx.x, r=t>>2, q=t&3;
  int row = i0 + r;
  uint4 u0=make_uint4(0,0,0,0), u1=u0;
  if(row < srows){
    const ushort* sp = src + (size_t)g*sgstr + (size_t)row*128 + p0 + q*16;
    u0=*(const uint4*)sp; u1=*(const uint4*)(sp+8);
  }
  *(uint4*)&lt[r][q*16]=u0; *(uint4*)&lt[r][q*16+8]=u1;
  __syncthreads();
  int pr=t>>2, q2=t&3;
  union { ushort s[8]; uint4 u; } o0, o1;
  #pragma unroll
  for(int e=0;e<8;e++){ o0.s[e]=lt[q2*16+e][pr]; o1.s[e]=lt[q2*16+8+e][pr]; }
  ushort* dp = dst + (size_t)g*NSP + (size_t)(p0+pr)*128 + i0 + q2*16;
  *(uint4*)dp = o0.u; *(uint4*)(dp+8) = o1.u;
}

// ---------------- pixel transpose: [b][c:256][NSP] -> [b][NSP][c] ----------------
__global__ __launch_bounds__(256) void k_tP(const ushort* src, ushort* dst){
  __shared__ ushort lt[64][72];
  int b=blockIdx.z, i0=blockIdx.y*64, p0=blockIdx.x*64;
  int t=threadIdx.x, r=t>>2, q=t&3;
  const ushort* sp = src + (size_t)(b*NC+i0+r)*NSP + p0 + q*16;
  uint4 u0=*(const uint4*)sp, u1=*(const uint4*)(sp+8);
  *(uint4*)&lt[r][q*16]=u0; *(uint4*)&lt[r][q*16+8]=u1;
  __syncthreads();
  int pr=t>>2, q2=t&3;
  union { ushort s[8]; uint4 u; } o0, o1;
  #pragma unroll
  for(int e=0;e<8;e++){ o0.s[e]=lt[q2*16+e][pr]; o1.s[e]=lt[q2*16+8+e][pr]; }
  ushort* dp = dst + ((size_t)b*NSP + p0 + pr)*NC + i0 + q2*16;
  *(uint4*)dp = o0.u; *(uint4*)(dp+8) = o1.u;
}

// ---------------- complex spectral mix via MFMA ----------------
__global__ __launch_bounds__(256) void k_mixg(float* ws){
  int b = blockIdx.z, p0 = blockIdx.x*32;
  int tid = threadIdx.x, w = tid>>6, l = tid&63, lq = l>>4, lr = l&15;
  const ushort* Wr = (const ushort*)(ws+OFF_WRT);
  const ushort* Wi = (const ushort*)(ws+OFF_WIT);
  const ushort* Gr = (const ushort*)(ws+RA0) + (size_t)b*NSP*NC;
  const ushort* Gi = (const ushort*)(ws+RA1) + (size_t)b*NSP*NC;
  const ushort *wrr[4], *wir[4], *brr[2], *bir[2];
  #pragma unroll
  for(int mt=0;mt<4;mt++){ size_t ro=(size_t)(w*64+mt*16+lr)*NC+lq*8; wrr[mt]=Wr+ro; wir[mt]=Wi+ro; }
  #pragma unroll
  for(int nt=0;nt<2;nt++){ size_t ro=(size_t)(p0+nt*16+lr)*NC+lq*8; brr[nt]=Gr+ro; bir[nt]=Gi+ro; }
  f32x4 aR[4][2]={}, aI[4][2]={};
  for(int k=0;k<256;k+=32){
    short8 fr[4], fi[4], fin[4], gr[2], gi[2];
    #pragma unroll
    for(int mt=0;mt<4;mt++){
      fr[mt]=*(const short8*)(wrr[mt]+k);
      fi[mt]=*(const short8*)(wir[mt]+k);
      union { short8 s; uint u[4]; } nv; nv.s=fi[mt];
      nv.u[0]^=0x80008000u; nv.u[1]^=0x80008000u; nv.u[2]^=0x80008000u; nv.u[3]^=0x80008000u;
      fin[mt]=nv.s;
    }
    #pragma unroll
    for(int nt=0;nt<2;nt++){ gr[nt]=*(const short8*)(brr[nt]+k); gi[nt]=*(const short8*)(bir[nt]+k); }
    #pragma unroll
    for(int mt=0;mt<4;mt++)
      #pragma unroll
      for(int nt=0;nt<2;nt++){
        aR[mt][nt]=__builtin_amdgcn_mfma_f32_16x16x32_bf16(fr[mt], gr[nt], aR[mt][nt],0,0,0);
        aR[mt][nt]=__builtin_amdgcn_mfma_f32_16x16x32_bf16(fin[mt],gi[nt], aR[mt][nt],0,0,0);
        aI[mt][nt]=__builtin_amdgcn_mfma_f32_16x16x32_bf16(fi[mt], gr[nt], aI[mt][nt],0,0,0);
        aI[mt][nt]=__builtin_amdgcn_mfma_f32_16x16x32_bf16(fr[mt], gi[nt], aI[mt][nt],0,0,0);
      }
  }
  ushort* Yre = (ushort*)(ws+RB0);
  ushort* Yim = (ushort*)(ws+RB1);
  #pragma unroll
  for(int mt=0;mt<4;mt++){
    #pragma unroll
    for(int r=0;r<4;r++){
      int m = w*64 + mt*16 + lq*4 + r;
      #pragma unroll
      for(int nt=0;nt<2;nt++){
        int n = p0 + nt*16 + lr;
        size_t ad = (size_t)(b*NC+m)*NSP + n;
        Yre[ad] = f2us(aR[mt][nt][r]);
        Yim[ad] = f2us(aI[mt][nt][r]);
      }
    }
  }
}

// ---------------- Phase A: fused x-transpose + inner conv + gelu + stats + U' ----------------
__global__ __launch_bounds__(256,2) void k_inner(float* ws, const float* x, const float* ib){
  __shared__ ushort xt[64][264];
  int b = blockIdx.z, blk = blockIdx.x, p0 = blk*64;
  int t = threadIdx.x, w = t>>6, l = t&63, lq = l>>4, lr = l&15;
  // load + transpose x tile -> xt[p][c] bf16
  #pragma unroll 4
  for(int cc=0; cc<16; cc++){
    int c = cc*16 + (t>>4);
    int p4 = (t&15)*4;
    float4 v = *(const float4*)(x + ((size_t)(b*NC+c))*NHW + p0 + p4);
    xt[p4  ][c]=f2us(v.x); xt[p4+1][c]=f2us(v.y);
    xt[p4+2][c]=f2us(v.z); xt[p4+3][c]=f2us(v.w);
  }
  __syncthreads();
  const ushort* W = (const ushort*)(ws+OFF_IWB);
  const ushort* ar[4];
  #pragma unroll
  for(int mt=0;mt<4;mt++) ar[mt] = W + (size_t)(w*64+mt*16+lr)*256 + lq*8;
  f32x4 acc[4][4] = {};
  #pragma unroll
  for(int kk=0;kk<8;kk++){
    int k = kk*32;
    short8 af[4], bfr[4];
    #pragma unroll
    for(int mt=0;mt<4;mt++) af[mt] = *(const short8*)(ar[mt]+k);
    #pragma unroll
    for(int nt=0;nt<4;nt++) bfr[nt] = *(const short8*)&xt[nt*16+lr][k+lq*8];
    #pragma unroll
    for(int mt=0;mt<4;mt++)
      #pragma unroll
      for(int nt=0;nt<4;nt++)
        acc[mt][nt] = __builtin_amdgcn_mfma_f32_16x16x32_bf16(af[mt], bfr[nt], acc[mt][nt], 0,0,0);
  }
  __syncthreads();   // all waves done reading xt; reuse as output transpose buffer
  const ushort* Usp = (const ushort*)(ws+OFF_RA);
  float* PS = ws + OFF_PS + ((size_t)(b*NPT+blk))*512;
  #pragma unroll
  for(int mt=0;mt<4;mt++){
    #pragma unroll
    for(int r=0;r<4;r++){
      int m = w*64 + mt*16 + lq*4 + r;
      float bb = ib[m];
      float ss = 0.f, sq = 0.f;
      #pragma unroll
      for(int nt=0;nt<4;nt++){
        int n = p0 + nt*16 + lr;
        float uv = us2f(Usp[((size_t)(b*NC+m))*NHW + n]);
        float g = gelu_f(acc[mt][nt][r] + bb + uv);
        xt[nt*16+lr][m] = f2us(g);
        ss += g; sq = fmaf(g,g,sq);
      }
      #pragma unroll
      for(int ofs=1; ofs<16; ofs<<=1){ ss += __shfl_xor(ss, ofs, 64); sq += __shfl_xor(sq, ofs, 64); }
      if(lr==0){ PS[m] = ss; PS[256+m] = sq; }
    }
  }
  __syncthreads();
  ushort* Up = (ushort*)(ws+OFF_RB);
  #pragma unroll
  for(int pp=0; pp<4; pp++){
    int p = pp*16 + (t>>4);
    int c0 = (t&15)*16;
    uint4 w0 = *(uint4*)&xt[p][c0];
    uint4 w1v = *(uint4*)&xt[p][c0+8];
    ushort* dp = Up + ((size_t)(b*NHW + p0 + p))*256 + c0;
    *(uint4*)dp = w0; *(uint4*)(dp+8) = w1v;
  }
}

// ---------------- stats1: reduce partials -> a1,d1 (FiLM folded) ----------------
__global__ __launch_bounds__(256) void k_stats1p(const float* gamma, const float* beta,
                                                 const float* n1w, const float* n1b, float* ws){
  int g = blockIdx.x, b = g>>8, c = g&255;
  float s=0.f, q=0.f;
  for(int i=threadIdx.x;i<NPT;i+=256){
    const float* P = ws + OFF_PS + ((size_t)(b*NPT+i))*512;
    s += P[c]; q += P[256+c];
  }
  __shared__ float ls[4], lq2[4];
  #pragma unroll
  for(int o=32;o>0;o>>=1){ s+=__shfl_down(s,o,64); q+=__shfl_down(q,o,64); }
  int lane=threadIdx.x&63, wid=threadIdx.x>>6;
  if(!lane){ ls[wid]=s; lq2[wid]=q; }
  __syncthreads();
  if(!threadIdx.x){
    s=ls[0]+ls[1]+ls[2]+ls[3]; q=lq2[0]+lq2[1]+lq2[2]+lq2[3];
    float m=s*(1.f/NHW), var=q*(1.f/NHW)-m*m;
    float r=rsqrtf(var+REPS);
    float gp1 = 1.f + gamma[c];
    float wv = n1w[c];
    ws[OFF_A1c+g] = gp1*wv*r;
    ws[OFF_D1c+g] = gp1*(n1b[c] - m*r*wv) + beta[c];
  }
}

// ---------------- fold a1/d1 into W1: W1'[b]=W1*diag(a1), b1'=W1*d1+b1 ----------------
__global__ __launch_bounds__(64) void k_fold(float* ws, const float* w1, const float* b1){
  int o = blockIdx.x, b = blockIdx.y, t = threadIdx.x;
  float acc = 0.f;
  ushort* W1p = (ushort*)(ws+OFF_W1P);
  #pragma unroll
  for(int ii=0; ii<4; ii++){
    int i = ii*64 + t;
    float wv = w1[o*256+i];
    W1p[((size_t)(b*NHID+o))*256 + i] = f2us(wv * ws[OFF_A1c + b*NC + i]);
    acc = fmaf(wv, ws[OFF_D1c + b*NC + i], acc);
  }
  #pragma unroll
  for(int ofs=32; ofs; ofs>>=1) acc += __shfl_down(acc, ofs, 64);
  if(!t) ws[OFF_B1P + b*NHID + o] = acc + b1[o];
}

// ---------------- Phase C: fused mlp1+gelu+mlp2+residual (32-px blocks, 32KB LDS) ----------------
// Cooperative round-0 structure (weights 1x per block) with the occupancy fix:
//  - block = 32 pixels -> midT = 32px x 512hid bf16 = 32KB -> 4 blocks/CU.
//  - GEMM1: wave w computes hid rows [w*128, w*128+128) x 32 px  (acc1[8][2]).
//  - mid handoff through LDS with 16B-block XOR swizzle: hid-block j (8 elems)
//    of pixel px stored at block (j ^ (px&7)) -> ds_write_b64 / ds_read_b128
//    both spread across banks (2-way max). Bijective within each px row.
//  - GEMM2: wave w computes out rows [w*64, w*64+64) x 32 px (acc2[4][2], W2 natural).
__global__ __launch_bounds__(256,4) void k_mlp(float* ws, const float* x, const float* b2, float* out){
  __shared__ ushort midT[32*512];   // 32 KB
  int b = blockIdx.z, p0 = blockIdx.x*32;
  int t = threadIdx.x, w = t>>6, l = t&63, lq = l>>4, lr = l&15;
  int h7 = lr & 7;
  const ushort* W1p = (const ushort*)(ws+OFF_W1P) + (size_t)b*NHID*256;
  const ushort* Up  = (const ushort*)(ws+OFF_RB);
  const float*  b1p = ws + OFF_B1P + b*NHID;
  // ---- GEMM1: mid[w*128 .. +128) x 32 px over K=256 ----
  const ushort* ar[8]; const ushort* br[2];
  #pragma unroll
  for(int mt=0;mt<8;mt++) ar[mt] = W1p + (size_t)(w*128+mt*16+lr)*256 + lq*8;
  #pragma unroll
  for(int nt=0;nt<2;nt++) br[nt] = Up + ((size_t)(b*NHW + p0 + nt*16+lr))*256 + lq*8;
  f32x4 acc1[8][2] = {};
  #pragma unroll
  for(int kk=0;kk<8;kk++){
    int k = kk*32;
    short8 bfr[2];
    #pragma unroll
    for(int nt=0;nt<2;nt++) bfr[nt] = *(const short8*)(br[nt]+k);
    #pragma unroll
    for(int mt=0;mt<8;mt++){
      short8 af = *(const short8*)(ar[mt]+k);
      #pragma unroll
      for(int nt=0;nt<2;nt++)
        acc1[mt][nt] = __builtin_amdgcn_mfma_f32_16x16x32_bf16(af, bfr[nt], acc1[mt][nt], 0,0,0);
    }
  }
  // ---- bias + gelu -> swizzled LDS (ds_write_b64: 4 hid vals per write) ----
  #pragma unroll
  for(int mt=0;mt<8;mt++){
    int jb = w*16 + mt*2 + (lq>>1);               // 16B hid-block index
    float4 bb = *(const float4*)(b1p + w*128 + mt*16 + lq*4);
    #pragma unroll
    for(int nt=0;nt<2;nt++){
      int px = nt*16 + lr;
      uint u0 = (uint)f2us(gelu_f(acc1[mt][nt][0]+bb.x)) | ((uint)f2us(gelu_f(acc1[mt][nt][1]+bb.y))<<16);
      uint u1 = (uint)f2us(gelu_f(acc1[mt][nt][2]+bb.z)) | ((uint)f2us(gelu_f(acc1[mt][nt][3]+bb.w))<<16);
      uint byo = (uint)px*1024u + (uint)((jb ^ h7)<<4) + (uint)((lq&1)<<3);
      *(uint2*)((char*)midT + byo) = make_uint2(u0, u1);
    }
  }
  __syncthreads();
  // ---- GEMM2: out[w*64 .. +64) x 32 px over K=512 ----
  const ushort* a2[4];
  #pragma unroll
  for(int mt=0;mt<4;mt++) a2[mt] = (const ushort*)(ws+OFF_W2B) + (size_t)(w*64+mt*16+lr)*512 + lq*8;
  f32x4 acc2[4][2] = {};
  #pragma unroll
  for(int kk=0;kk<16;kk++){
    short8 bfr[2];
    #pragma unroll
    for(int nt=0;nt<2;nt++){
      int px = nt*16 + lr;
      int j2 = kk*4 + lq;                          // 16B hid-block index of this frag
      uint byo = (uint)px*1024u + (uint)((j2 ^ h7)<<4);
      bfr[nt] = *(const short8*)((const char*)midT + byo);
    }
    #pragma unroll
    for(int mt=0;mt<4;mt++){
      short8 af = *(const short8*)(a2[mt]+kk*32);
      #pragma unroll
      for(int nt=0;nt<2;nt++)
        acc2[mt][nt] = __builtin_amdgcn_mfma_f32_16x16x32_bf16(af, bfr[nt], acc2[mt][nt], 0,0,0);
    }
  }
  // ---- epilogue: + b2 + residual ----
  #pragma unroll
  for(int mt=0;mt<4;mt++){
    float4 bb = *(const float4*)(b2 + w*64 + mt*16 + lq*4);
    float bbv[4] = {bb.x, bb.y, bb.z, bb.w};
    #pragma unroll
    for(int r=0;r<4;r++){
      int om = w*64 + mt*16 + lq*4 + r;
      #pragma unroll
      for(int nt=0;nt<2;nt++){
        int n = p0 + nt*16 + lr;
        size_t ad = ((size_t)(b*NC+om))*NHW + n;
        out[ad] = acc2[mt][nt][r] + bbv[r] + x[ad];
      }
    }
  }
}

extern "C" void kernel_launch(void* const* d_in, const int* in_sizes, int n_in,
                              void* d_out, int out_size, void* d_ws, size_t ws_size,
                              hipStream_t stream) {
  const float* x     = (const float*)d_in[0];
  const float* gamma = (const float*)d_in[1];
  const float* beta  = (const float*)d_in[2];
  const float* n0w   = (const float*)d_in[3];
  const float* n0b   = (const float*)d_in[4];
  const float* n1w   = (const float*)d_in[5];
  const float* n1b   = (const float*)d_in[6];
  const float* wsr   = (const float*)d_in[7];
  const float* wsi   = (const float*)d_in[8];
  const float* iw    = (const float*)d_in[9];
  const float* ib    = (const float*)d_in[10];
  const float* w1    = (const float*)d_in[11];
  const float* b1    = (const float*)d_in[12];
  const float* w2    = (const float*)d_in[13];
  const float* b2    = (const float*)d_in[14];
  float* ws = (float*)d_ws;
  float* out = (float*)d_out;
  if (ws_size < WS_FLOATS*4ULL) return;

  k_setup <<<dim3(2304), dim3(256), 0, stream>>>(ws, wsr, wsi, iw, w2);
  k_stats0<<<dim3(512),  dim3(256), 0, stream>>>(x, n0w, n0b, ws);
  k_norm  <<<dim3(120,512), dim3(256), 0, stream>>>(x, ws);
  // GEMM1: A1(RA) -> F(RB planes)
  k_sgemm<0,0><<<dim3(4,240), dim3(256), 0, stream>>>((const ushort*)(ws+RA0), (const ushort*)(ws+RA0),
      (const ushort*)(ws+OFF_TWF), (ushort*)(ws+OFF_FRE), (ushort*)(ws+OFF_FIM), nullptr);
  // T1: F(RB) -> Ft(RA)
  k_t64 <<<dim3(2,2,512), dim3(256), 0, stream>>>((const ushort*)(ws+OFF_FRE), (ushort*)(ws+RA0), NH, NH*128);
  k_t64 <<<dim3(2,2,512), dim3(256), 0, stream>>>((const ushort*)(ws+OFF_FIM), (ushort*)(ws+RA1), NH, NH*128);
  // GEMM2: Ft(RA) -> G(RB)
  k_sgemm<1,0><<<dim3(4,256), dim3(256), 0, stream>>>((const ushort*)(ws+RA0), (const ushort*)(ws+RA1),
      (const ushort*)(ws+OFF_THF), (ushort*)(ws+RB0), (ushort*)(ws+RB1), nullptr);
  // T2: G(RB) -> Gt(RA) [b][p][c]
  k_tP <<<dim3(256,4,2), dim3(256), 0, stream>>>((const ushort*)(ws+RB0), (ushort*)(ws+RA0));
  k_tP <<<dim3(256,4,2), dim3(256), 0, stream>>>((const ushort*)(ws+RB1), (ushort*)(ws+RA1));
  // mix: Gt(RA) -> Y(RB)
  k_mixg <<<dim3(512,1,2), dim3(256), 0, stream>>>(ws);
  // GEMM4: Y(RB) -> Z(RA)
  k_sgemm<1,0><<<dim3(4,256), dim3(256), 0, stream>>>((const ushort*)(ws+RB0), (const ushort*)(ws+RB1),
      (const ushort*)(ws+OFF_THI), (ushort*)(ws+RA0), (ushort*)(ws+RA1), nullptr);
  // T3: Z(RA) -> Zt(RB)
  k_t64 <<<dim3(2,2,512), dim3(256), 0, stream>>>((const ushort*)(ws+RA0), (ushort*)(ws+RB0), 128, NSP);
  k_t64 <<<dim3(2,2,512), dim3(256), 0, stream>>>((const ushort*)(ws+RA1), (ushort*)(ws+RB1), 128, NSP);
  // GEMM5: Zt(RB) -> U spectral bf16 channel-major (RA)
  k_sgemm<1,1><<<dim3(4,256), dim3(256), 0, stream>>>((const ushort*)(ws+RB0), (const ushort*)(ws+RB1),
      (const ushort*)(ws+OFF_TWI), nullptr, nullptr, (ushort*)(ws+RA0));
  // Phase A: inner conv fused (x + Usp -> U' pixel-major bf16 in RB, + stats partials)
  k_inner <<<dim3(NPT,1,2), dim3(256), 0, stream>>>(ws, x, ib);
  k_stats1p<<<dim3(512), dim3(256), 0, stream>>>(gamma, beta, n1w, n1b, ws);
  k_fold  <<<dim3(512,2), dim3(64), 0, stream>>>(ws, w1, b1);
  // Phase C: fused MLP, 32-px blocks, swizzled 32KB LDS handoff
  k_mlp   <<<dim3(900,1,2), dim3(256), 0, stream>>>(ws, x, b2, out);
}

// Round 4
// 643.883 us; speedup vs baseline: 1.2118x; 1.0539x over previous
//
#include <hip/hip_runtime.h>
#include <hip/hip_bf16.h>

typedef __hip_bfloat16 bf16;
typedef short short8 __attribute__((ext_vector_type(8)));
typedef float f32x4 __attribute__((ext_vector_type(4)));

#define NB 2
#define NC 256
#define NH 120
#define NW 240
#define NHW (NH*NW)      // 28800
#define NSP 16384        // padded spectral pixels per image (128*128)
#define NHID 512
#define NPT 450          // pixel tiles of 64
#define REPS 1e-5f
#define SC_W 0.06454972243679028f   // 1/sqrt(240)
#define SC_H 0.09128709291752769f   // 1/sqrt(120)
#define PI2 6.283185307179586f

__device__ __forceinline__ float gelu_f(float x){ return 0.5f*x*(1.f+erff(x*0.7071067811865476f)); }
__device__ __forceinline__ float us2f(ushort u){ union{float f; uint v;} c; c.v=((uint)u)<<16; return c.f; }
__device__ __forceinline__ ushort f2us(float f){ bf16 b=__float2bfloat16(f); return *(ushort*)&b; }

// async 16B global->LDS (wave-uniform LDS base + lane*16; global addr per-lane)
typedef __attribute__((address_space(3))) void lds_void;
typedef const __attribute__((address_space(1))) void gbl_void;
__device__ __forceinline__ void gload16(const ushort* g, ushort* l){
  __builtin_amdgcn_global_load_lds((gbl_void*)g, (lds_void*)l, 16, 0, 0);
}

// ---- workspace float offsets ----
#define OFF_A0   0
#define OFF_D0   512
#define OFF_A1c  1024
#define OFF_D1c  1536
#define OFF_TWF  2048       // bf16[256][256] fwd-W DFT
#define OFF_THF  34816      // bf16[256][256] fwd-H
#define OFF_THI  67584      // bf16[256][256] inv-H
#define OFF_TWI  100352     // bf16[256][256] inv-W real
#define OFF_WRT  133120     // bf16[256][256] w_spec_r^T [o][i]
#define OFF_WIT  165888     // bf16[256][256] w_spec_i^T
#define OFF_IWB  198656     // bf16[256][256] inner_w [o][i]
#define OFF_W2B  231424     // bf16[256][512]  natural layout
#define OFF_W1P  296960     // bf16[2][512][256]  a1-folded mlp_w1
#define OFF_B1P  428032     // f32[2][512]        folded bias1
#define OFF_PS   429056     // f32[2][450][512]   stats partials (sum | sumsq)
#define OFF_RA   889856     // 8388608 floats ping A
#define OFF_RB   9278464    // 8388608 floats ping B
#define WS_FLOATS 17667072ULL   // 70.7 MB

#define RA0 OFF_RA
#define RA1 (OFF_RA+4194304)
#define RB0 OFF_RB
#define RB1 (OFF_RB+4194304)
#define OFF_FRE RB0
#define OFF_FIM (RB0+3932160)

// ---------------- setup: DFT matrices + weight casts ----------------
__global__ __launch_bounds__(256) void k_setup(float* ws, const float* wsr, const float* wsi,
                                               const float* iw, const float* w2){
  int t = blockIdx.x*256 + threadIdx.x;
  if (t < 65536){ // TWF [n][w]
    int n=t>>8, w=t&255; float v=0.f;
    if(w<NW){
      if(n<121){ v = cosf(PI2*(float)((n*w)%NW)/(float)NW)*SC_W; }
      else if(n>=128 && n<249){ int k=n-128; v = -sinf(PI2*(float)((k*w)%NW)/(float)NW)*SC_W; }
    }
    ((ushort*)(ws+OFF_TWF))[t]=f2us(v); return;
  } t-=65536;
  if (t < 65536){ // THF
    int n=t>>8, j=t&255; float v=0.f;
    int h = j&127; bool im = (j>=128);
    if(h<NH){
      if(n<128){ int m=n; if(m<NH){ float sn,cs; sincosf(PI2*(float)((m*h)%NH)/(float)NH,&sn,&cs);
        v = (im? sn : cs)*SC_H; } }
      else { int m=n-128; if(m<NH){ float sn,cs; sincosf(PI2*(float)((m*h)%NH)/(float)NH,&sn,&cs);
        v = (im? cs : -sn)*SC_H; } }
    }
    ((ushort*)(ws+OFF_THF))[t]=f2us(v); return;
  } t-=65536;
  if (t < 65536){ // THI
    int n=t>>8, j=t&255; float v=0.f;
    int m = j&127; bool im = (j>=128);
    if(m<NH){
      if(n<128){ int h=n; if(h<NH){ float sn,cs; sincosf(PI2*(float)((h*m)%NH)/(float)NH,&sn,&cs);
        v = (im? -sn : cs)*SC_H; } }
      else { int h=n-128; if(h<NH){ float sn,cs; sincosf(PI2*(float)((h*m)%NH)/(float)NH,&sn,&cs);
        v = (im? cs : sn)*SC_H; } }
    }
    ((ushort*)(ws+OFF_THI))[t]=f2us(v); return;
  } t-=65536;
  if (t < 65536){ // TWI
    int w=t>>8, j=t&255; float v=0.f;
    if(w<NW){
      int k = j&127; bool im = (j>=128);
      if(k<121){
        float ck = (k==0||k==120)? 1.f : 2.f;
        float sn,cs; sincosf(PI2*(float)((w*k)%NW)/(float)NW,&sn,&cs);
        v = ck*(im? -sn : cs)*SC_W;
      }
    }
    ((ushort*)(ws+OFF_TWI))[t]=f2us(v); return;
  } t-=65536;
  if (t < 65536){ int o=t>>8,i=t&255; ((ushort*)(ws+OFF_WRT))[t]=f2us(wsr[i*NC+o]); return; } t-=65536;
  if (t < 65536){ int o=t>>8,i=t&255; ((ushort*)(ws+OFF_WIT))[t]=f2us(wsi[i*NC+o]); return; } t-=65536;
  if (t < 65536){ ((ushort*)(ws+OFF_IWB))[t]=f2us(iw[t]); return; } t-=65536;
  if (t < 131072){ ((ushort*)(ws+OFF_W2B))[t]=f2us(w2[t]); return; }
}

// ---------------- instance-norm stats on x ----------------
__global__ __launch_bounds__(256) void k_stats0(const float* x, const float* n0w, const float* n0b, float* ws){
  int g = blockIdx.x, c = g & (NC-1);
  const float4* xp = (const float4*)(x + (size_t)g*NHW);
  float s=0.f, q=0.f;
  for(int i=threadIdx.x;i<NHW/4;i+=256){
    float4 v=xp[i];
    s+=v.x+v.y+v.z+v.w;
    q=fmaf(v.x,v.x,fmaf(v.y,v.y,fmaf(v.z,v.z,fmaf(v.w,v.w,q))));
  }
  __shared__ float ls[4], lq[4];
  #pragma unroll
  for(int o=32;o>0;o>>=1){ s+=__shfl_down(s,o,64); q+=__shfl_down(q,o,64); }
  int lane=threadIdx.x&63, wid=threadIdx.x>>6;
  if(!lane){ ls[wid]=s; lq[wid]=q; }
  __syncthreads();
  if(!threadIdx.x){
    s=ls[0]+ls[1]+ls[2]+ls[3]; q=lq[0]+lq[1]+lq[2]+lq[3];
    float m=s*(1.f/NHW), var=q*(1.f/NHW)-m*m;
    float r=rsqrtf(var+REPS);
    float a=r*n0w[c];
    ws[OFF_A0+g]=a; ws[OFF_D0+g]=fmaf(-m,a,n0b[c]);
  }
}

// ---------------- norm+cast: x -> A1 bf16 [g][h][256] ----------------
__global__ __launch_bounds__(256) void k_norm(const float* x, float* ws){
  int h = blockIdx.x, g = blockIdx.y, t = threadIdx.x;
  float a = ws[OFF_A0+g], d = ws[OFF_D0+g];
  ushort v = 0;
  if(t < NW) v = f2us(fmaf(a, x[(size_t)g*NHW + (size_t)h*NW + t], d));
  ((ushort*)(ws+RA0))[(size_t)g*30720 + (size_t)h*256 + t] = v;
}

// ---------------- spectral GEMM ----------------
template<int SPLIT, int EPI>
__global__ __launch_bounds__(256) void k_sgemm(const ushort* Ap0, const ushort* Ap1, const ushort* Bm,
                                               ushort* O0, ushort* O1, ushort* Ub){
  int nb = blockIdx.x*64, mb = blockIdx.y*256;
  int tid = threadIdx.x, w = tid>>6, l = tid&63, lq = l>>4, lr = l&15;
  const ushort* ar0[4]; const ushort* ar1[4]; const ushort* br[4];
  #pragma unroll
  for(int mt=0;mt<4;mt++){
    size_t r = mb + w*64 + mt*16 + lr;
    ar0[mt] = Ap0 + r*(SPLIT?128:256) + lq*8;
    ar1[mt] = SPLIT ? (Ap1 + r*128 + lq*8) : ar0[mt];
  }
  #pragma unroll
  for(int nt=0;nt<4;nt++) br[nt] = Bm + (size_t)(nb + nt*16 + lr)*256 + lq*8;
  f32x4 acc[4][4] = {};
  #pragma unroll
  for(int kk=0;kk<8;kk++){
    int k = kk*32;
    short8 af[4], bfr[4];
    #pragma unroll
    for(int mt=0;mt<4;mt++){
      const ushort* p = SPLIT ? ((k<128 ? ar0[mt] : ar1[mt]) + (k&127)) : (ar0[mt] + k);
      af[mt] = *(const short8*)p;
    }
    #pragma unroll
    for(int nt=0;nt<4;nt++) bfr[nt] = *(const short8*)(br[nt]+k);
    #pragma unroll
    for(int mt=0;mt<4;mt++)
      #pragma unroll
      for(int nt=0;nt<4;nt++)
        acc[mt][nt] = __builtin_amdgcn_mfma_f32_16x16x32_bf16(af[mt], bfr[nt], acc[mt][nt], 0,0,0);
  }
  #pragma unroll
  for(int mt=0;mt<4;mt++){
    #pragma unroll
    for(int r=0;r<4;r++){
      int m = mb + w*64 + mt*16 + lq*4 + r;
      #pragma unroll
      for(int nt=0;nt<4;nt++){
        int n = nb + nt*16 + lr;
        float v = acc[mt][nt][r];
        if (EPI==0){
          if(n<128) O0[(size_t)m*128+n] = f2us(v);
          else      O1[(size_t)m*128+n-128] = f2us(v);
        } else {
          int g = m>>7, h = m&127;
          if(h<NH && n<NW) Ub[(size_t)g*NHW + (size_t)h*NW + n] = f2us(v);
        }
      }
    }
  }
}

// ---------------- 64x64 bf16 transpose within 128-stride planes ----------------
__global__ __launch_bounds__(256) void k_t64(const ushort* src, ushort* dst, int srows, int sgstr){
  __shared__ ushort lt[64][72];
  int g=blockIdx.z, i0=blockIdx.y*64, p0=blockIdx.x*64;
  int t=threadIdx.x, r=t>>2, q=t&3;
  int row = i0 + r;
  uint4 u0=make_uint4(0,0,0,0), u1=u0;
  if(row < srows){
    const ushort* sp = src + (size_t)g*sgstr + (size_t)row*128 + p0 + q*16;
    u0=*(const uint4*)sp; u1=*(const uint4*)(sp+8);
  }
  *(uint4*)&lt[r][q*16]=u0; *(uint4*)&lt[r][q*16+8]=u1;
  __syncthreads();
  int pr=t>>2, q2=t&3;
  union { ushort s[8]; uint4 u; } o0, o1;
  #pragma unroll
  for(int e=0;e<8;e++){ o0.s[e]=lt[q2*16+e][pr]; o1.s[e]=lt[q2*16+8+e][pr]; }
  ushort* dp = dst + (size_t)g*NSP + (size_t)(p0+pr)*128 + i0 + q2*16;
  *(uint4*)dp = o0.u; *(uint4*)(dp+8) = o1.u;
}

// ---------------- pixel transpose: [b][c:256][NSP] -> [b][NSP][c] ----------------
__global__ __launch_bounds__(256) void k_tP(const ushort* src, ushort* dst){
  __shared__ ushort lt[64][72];
  int b=blockIdx.z, i0=blockIdx.y*64, p0=blockIdx.x*64;
  int t=threadIdx.x, r=t>>2, q=t&3;
  const ushort* sp = src + (size_t)(b*NC+i0+r)*NSP + p0 + q*16;
  uint4 u0=*(const uint4*)sp, u1=*(const uint4*)(sp+8);
  *(uint4*)&lt[r][q*16]=u0; *(uint4*)&lt[r][q*16+8]=u1;
  __syncthreads();
  int pr=t>>2, q2=t&3;
  union { ushort s[8]; uint4 u; } o0, o1;
  #pragma unroll
  for(int e=0;e<8;e++){ o0.s[e]=lt[q2*16+e][pr]; o1.s[e]=lt[q2*16+8+e][pr]; }
  ushort* dp = dst + ((size_t)b*NSP + p0 + pr)*NC + i0 + q2*16;
  *(uint4*)dp = o0.u; *(uint4*)(dp+8) = o1.u;
}

// ---------------- complex spectral mix via MFMA ----------------
__global__ __launch_bounds__(256) void k_mixg(float* ws){
  int b = blockIdx.z, p0 = blockIdx.x*32;
  int tid = threadIdx.x, w = tid>>6, l = tid&63, lq = l>>4, lr = l&15;
  const ushort* Wr = (const ushort*)(ws+OFF_WRT);
  const ushort* Wi = (const ushort*)(ws+OFF_WIT);
  const ushort* Gr = (const ushort*)(ws+RA0) + (size_t)b*NSP*NC;
  const ushort* Gi = (const ushort*)(ws+RA1) + (size_t)b*NSP*NC;
  const ushort *wrr[4], *wir[4], *brr[2], *bir[2];
  #pragma unroll
  for(int mt=0;mt<4;mt++){ size_t ro=(size_t)(w*64+mt*16+lr)*NC+lq*8; wrr[mt]=Wr+ro; wir[mt]=Wi+ro; }
  #pragma unroll
  for(int nt=0;nt<2;nt++){ size_t ro=(size_t)(p0+nt*16+lr)*NC+lq*8; brr[nt]=Gr+ro; bir[nt]=Gi+ro; }
  f32x4 aR[4][2]={}, aI[4][2]={};
  for(int k=0;k<256;k+=32){
    short8 fr[4], fi[4], fin[4], gr[2], gi[2];
    #pragma unroll
    for(int mt=0;mt<4;mt++){
      fr[mt]=*(const short8*)(wrr[mt]+k);
      fi[mt]=*(const short8*)(wir[mt]+k);
      union { short8 s; uint u[4]; } nv; nv.s=fi[mt];
      nv.u[0]^=0x80008000u; nv.u[1]^=0x80008000u; nv.u[2]^=0x80008000u; nv.u[3]^=0x80008000u;
      fin[mt]=nv.s;
    }
    #pragma unroll
    for(int nt=0;nt<2;nt++){ gr[nt]=*(const short8*)(brr[nt]+k); gi[nt]=*(const short8*)(bir[nt]+k); }
    #pragma unroll
    for(int mt=0;mt<4;mt++)
      #pragma unroll
      for(int nt=0;nt<2;nt++){
        aR[mt][nt]=__builtin_amdgcn_mfma_f32_16x16x32_bf16(fr[mt], gr[nt], aR[mt][nt],0,0,0);
        aR[mt][nt]=__builtin_amdgcn_mfma_f32_16x16x32_bf16(fin[mt],gi[nt], aR[mt][nt],0,0,0);
        aI[mt][nt]=__builtin_amdgcn_mfma_f32_16x16x32_bf16(fi[mt], gr[nt], aI[mt][nt],0,0,0);
        aI[mt][nt]=__builtin_amdgcn_mfma_f32_16x16x32_bf16(fr[mt], gi[nt], aI[mt][nt],0,0,0);
      }
  }
  ushort* Yre = (ushort*)(ws+RB0);
  ushort* Yim = (ushort*)(ws+RB1);
  #pragma unroll
  for(int mt=0;mt<4;mt++){
    #pragma unroll
    for(int r=0;r<4;r++){
      int m = w*64 + mt*16 + lq*4 + r;
      #pragma unroll
      for(int nt=0;nt<2;nt++){
        int n = p0 + nt*16 + lr;
        size_t ad = (size_t)(b*NC+m)*NSP + n;
        Yre[ad] = f2us(aR[mt][nt][r]);
        Yim[ad] = f2us(aI[mt][nt][r]);
      }
    }
  }
}

// ---------------- Phase A: fused x-transpose + inner conv + gelu + stats + U' ----------------
__global__ __launch_bounds__(256,2) void k_inner(float* ws, const float* x, const float* ib){
  __shared__ ushort xt[64][264];
  int b = blockIdx.z, blk = blockIdx.x, p0 = blk*64;
  int t = threadIdx.x, w = t>>6, l = t&63, lq = l>>4, lr = l&15;
  // load + transpose x tile -> xt[p][c] bf16
  #pragma unroll 4
  for(int cc=0; cc<16; cc++){
    int c = cc*16 + (t>>4);
    int p4 = (t&15)*4;
    float4 v = *(const float4*)(x + ((size_t)(b*NC+c))*NHW + p0 + p4);
    xt[p4  ][c]=f2us(v.x); xt[p4+1][c]=f2us(v.y);
    xt[p4+2][c]=f2us(v.z); xt[p4+3][c]=f2us(v.w);
  }
  __syncthreads();
  const ushort* W = (const ushort*)(ws+OFF_IWB);
  const ushort* ar[4];
  #pragma unroll
  for(int mt=0;mt<4;mt++) ar[mt] = W + (size_t)(w*64+mt*16+lr)*256 + lq*8;
  f32x4 acc[4][4] = {};
  #pragma unroll
  for(int kk=0;kk<8;kk++){
    int k = kk*32;
    short8 af[4], bfr[4];
    #pragma unroll
    for(int mt=0;mt<4;mt++) af[mt] = *(const short8*)(ar[mt]+k);
    #pragma unroll
    for(int nt=0;nt<4;nt++) bfr[nt] = *(const short8*)&xt[nt*16+lr][k+lq*8];
    #pragma unroll
    for(int mt=0;mt<4;mt++)
      #pragma unroll
      for(int nt=0;nt<4;nt++)
        acc[mt][nt] = __builtin_amdgcn_mfma_f32_16x16x32_bf16(af[mt], bfr[nt], acc[mt][nt], 0,0,0);
  }
  __syncthreads();   // all waves done reading xt; reuse as output transpose buffer
  const ushort* Usp = (const ushort*)(ws+OFF_RA);
  float* PS = ws + OFF_PS + ((size_t)(b*NPT+blk))*512;
  #pragma unroll
  for(int mt=0;mt<4;mt++){
    #pragma unroll
    for(int r=0;r<4;r++){
      int m = w*64 + mt*16 + lq*4 + r;
      float bb = ib[m];
      float ss = 0.f, sq = 0.f;
      #pragma unroll
      for(int nt=0;nt<4;nt++){
        int n = p0 + nt*16 + lr;
        float uv = us2f(Usp[((size_t)(b*NC+m))*NHW + n]);
        float g = gelu_f(acc[mt][nt][r] + bb + uv);
        xt[nt*16+lr][m] = f2us(g);
        ss += g; sq = fmaf(g,g,sq);
      }
      #pragma unroll
      for(int ofs=1; ofs<16; ofs<<=1){ ss += __shfl_xor(ss, ofs, 64); sq += __shfl_xor(sq, ofs, 64); }
      if(lr==0){ PS[m] = ss; PS[256+m] = sq; }
    }
  }
  __syncthreads();
  ushort* Up = (ushort*)(ws+OFF_RB);
  #pragma unroll
  for(int pp=0; pp<4; pp++){
    int p = pp*16 + (t>>4);
    int c0 = (t&15)*16;
    uint4 w0 = *(uint4*)&xt[p][c0];
    uint4 w1v = *(uint4*)&xt[p][c0+8];
    ushort* dp = Up + ((size_t)(b*NHW + p0 + p))*256 + c0;
    *(uint4*)dp = w0; *(uint4*)(dp+8) = w1v;
  }
}

// ---------------- stats1: reduce partials -> a1,d1 (FiLM folded) ----------------
__global__ __launch_bounds__(256) void k_stats1p(const float* gamma, const float* beta,
                                                 const float* n1w, const float* n1b, float* ws){
  int g = blockIdx.x, b = g>>8, c = g&255;
  float s=0.f, q=0.f;
  for(int i=threadIdx.x;i<NPT;i+=256){
    const float* P = ws + OFF_PS + ((size_t)(b*NPT+i))*512;
    s += P[c]; q += P[256+c];
  }
  __shared__ float ls[4], lq2[4];
  #pragma unroll
  for(int o=32;o>0;o>>=1){ s+=__shfl_down(s,o,64); q+=__shfl_down(q,o,64); }
  int lane=threadIdx.x&63, wid=threadIdx.x>>6;
  if(!lane){ ls[wid]=s; lq2[wid]=q; }
  __syncthreads();
  if(!threadIdx.x){
    s=ls[0]+ls[1]+ls[2]+ls[3]; q=lq2[0]+lq2[1]+lq2[2]+lq2[3];
    float m=s*(1.f/NHW), var=q*(1.f/NHW)-m*m;
    float r=rsqrtf(var+REPS);
    float gp1 = 1.f + gamma[c];
    float wv = n1w[c];
    ws[OFF_A1c+g] = gp1*wv*r;
    ws[OFF_D1c+g] = gp1*(n1b[c] - m*r*wv) + beta[c];
  }
}

// ---------------- fold a1/d1 into W1: W1'[b]=W1*diag(a1), b1'=W1*d1+b1 ----------------
__global__ __launch_bounds__(64) void k_fold(float* ws, const float* w1, const float* b1){
  int o = blockIdx.x, b = blockIdx.y, t = threadIdx.x;
  float acc = 0.f;
  ushort* W1p = (ushort*)(ws+OFF_W1P);
  #pragma unroll
  for(int ii=0; ii<4; ii++){
    int i = ii*64 + t;
    float wv = w1[o*256+i];
    W1p[((size_t)(b*NHID+o))*256 + i] = f2us(wv * ws[OFF_A1c + b*NC + i]);
    acc = fmaf(wv, ws[OFF_D1c + b*NC + i], acc);
  }
  #pragma unroll
  for(int ofs=32; ofs; ofs>>=1) acc += __shfl_down(acc, ofs, 64);
  if(!t) ws[OFF_B1P + b*NHID + o] = acc + b1[o];
}

// ---------------- Phase C: two staged 128x128-tile GEMMs (m97 structure) ----------------
// C[M][N] = A[M][K] . B[N][K]^T, bf16 in / f32 acc. 4 waves, wave = 64x64 subtile.
// K-step 32: A-tile/B-tile 128x32 bf16 = 8KB each, double-buffered (32KB LDS).
// Staging: global_load_lds width-16; LDS dest linear (wave base + lane*16); the
// 16B-chunk is swizzled on the GLOBAL side (cg = cd ^ ((row>>1)&3)) and the same
// XOR is applied on the ds_read side -> 2-way bank aliasing only (free).
// One barrier per K-step: stage(next buf) after barrier overlaps compute(cur buf);
// compiler's vmcnt/lgkm drain before s_barrier provides the cross-iteration fence.
// EPI 0 (mlp1): D=gelu(acc+bias[n]) -> bf16 mid[m][512].  (A=U' px-major, B=W1p)
// EPI 1 (mlp2): D=acc+bias[m]+x[m*NHW+n] -> f32 out.      (A=W2, B=mid)
template<int KD, int EPI>
__global__ __launch_bounds__(256) void k_gemm128(const ushort* __restrict__ A, const ushort* __restrict__ B,
                                                 const float* __restrict__ bias, const float* __restrict__ xres,
                                                 ushort* __restrict__ Obf, float* __restrict__ Ofl){
  __shared__ ushort As[2][4096] __attribute__((aligned(16)));
  __shared__ ushort Bs[2][4096] __attribute__((aligned(16)));
  int t = threadIdx.x, w = t>>6, l = t&63, lq = l>>4, lr = l&15;
  int wr = w>>1, wc = w&1;
  int nb = blockIdx.x*128, mb = blockIdx.y*128;
  const ushort* Ab = A + (size_t)mb*KD;
  const ushort* Bb = B + (size_t)nb*KD;
  // staging geometry: thread t fills LDS chunk t (row t>>2, chunk t&3) and row+64;
  // source chunk is pre-swizzled so reads can XOR the same pattern.
  int srow = t>>2;
  int scg  = (t&3) ^ ((t>>3)&3);
  size_t so0 = (size_t)srow*KD + scg*8;
  size_t so1 = (size_t)(srow+64)*KD + scg*8;
  int ld0 = w*512, ld1 = 2048 + w*512;     // wave-uniform LDS dest bases (ushort units)
  int swk = (lq ^ ((lr>>1)&3))*8;          // swizzled read chunk offset (ushort units)
  f32x4 acc[4][4] = {};
  // prologue: stage kt=0 into buf 0
  gload16(Ab+so0, &As[0][ld0]); gload16(Ab+so1, &As[0][ld1]);
  gload16(Bb+so0, &Bs[0][ld0]); gload16(Bb+so1, &Bs[0][ld1]);
  const int NK = KD/32;
  for(int kt=0; kt<NK; kt++){
    int cur = kt&1;
    __syncthreads();                        // buf[cur] staged (vmcnt drained pre-barrier)
    if(kt+1 < NK){
      size_t ko = (size_t)(kt+1)*32;
      gload16(Ab+so0+ko, &As[cur^1][ld0]); gload16(Ab+so1+ko, &As[cur^1][ld1]);
      gload16(Bb+so0+ko, &Bs[cur^1][ld0]); gload16(Bb+so1+ko, &Bs[cur^1][ld1]);
    }
    short8 af[4], bfr[4];
    #pragma unroll
    for(int mt=0;mt<4;mt++) af[mt]  = *(const short8*)&As[cur][(wr*64+mt*16+lr)*32 + swk];
    #pragma unroll
    for(int nt=0;nt<4;nt++) bfr[nt] = *(const short8*)&Bs[cur][(wc*64+nt*16+lr)*32 + swk];
    #pragma unroll
    for(int mt=0;mt<4;mt++)
      #pragma unroll
      for(int nt=0;nt<4;nt++)
        acc[mt][nt] = __builtin_amdgcn_mfma_f32_16x16x32_bf16(af[mt], bfr[nt], acc[mt][nt], 0,0,0);
  }
  if (EPI==0){
    #pragma unroll
    for(int nt=0;nt<4;nt++){
      int n = nb + wc*64 + nt*16 + lr;
      float bb = bias[n];
      #pragma unroll
      for(int mt=0;mt<4;mt++)
        #pragma unroll
        for(int r=0;r<4;r++){
          int m = mb + wr*64 + mt*16 + lq*4 + r;
          Obf[(size_t)m*NHID + n] = f2us(gelu_f(acc[mt][nt][r] + bb));
        }
    }
  } else {
    #pragma unroll
    for(int mt=0;mt<4;mt++)
      #pragma unroll
      for(int r=0;r<4;r++){
        int m = mb + wr*64 + mt*16 + lq*4 + r;
        float bb = bias[m];
        #pragma unroll
        for(int nt=0;nt<4;nt++){
          int n = nb + wc*64 + nt*16 + lr;
          size_t ad = (size_t)m*NHW + n;
          Ofl[ad] = acc[mt][nt][r] + bb + xres[ad];
        }
      }
  }
}

extern "C" void kernel_launch(void* const* d_in, const int* in_sizes, int n_in,
                              void* d_out, int out_size, void* d_ws, size_t ws_size,
                              hipStream_t stream) {
  const float* x     = (const float*)d_in[0];
  const float* gamma = (const float*)d_in[1];
  const float* beta  = (const float*)d_in[2];
  const float* n0w   = (const float*)d_in[3];
  const float* n0b   = (const float*)d_in[4];
  const float* n1w   = (const float*)d_in[5];
  const float* n1b   = (const float*)d_in[6];
  const float* wsr   = (const float*)d_in[7];
  const float* wsi   = (const float*)d_in[8];
  const float* iw    = (const float*)d_in[9];
  const float* ib    = (const float*)d_in[10];
  const float* w1    = (const float*)d_in[11];
  const float* b1    = (const float*)d_in[12];
  const float* w2    = (const float*)d_in[13];
  const float* b2    = (const float*)d_in[14];
  float* ws = (float*)d_ws;
  float* out = (float*)d_out;
  if (ws_size < WS_FLOATS*4ULL) return;

  k_setup <<<dim3(2304), dim3(256), 0, stream>>>(ws, wsr, wsi, iw, w2);
  k_stats0<<<dim3(512),  dim3(256), 0, stream>>>(x, n0w, n0b, ws);
  k_norm  <<<dim3(120,512), dim3(256), 0, stream>>>(x, ws);
  // GEMM1: A1(RA) -> F(RB planes)
  k_sgemm<0,0><<<dim3(4,240), dim3(256), 0, stream>>>((const ushort*)(ws+RA0), (const ushort*)(ws+RA0),
      (const ushort*)(ws+OFF_TWF), (ushort*)(ws+OFF_FRE), (ushort*)(ws+OFF_FIM), nullptr);
  // T1: F(RB) -> Ft(RA)
  k_t64 <<<dim3(2,2,512), dim3(256), 0, stream>>>((const ushort*)(ws+OFF_FRE), (ushort*)(ws+RA0), NH, NH*128);
  k_t64 <<<dim3(2,2,512), dim3(256), 0, stream>>>((const ushort*)(ws+OFF_FIM), (ushort*)(ws+RA1), NH, NH*128);
  // GEMM2: Ft(RA) -> G(RB)
  k_sgemm<1,0><<<dim3(4,256), dim3(256), 0, stream>>>((const ushort*)(ws+RA0), (const ushort*)(ws+RA1),
      (const ushort*)(ws+OFF_THF), (ushort*)(ws+RB0), (ushort*)(ws+RB1), nullptr);
  // T2: G(RB) -> Gt(RA) [b][p][c]
  k_tP <<<dim3(256,4,2), dim3(256), 0, stream>>>((const ushort*)(ws+RB0), (ushort*)(ws+RA0));
  k_tP <<<dim3(256,4,2), dim3(256), 0, stream>>>((const ushort*)(ws+RB1), (ushort*)(ws+RA1));
  // mix: Gt(RA) -> Y(RB)
  k_mixg <<<dim3(512,1,2), dim3(256), 0, stream>>>(ws);
  // GEMM4: Y(RB) -> Z(RA)
  k_sgemm<1,0><<<dim3(4,256), dim3(256), 0, stream>>>((const ushort*)(ws+RB0), (const ushort*)(ws+RB1),
      (const ushort*)(ws+OFF_THI), (ushort*)(ws+RA0), (ushort*)(ws+RA1), nullptr);
  // T3: Z(RA) -> Zt(RB)
  k_t64 <<<dim3(2,2,512), dim3(256), 0, stream>>>((const ushort*)(ws+RA0), (ushort*)(ws+RB0), 128, NSP);
  k_t64 <<<dim3(2,2,512), dim3(256), 0, stream>>>((const ushort*)(ws+RA1), (ushort*)(ws+RB1), 128, NSP);
  // GEMM5: Zt(RB) -> U spectral bf16 channel-major (RA)
  k_sgemm<1,1><<<dim3(4,256), dim3(256), 0, stream>>>((const ushort*)(ws+RB0), (const ushort*)(ws+RB1),
      (const ushort*)(ws+OFF_TWI), nullptr, nullptr, (ushort*)(ws+RA0));
  // Phase A: inner conv fused (x + Usp -> U' pixel-major bf16 in RB, + stats partials)
  k_inner <<<dim3(NPT,1,2), dim3(256), 0, stream>>>(ws, x, ib);
  k_stats1p<<<dim3(512), dim3(256), 0, stream>>>(gamma, beta, n1w, n1b, ws);
  k_fold  <<<dim3(512,2), dim3(64), 0, stream>>>(ws, w1, b1);
  // Phase C: per-batch  mlp1 (U'*W1p^T -> gelu -> mid)  then  mlp2 (W2*mid^T + b2 + x -> out).
  // mid[28800][512] bf16 (29.5MB) lives in the now-free RA region.
  ushort* mid = (ushort*)(ws+OFF_RA);
  for(int b=0;b<2;b++){
    k_gemm128<256,0><<<dim3(4,225), dim3(256), 0, stream>>>(
        (const ushort*)(ws+OFF_RB) + (size_t)b*NHW*256,     // A = U'[b] px-major [28800][256]
        (const ushort*)(ws+OFF_W1P) + (size_t)b*NHID*256,   // B = W1p[b] [512][256]
        ws+OFF_B1P + b*NHID, nullptr, mid, nullptr);
    k_gemm128<512,1><<<dim3(225,2), dim3(256), 0, stream>>>(
        (const ushort*)(ws+OFF_W2B),                        // A = W2 [256][512]
        mid,                                                // B = mid [28800][512]
        b2, x + (size_t)b*NC*NHW, nullptr, out + (size_t)b*NC*NHW);
  }
}

// Round 5
// 641.026 us; speedup vs baseline: 1.2172x; 1.0045x over previous
//
#include <hip/hip_runtime.h>
#include <hip/hip_bf16.h>

typedef __hip_bfloat16 bf16;
typedef short short8 __attribute__((ext_vector_type(8)));
typedef float f32x4 __attribute__((ext_vector_type(4)));

#define NB 2
#define NC 256
#define NH 120
#define NW 240
#define NHW (NH*NW)      // 28800
#define NSP 16384        // padded spectral pixels per image (128*128)
#define NHID 512
#define NPT 450          // pixel tiles of 64
#define REPS 1e-5f
#define SC_W 0.06454972243679028f   // 1/sqrt(240)
#define SC_H 0.09128709291752769f   // 1/sqrt(120)
#define PI2 6.283185307179586f

__device__ __forceinline__ float gelu_f(float x){ return 0.5f*x*(1.f+erff(x*0.7071067811865476f)); }
__device__ __forceinline__ float us2f(ushort u){ union{float f; uint v;} c; c.v=((uint)u)<<16; return c.f; }
__device__ __forceinline__ ushort f2us(float f){ bf16 b=__float2bfloat16(f); return *(ushort*)&b; }

// async 16B global->LDS (wave-uniform LDS base + lane*16; global addr per-lane)
typedef __attribute__((address_space(3))) void lds_void;
typedef const __attribute__((address_space(1))) void gbl_void;
__device__ __forceinline__ void gload16(const ushort* g, ushort* l){
  __builtin_amdgcn_global_load_lds((gbl_void*)g, (lds_void*)l, 16, 0, 0);
}

// ---- workspace float offsets ----
#define OFF_A0   0
#define OFF_D0   512
#define OFF_A1c  1024
#define OFF_D1c  1536
#define OFF_TWF  2048       // bf16[256][256] fwd-W DFT
#define OFF_THF  34816      // bf16[256][256] fwd-H
#define OFF_THI  67584      // bf16[256][256] inv-H
#define OFF_TWI  100352     // bf16[256][256] inv-W real
#define OFF_WRT  133120     // bf16[256][256] w_spec_r^T [o][i]
#define OFF_WIT  165888     // bf16[256][256] w_spec_i^T
#define OFF_IWB  198656     // bf16[256][256] inner_w [o][i]
#define OFF_W2B  231424     // bf16[256][512]  natural layout
#define OFF_W1P  296960     // bf16[2][512][256]  a1-folded mlp_w1
#define OFF_B1P  428032     // f32[2][512]        folded bias1
#define OFF_PS   429056     // f32[2][450][512]   stats partials (sum | sumsq)
#define OFF_RA   889856     // 8388608 floats ping A
#define OFF_RB   9278464    // 8388608 floats ping B
#define WS_FLOATS 17667072ULL   // 70.7 MB

#define RA0 OFF_RA
#define RA1 (OFF_RA+4194304)
#define RB0 OFF_RB
#define RB1 (OFF_RB+4194304)
#define OFF_FRE RB0
#define OFF_FIM (RB0+3932160)

// ---------------- setup: DFT matrices + weight casts ----------------
__global__ __launch_bounds__(256) void k_setup(float* ws, const float* wsr, const float* wsi,
                                               const float* iw, const float* w2){
  int t = blockIdx.x*256 + threadIdx.x;
  if (t < 65536){ // TWF [n][w]
    int n=t>>8, w=t&255; float v=0.f;
    if(w<NW){
      if(n<121){ v = cosf(PI2*(float)((n*w)%NW)/(float)NW)*SC_W; }
      else if(n>=128 && n<249){ int k=n-128; v = -sinf(PI2*(float)((k*w)%NW)/(float)NW)*SC_W; }
    }
    ((ushort*)(ws+OFF_TWF))[t]=f2us(v); return;
  } t-=65536;
  if (t < 65536){ // THF
    int n=t>>8, j=t&255; float v=0.f;
    int h = j&127; bool im = (j>=128);
    if(h<NH){
      if(n<128){ int m=n; if(m<NH){ float sn,cs; sincosf(PI2*(float)((m*h)%NH)/(float)NH,&sn,&cs);
        v = (im? sn : cs)*SC_H; } }
      else { int m=n-128; if(m<NH){ float sn,cs; sincosf(PI2*(float)((m*h)%NH)/(float)NH,&sn,&cs);
        v = (im? cs : -sn)*SC_H; } }
    }
    ((ushort*)(ws+OFF_THF))[t]=f2us(v); return;
  } t-=65536;
  if (t < 65536){ // THI
    int n=t>>8, j=t&255; float v=0.f;
    int m = j&127; bool im = (j>=128);
    if(m<NH){
      if(n<128){ int h=n; if(h<NH){ float sn,cs; sincosf(PI2*(float)((h*m)%NH)/(float)NH,&sn,&cs);
        v = (im? -sn : cs)*SC_H; } }
      else { int h=n-128; if(h<NH){ float sn,cs; sincosf(PI2*(float)((h*m)%NH)/(float)NH,&sn,&cs);
        v = (im? cs : sn)*SC_H; } }
    }
    ((ushort*)(ws+OFF_THI))[t]=f2us(v); return;
  } t-=65536;
  if (t < 65536){ // TWI
    int w=t>>8, j=t&255; float v=0.f;
    if(w<NW){
      int k = j&127; bool im = (j>=128);
      if(k<121){
        float ck = (k==0||k==120)? 1.f : 2.f;
        float sn,cs; sincosf(PI2*(float)((w*k)%NW)/(float)NW,&sn,&cs);
        v = ck*(im? -sn : cs)*SC_W;
      }
    }
    ((ushort*)(ws+OFF_TWI))[t]=f2us(v); return;
  } t-=65536;
  if (t < 65536){ int o=t>>8,i=t&255; ((ushort*)(ws+OFF_WRT))[t]=f2us(wsr[i*NC+o]); return; } t-=65536;
  if (t < 65536){ int o=t>>8,i=t&255; ((ushort*)(ws+OFF_WIT))[t]=f2us(wsi[i*NC+o]); return; } t-=65536;
  if (t < 65536){ ((ushort*)(ws+OFF_IWB))[t]=f2us(iw[t]); return; } t-=65536;
  if (t < 131072){ ((ushort*)(ws+OFF_W2B))[t]=f2us(w2[t]); return; }
}

// ---------------- instance-norm stats on x ----------------
__global__ __launch_bounds__(256) void k_stats0(const float* x, const float* n0w, const float* n0b, float* ws){
  int g = blockIdx.x, c = g & (NC-1);
  const float4* xp = (const float4*)(x + (size_t)g*NHW);
  float s=0.f, q=0.f;
  for(int i=threadIdx.x;i<NHW/4;i+=256){
    float4 v=xp[i];
    s+=v.x+v.y+v.z+v.w;
    q=fmaf(v.x,v.x,fmaf(v.y,v.y,fmaf(v.z,v.z,fmaf(v.w,v.w,q))));
  }
  __shared__ float ls[4], lq[4];
  #pragma unroll
  for(int o=32;o>0;o>>=1){ s+=__shfl_down(s,o,64); q+=__shfl_down(q,o,64); }
  int lane=threadIdx.x&63, wid=threadIdx.x>>6;
  if(!lane){ ls[wid]=s; lq[wid]=q; }
  __syncthreads();
  if(!threadIdx.x){
    s=ls[0]+ls[1]+ls[2]+ls[3]; q=lq[0]+lq[1]+lq[2]+lq[3];
    float m=s*(1.f/NHW), var=q*(1.f/NHW)-m*m;
    float r=rsqrtf(var+REPS);
    float a=r*n0w[c];
    ws[OFF_A0+g]=a; ws[OFF_D0+g]=fmaf(-m,a,n0b[c]);
  }
}

// ---------------- norm+cast: x -> A1 bf16 [g][120][256] (vectorized, 512 blocks) ----------------
__global__ __launch_bounds__(256) void k_norm(const float* x, float* ws){
  int g = blockIdx.x;
  float a = ws[OFF_A0+g], d = ws[OFF_D0+g];
  const float4* xp = (const float4*)(x + (size_t)g*NHW);
  ushort* dst = ((ushort*)(ws+RA0)) + (size_t)g*30720;
  for(int i=threadIdx.x; i<7200; i+=256){          // 7200 float4 = 120 rows x 60
    float4 v = xp[i];
    int h = i/60, w4 = (i - h*60)*4;
    ushort4 o;
    o.x=f2us(fmaf(a,v.x,d)); o.y=f2us(fmaf(a,v.y,d));
    o.z=f2us(fmaf(a,v.z,d)); o.w=f2us(fmaf(a,v.w,d));
    *(ushort4*)(dst + h*256 + w4) = o;
  }
  for(int i=threadIdx.x; i<480; i+=256){           // zero pad w=240..255
    int h = i>>2, w4 = 240 + (i&3)*4;
    ushort4 z = {0,0,0,0};
    *(ushort4*)(dst + h*256 + w4) = z;
  }
}

// ---------------- spectral GEMM ----------------
template<int SPLIT, int EPI>
__global__ __launch_bounds__(256) void k_sgemm(const ushort* Ap0, const ushort* Ap1, const ushort* Bm,
                                               ushort* O0, ushort* O1, ushort* Ub){
  int nb = blockIdx.x*64, mb = blockIdx.y*256;
  int tid = threadIdx.x, w = tid>>6, l = tid&63, lq = l>>4, lr = l&15;
  const ushort* ar0[4]; const ushort* ar1[4]; const ushort* br[4];
  #pragma unroll
  for(int mt=0;mt<4;mt++){
    size_t r = mb + w*64 + mt*16 + lr;
    ar0[mt] = Ap0 + r*(SPLIT?128:256) + lq*8;
    ar1[mt] = SPLIT ? (Ap1 + r*128 + lq*8) : ar0[mt];
  }
  #pragma unroll
  for(int nt=0;nt<4;nt++) br[nt] = Bm + (size_t)(nb + nt*16 + lr)*256 + lq*8;
  f32x4 acc[4][4] = {};
  #pragma unroll
  for(int kk=0;kk<8;kk++){
    int k = kk*32;
    short8 af[4], bfr[4];
    #pragma unroll
    for(int mt=0;mt<4;mt++){
      const ushort* p = SPLIT ? ((k<128 ? ar0[mt] : ar1[mt]) + (k&127)) : (ar0[mt] + k);
      af[mt] = *(const short8*)p;
    }
    #pragma unroll
    for(int nt=0;nt<4;nt++) bfr[nt] = *(const short8*)(br[nt]+k);
    #pragma unroll
    for(int mt=0;mt<4;mt++)
      #pragma unroll
      for(int nt=0;nt<4;nt++)
        acc[mt][nt] = __builtin_amdgcn_mfma_f32_16x16x32_bf16(af[mt], bfr[nt], acc[mt][nt], 0,0,0);
  }
  #pragma unroll
  for(int mt=0;mt<4;mt++){
    #pragma unroll
    for(int r=0;r<4;r++){
      int m = mb + w*64 + mt*16 + lq*4 + r;
      #pragma unroll
      for(int nt=0;nt<4;nt++){
        int n = nb + nt*16 + lr;
        float v = acc[mt][nt][r];
        if (EPI==0){
          if(n<128) O0[(size_t)m*128+n] = f2us(v);
          else      O1[(size_t)m*128+n-128] = f2us(v);
        } else {
          int g = m>>7, h = m&127;
          if(h<NH && n<NW) Ub[(size_t)g*NHW + (size_t)h*NW + n] = f2us(v);
        }
      }
    }
  }
}

// ---------------- 64x64 bf16 transpose within 128-stride planes ----------------
__global__ __launch_bounds__(256) void k_t64(const ushort* src, ushort* dst, int srows, int sgstr){
  __shared__ ushort lt[64][72];
  int g=blockIdx.z, i0=blockIdx.y*64, p0=blockIdx.x*64;
  int t=threadIdx.x, r=t>>2, q=t&3;
  int row = i0 + r;
  uint4 u0=make_uint4(0,0,0,0), u1=u0;
  if(row < srows){
    const ushort* sp = src + (size_t)g*sgstr + (size_t)row*128 + p0 + q*16;
    u0=*(const uint4*)sp; u1=*(const uint4*)(sp+8);
  }
  *(uint4*)&lt[r][q*16]=u0; *(uint4*)&lt[r][q*16+8]=u1;
  __syncthreads();
  int pr=t>>2, q2=t&3;
  union { ushort s[8]; uint4 u; } o0, o1;
  #pragma unroll
  for(int e=0;e<8;e++){ o0.s[e]=lt[q2*16+e][pr]; o1.s[e]=lt[q2*16+8+e][pr]; }
  ushort* dp = dst + (size_t)g*NSP + (size_t)(p0+pr)*128 + i0 + q2*16;
  *(uint4*)dp = o0.u; *(uint4*)(dp+8) = o1.u;
}

// ---------------- pixel transpose: [b][c:256][NSP] -> [b][NSP][c] ----------------
__global__ __launch_bounds__(256) void k_tP(const ushort* src, ushort* dst){
  __shared__ ushort lt[64][72];
  int b=blockIdx.z, i0=blockIdx.y*64, p0=blockIdx.x*64;
  int t=threadIdx.x, r=t>>2, q=t&3;
  const ushort* sp = src + (size_t)(b*NC+i0+r)*NSP + p0 + q*16;
  uint4 u0=*(const uint4*)sp, u1=*(const uint4*)(sp+8);
  *(uint4*)&lt[r][q*16]=u0; *(uint4*)&lt[r][q*16+8]=u1;
  __syncthreads();
  int pr=t>>2, q2=t&3;
  union { ushort s[8]; uint4 u; } o0, o1;
  #pragma unroll
  for(int e=0;e<8;e++){ o0.s[e]=lt[q2*16+e][pr]; o1.s[e]=lt[q2*16+8+e][pr]; }
  ushort* dp = dst + ((size_t)b*NSP + p0 + pr)*NC + i0 + q2*16;
  *(uint4*)dp = o0.u; *(uint4*)(dp+8) = o1.u;
}

// ---------------- complex spectral mix via MFMA ----------------
__global__ __launch_bounds__(256) void k_mixg(float* ws){
  int b = blockIdx.z, p0 = blockIdx.x*32;
  int tid = threadIdx.x, w = tid>>6, l = tid&63, lq = l>>4, lr = l&15;
  const ushort* Wr = (const ushort*)(ws+OFF_WRT);
  const ushort* Wi = (const ushort*)(ws+OFF_WIT);
  const ushort* Gr = (const ushort*)(ws+RA0) + (size_t)b*NSP*NC;
  const ushort* Gi = (const ushort*)(ws+RA1) + (size_t)b*NSP*NC;
  const ushort *wrr[4], *wir[4], *brr[2], *bir[2];
  #pragma unroll
  for(int mt=0;mt<4;mt++){ size_t ro=(size_t)(w*64+mt*16+lr)*NC+lq*8; wrr[mt]=Wr+ro; wir[mt]=Wi+ro; }
  #pragma unroll
  for(int nt=0;nt<2;nt++){ size_t ro=(size_t)(p0+nt*16+lr)*NC+lq*8; brr[nt]=Gr+ro; bir[nt]=Gi+ro; }
  f32x4 aR[4][2]={}, aI[4][2]={};
  for(int k=0;k<256;k+=32){
    short8 fr[4], fi[4], fin[4], gr[2], gi[2];
    #pragma unroll
    for(int mt=0;mt<4;mt++){
      fr[mt]=*(const short8*)(wrr[mt]+k);
      fi[mt]=*(const short8*)(wir[mt]+k);
      union { short8 s; uint u[4]; } nv; nv.s=fi[mt];
      nv.u[0]^=0x80008000u; nv.u[1]^=0x80008000u; nv.u[2]^=0x80008000u; nv.u[3]^=0x80008000u;
      fin[mt]=nv.s;
    }
    #pragma unroll
    for(int nt=0;nt<2;nt++){ gr[nt]=*(const short8*)(brr[nt]+k); gi[nt]=*(const short8*)(bir[nt]+k); }
    #pragma unroll
    for(int mt=0;mt<4;mt++)
      #pragma unroll
      for(int nt=0;nt<2;nt++){
        aR[mt][nt]=__builtin_amdgcn_mfma_f32_16x16x32_bf16(fr[mt], gr[nt], aR[mt][nt],0,0,0);
        aR[mt][nt]=__builtin_amdgcn_mfma_f32_16x16x32_bf16(fin[mt],gi[nt], aR[mt][nt],0,0,0);
        aI[mt][nt]=__builtin_amdgcn_mfma_f32_16x16x32_bf16(fi[mt], gr[nt], aI[mt][nt],0,0,0);
        aI[mt][nt]=__builtin_amdgcn_mfma_f32_16x16x32_bf16(fr[mt], gi[nt], aI[mt][nt],0,0,0);
      }
  }
  ushort* Yre = (ushort*)(ws+RB0);
  ushort* Yim = (ushort*)(ws+RB1);
  #pragma unroll
  for(int mt=0;mt<4;mt++){
    #pragma unroll
    for(int r=0;r<4;r++){
      int m = w*64 + mt*16 + lq*4 + r;
      #pragma unroll
      for(int nt=0;nt<2;nt++){
        int n = p0 + nt*16 + lr;
        size_t ad = (size_t)(b*NC+m)*NSP + n;
        Yre[ad] = f2us(aR[mt][nt][r]);
        Yim[ad] = f2us(aI[mt][nt][r]);
      }
    }
  }
}

// ---------------- Phase A: fused x-transpose + inner conv + gelu + stats + U' ----------------
// v5: Usp tile prefetched via 8x gload16 into LDS at kernel entry (VGPR-free, coalesced,
// drains under the x-load/GEMM phases) -- replaces 64 latency-exposed scalar HBM loads
// in the gelu phase. 16B-chunk XOR swizzle (slot = jd ^ (row&7)) on staging source and
// gelu read keeps LDS conflicts ~4-way.
__global__ __launch_bounds__(256,2) void k_inner(float* ws, const float* x, const float* ib){
  __shared__ ushort xt[64][264];
  __shared__ ushort us[16384];     // [256 ch][8 chunks][8 ushorts], chunk-swizzled
  int b = blockIdx.z, blk = blockIdx.x, p0 = blk*64;
  int t = threadIdx.x, w = t>>6, l = t&63, lq = l>>4, lr = l&15;
  // async-prefetch Usp[256][p0..p0+63] -> us
  const ushort* Usp = (const ushort*)(ws+OFF_RA);
  #pragma unroll
  for(int i=0;i<8;i++){
    int L = i*256 + t;
    int row = L>>3;
    int jd = (L&7) ^ (row&7);
    gload16(Usp + (size_t)(b*NC + row)*NHW + p0 + jd*8, &us[(i*256 + w*64)*8]);
  }
  // load + transpose x tile -> xt[p][c] bf16
  #pragma unroll 4
  for(int cc=0; cc<16; cc++){
    int c = cc*16 + (t>>4);
    int p4 = (t&15)*4;
    float4 v = *(const float4*)(x + ((size_t)(b*NC+c))*NHW + p0 + p4);
    xt[p4  ][c]=f2us(v.x); xt[p4+1][c]=f2us(v.y);
    xt[p4+2][c]=f2us(v.z); xt[p4+3][c]=f2us(v.w);
  }
  __syncthreads();
  const ushort* W = (const ushort*)(ws+OFF_IWB);
  const ushort* ar[4];
  #pragma unroll
  for(int mt=0;mt<4;mt++) ar[mt] = W + (size_t)(w*64+mt*16+lr)*256 + lq*8;
  f32x4 acc[4][4] = {};
  #pragma unroll
  for(int kk=0;kk<8;kk++){
    int k = kk*32;
    short8 af[4], bfr[4];
    #pragma unroll
    for(int mt=0;mt<4;mt++) af[mt] = *(const short8*)(ar[mt]+k);
    #pragma unroll
    for(int nt=0;nt<4;nt++) bfr[nt] = *(const short8*)&xt[nt*16+lr][k+lq*8];
    #pragma unroll
    for(int mt=0;mt<4;mt++)
      #pragma unroll
      for(int nt=0;nt<4;nt++)
        acc[mt][nt] = __builtin_amdgcn_mfma_f32_16x16x32_bf16(af[mt], bfr[nt], acc[mt][nt], 0,0,0);
  }
  __syncthreads();   // all waves done reading xt; reuse as output transpose buffer
  float* PS = ws + OFF_PS + ((size_t)(b*NPT+blk))*512;
  #pragma unroll
  for(int mt=0;mt<4;mt++){
    #pragma unroll
    for(int r=0;r<4;r++){
      int m = w*64 + mt*16 + lq*4 + r;
      float bb = ib[m];
      int m7 = m&7;
      float ss = 0.f, sq = 0.f;
      #pragma unroll
      for(int nt=0;nt<4;nt++){
        int ncol = nt*16 + lr;
        float uv = us2f(us[m*64 + (((ncol>>3) ^ m7)<<3) + (ncol&7)]);
        float g = gelu_f(acc[mt][nt][r] + bb + uv);
        xt[ncol][m] = f2us(g);
        ss += g; sq = fmaf(g,g,sq);
      }
      #pragma unroll
      for(int ofs=1; ofs<16; ofs<<=1){ ss += __shfl_xor(ss, ofs, 64); sq += __shfl_xor(sq, ofs, 64); }
      if(lr==0){ PS[m] = ss; PS[256+m] = sq; }
    }
  }
  __syncthreads();
  ushort* Up = (ushort*)(ws+OFF_RB);
  #pragma unroll
  for(int pp=0; pp<4; pp++){
    int p = pp*16 + (t>>4);
    int c0 = (t&15)*16;
    uint4 w0 = *(uint4*)&xt[p][c0];
    uint4 w1v = *(uint4*)&xt[p][c0+8];
    ushort* dp = Up + ((size_t)(b*NHW + p0 + p))*256 + c0;
    *(uint4*)dp = w0; *(uint4*)(dp+8) = w1v;
  }
}

// ---------------- stats1: reduce partials -> a1,d1 (FiLM folded) ----------------
__global__ __launch_bounds__(256) void k_stats1p(const float* gamma, const float* beta,
                                                 const float* n1w, const float* n1b, float* ws){
  int g = blockIdx.x, b = g>>8, c = g&255;
  float s=0.f, q=0.f;
  for(int i=threadIdx.x;i<NPT;i+=256){
    const float* P = ws + OFF_PS + ((size_t)(b*NPT+i))*512;
    s += P[c]; q += P[256+c];
  }
  __shared__ float ls[4], lq2[4];
  #pragma unroll
  for(int o=32;o>0;o>>=1){ s+=__shfl_down(s,o,64); q+=__shfl_down(q,o,64); }
  int lane=threadIdx.x&63, wid=threadIdx.x>>6;
  if(!lane){ ls[wid]=s; lq2[wid]=q; }
  __syncthreads();
  if(!threadIdx.x){
    s=ls[0]+ls[1]+ls[2]+ls[3]; q=lq2[0]+lq2[1]+lq2[2]+lq2[3];
    float m=s*(1.f/NHW), var=q*(1.f/NHW)-m*m;
    float r=rsqrtf(var+REPS);
    float gp1 = 1.f + gamma[c];
    float wv = n1w[c];
    ws[OFF_A1c+g] = gp1*wv*r;
    ws[OFF_D1c+g] = gp1*(n1b[c] - m*r*wv) + beta[c];
  }
}

// ---------------- fold a1/d1 into W1: W1'[b]=W1*diag(a1), b1'=W1*d1+b1 ----------------
__global__ __launch_bounds__(64) void k_fold(float* ws, const float* w1, const float* b1){
  int o = blockIdx.x, b = blockIdx.y, t = threadIdx.x;
  float acc = 0.f;
  ushort* W1p = (ushort*)(ws+OFF_W1P);
  #pragma unroll
  for(int ii=0; ii<4; ii++){
    int i = ii*64 + t;
    float wv = w1[o*256+i];
    W1p[((size_t)(b*NHID+o))*256 + i] = f2us(wv * ws[OFF_A1c + b*NC + i]);
    acc = fmaf(wv, ws[OFF_D1c + b*NC + i], acc);
  }
  #pragma unroll
  for(int ofs=32; ofs; ofs>>=1) acc += __shfl_down(acc, ofs, 64);
  if(!t) ws[OFF_B1P + b*NHID + o] = acc + b1[o];
}

// ---------------- Phase C: two staged 128x128-tile GEMMs (m97 structure) ----------------
template<int KD, int EPI>
__global__ __launch_bounds__(256) void k_gemm128(const ushort* __restrict__ A, const ushort* __restrict__ B,
                                                 const float* __restrict__ bias, const float* __restrict__ xres,
                                                 ushort* __restrict__ Obf, float* __restrict__ Ofl){
  __shared__ ushort As[2][4096] __attribute__((aligned(16)));
  __shared__ ushort Bs[2][4096] __attribute__((aligned(16)));
  int t = threadIdx.x, w = t>>6, l = t&63, lq = l>>4, lr = l&15;
  int wr = w>>1, wc = w&1;
  int nb = blockIdx.x*128, mb = blockIdx.y*128;
  const ushort* Ab = A + (size_t)mb*KD;
  const ushort* Bb = B + (size_t)nb*KD;
  int srow = t>>2;
  int scg  = (t&3) ^ ((t>>3)&3);
  size_t so0 = (size_t)srow*KD + scg*8;
  size_t so1 = (size_t)(srow+64)*KD + scg*8;
  int ld0 = w*512, ld1 = 2048 + w*512;
  int swk = (lq ^ ((lr>>1)&3))*8;
  f32x4 acc[4][4] = {};
  gload16(Ab+so0, &As[0][ld0]); gload16(Ab+so1, &As[0][ld1]);
  gload16(Bb+so0, &Bs[0][ld0]); gload16(Bb+so1, &Bs[0][ld1]);
  const int NK = KD/32;
  for(int kt=0; kt<NK; kt++){
    int cur = kt&1;
    __syncthreads();
    if(kt+1 < NK){
      size_t ko = (size_t)(kt+1)*32;
      gload16(Ab+so0+ko, &As[cur^1][ld0]); gload16(Ab+so1+ko, &As[cur^1][ld1]);
      gload16(Bb+so0+ko, &Bs[cur^1][ld0]); gload16(Bb+so1+ko, &Bs[cur^1][ld1]);
    }
    short8 af[4], bfr[4];
    #pragma unroll
    for(int mt=0;mt<4;mt++) af[mt]  = *(const short8*)&As[cur][(wr*64+mt*16+lr)*32 + swk];
    #pragma unroll
    for(int nt=0;nt<4;nt++) bfr[nt] = *(const short8*)&Bs[cur][(wc*64+nt*16+lr)*32 + swk];
    #pragma unroll
    for(int mt=0;mt<4;mt++)
      #pragma unroll
      for(int nt=0;nt<4;nt++)
        acc[mt][nt] = __builtin_amdgcn_mfma_f32_16x16x32_bf16(af[mt], bfr[nt], acc[mt][nt], 0,0,0);
  }
  if (EPI==0){
    #pragma unroll
    for(int nt=0;nt<4;nt++){
      int n = nb + wc*64 + nt*16 + lr;
      float bb = bias[n];
      #pragma unroll
      for(int mt=0;mt<4;mt++)
        #pragma unroll
        for(int r=0;r<4;r++){
          int m = mb + wr*64 + mt*16 + lq*4 + r;
          Obf[(size_t)m*NHID + n] = f2us(gelu_f(acc[mt][nt][r] + bb));
        }
    }
  } else {
    #pragma unroll
    for(int mt=0;mt<4;mt++)
      #pragma unroll
      for(int r=0;r<4;r++){
        int m = mb + wr*64 + mt*16 + lq*4 + r;
        float bb = bias[m];
        #pragma unroll
        for(int nt=0;nt<4;nt++){
          int n = nb + wc*64 + nt*16 + lr;
          size_t ad = (size_t)m*NHW + n;
          Ofl[ad] = acc[mt][nt][r] + bb + xres[ad];
        }
      }
  }
}

extern "C" void kernel_launch(void* const* d_in, const int* in_sizes, int n_in,
                              void* d_out, int out_size, void* d_ws, size_t ws_size,
                              hipStream_t stream) {
  const float* x     = (const float*)d_in[0];
  const float* gamma = (const float*)d_in[1];
  const float* beta  = (const float*)d_in[2];
  const float* n0w   = (const float*)d_in[3];
  const float* n0b   = (const float*)d_in[4];
  const float* n1w   = (const float*)d_in[5];
  const float* n1b   = (const float*)d_in[6];
  const float* wsr   = (const float*)d_in[7];
  const float* wsi   = (const float*)d_in[8];
  const float* iw    = (const float*)d_in[9];
  const float* ib    = (const float*)d_in[10];
  const float* w1    = (const float*)d_in[11];
  const float* b1    = (const float*)d_in[12];
  const float* w2    = (const float*)d_in[13];
  const float* b2    = (const float*)d_in[14];
  float* ws = (float*)d_ws;
  float* out = (float*)d_out;
  if (ws_size < WS_FLOATS*4ULL) return;

  k_setup <<<dim3(2304), dim3(256), 0, stream>>>(ws, wsr, wsi, iw, w2);
  k_stats0<<<dim3(512),  dim3(256), 0, stream>>>(x, n0w, n0b, ws);
  k_norm  <<<dim3(512), dim3(256), 0, stream>>>(x, ws);
  // GEMM1: A1(RA) -> F(RB planes)
  k_sgemm<0,0><<<dim3(4,240), dim3(256), 0, stream>>>((const ushort*)(ws+RA0), (const ushort*)(ws+RA0),
      (const ushort*)(ws+OFF_TWF), (ushort*)(ws+OFF_FRE), (ushort*)(ws+OFF_FIM), nullptr);
  // T1: F(RB) -> Ft(RA)
  k_t64 <<<dim3(2,2,512), dim3(256), 0, stream>>>((const ushort*)(ws+OFF_FRE), (ushort*)(ws+RA0), NH, NH*128);
  k_t64 <<<dim3(2,2,512), dim3(256), 0, stream>>>((const ushort*)(ws+OFF_FIM), (ushort*)(ws+RA1), NH, NH*128);
  // GEMM2: Ft(RA) -> G(RB)
  k_sgemm<1,0><<<dim3(4,256), dim3(256), 0, stream>>>((const ushort*)(ws+RA0), (const ushort*)(ws+RA1),
      (const ushort*)(ws+OFF_THF), (ushort*)(ws+RB0), (ushort*)(ws+RB1), nullptr);
  // T2: G(RB) -> Gt(RA) [b][p][c]
  k_tP <<<dim3(256,4,2), dim3(256), 0, stream>>>((const ushort*)(ws+RB0), (ushort*)(ws+RA0));
  k_tP <<<dim3(256,4,2), dim3(256), 0, stream>>>((const ushort*)(ws+RB1), (ushort*)(ws+RA1));
  // mix: Gt(RA) -> Y(RB)
  k_mixg <<<dim3(512,1,2), dim3(256), 0, stream>>>(ws);
  // GEMM4: Y(RB) -> Z(RA)
  k_sgemm<1,0><<<dim3(4,256), dim3(256), 0, stream>>>((const ushort*)(ws+RB0), (const ushort*)(ws+RB1),
      (const ushort*)(ws+OFF_THI), (ushort*)(ws+RA0), (ushort*)(ws+RA1), nullptr);
  // T3: Z(RA) -> Zt(RB)
  k_t64 <<<dim3(2,2,512), dim3(256), 0, stream>>>((const ushort*)(ws+RA0), (ushort*)(ws+RB0), 128, NSP);
  k_t64 <<<dim3(2,2,512), dim3(256), 0, stream>>>((const ushort*)(ws+RA1), (ushort*)(ws+RB1), 128, NSP);
  // GEMM5: Zt(RB) -> U spectral bf16 channel-major (RA)
  k_sgemm<1,1><<<dim3(4,256), dim3(256), 0, stream>>>((const ushort*)(ws+RB0), (const ushort*)(ws+RB1),
      (const ushort*)(ws+OFF_TWI), nullptr, nullptr, (ushort*)(ws+RA0));
  // Phase A: inner conv fused (x + Usp -> U' pixel-major bf16 in RB, + stats partials)
  k_inner <<<dim3(NPT,1,2), dim3(256), 0, stream>>>(ws, x, ib);
  k_stats1p<<<dim3(512), dim3(256), 0, stream>>>(gamma, beta, n1w, n1b, ws);
  k_fold  <<<dim3(512,2), dim3(64), 0, stream>>>(ws, w1, b1);
  // Phase C: per-batch  mlp1 (U'*W1p^T -> gelu -> mid)  then  mlp2 (W2*mid^T + b2 + x -> out).
  ushort* mid = (ushort*)(ws+OFF_RA);
  for(int b=0;b<2;b++){
    k_gemm128<256,0><<<dim3(4,225), dim3(256), 0, stream>>>(
        (const ushort*)(ws+OFF_RB) + (size_t)b*NHW*256,
        (const ushort*)(ws+OFF_W1P) + (size_t)b*NHID*256,
        ws+OFF_B1P + b*NHID, nullptr, mid, nullptr);
    k_gemm128<512,1><<<dim3(225,2), dim3(256), 0, stream>>>(
        (const ushort*)(ws+OFF_W2B),
        mid,
        b2, x + (size_t)b*NC*NHW, nullptr, out + (size_t)b*NC*NHW);
  }
}

// Round 6
// 636.434 us; speedup vs baseline: 1.2260x; 1.0072x over previous
//
#include <hip/hip_runtime.h>
#include <hip/hip_bf16.h>

typedef __hip_bfloat16 bf16;
typedef short short8 __attribute__((ext_vector_type(8)));
typedef float f32x4 __attribute__((ext_vector_type(4)));

#define NB 2
#define NC 256
#define NH 120
#define NW 240
#define NHW (NH*NW)      // 28800
#define NSP 16384        // padded spectral pixels per image (128*128)
#define NHID 512
#define NPT 450          // pixel tiles of 64
#define REPS 1e-5f
#define SC_W 0.06454972243679028f   // 1/sqrt(240)
#define SC_H 0.09128709291752769f   // 1/sqrt(120)
#define PI2 6.283185307179586f

__device__ __forceinline__ float gelu_f(float x){ return 0.5f*x*(1.f+erff(x*0.7071067811865476f)); }
__device__ __forceinline__ float us2f(ushort u){ union{float f; uint v;} c; c.v=((uint)u)<<16; return c.f; }
__device__ __forceinline__ ushort f2us(float f){ bf16 b=__float2bfloat16(f); return *(ushort*)&b; }

// async 16B global->LDS (wave-uniform LDS base + lane*16; global addr per-lane)
typedef __attribute__((address_space(3))) void lds_void;
typedef const __attribute__((address_space(1))) void gbl_void;
__device__ __forceinline__ void gload16(const ushort* g, ushort* l){
  __builtin_amdgcn_global_load_lds((gbl_void*)g, (lds_void*)l, 16, 0, 0);
}

// ---- workspace float offsets ----
#define OFF_A0   0
#define OFF_D0   512
#define OFF_A1c  1024
#define OFF_D1c  1536
#define OFF_TWF  2048       // bf16[256][256] fwd-W DFT
#define OFF_THF  34816      // bf16[256][256] fwd-H
#define OFF_THI  67584      // bf16[256][256] inv-H
#define OFF_TWI  100352     // bf16[256][256] inv-W real
#define OFF_WRT  133120     // bf16[256][256] w_spec_r^T [o][i]
#define OFF_WIT  165888     // bf16[256][256] w_spec_i^T
#define OFF_IWB  198656     // bf16[256][256] inner_w [o][i]
#define OFF_W2B  231424     // bf16[256][512]  natural layout
#define OFF_W1P  296960     // bf16[2][512][256]  a1-folded mlp_w1
#define OFF_B1P  428032     // f32[2][512]        folded bias1
#define OFF_PS   429056     // f32[2][450][512]   stats partials (sum | sumsq)
#define OFF_RA   889856     // 8388608 floats ping A
#define OFF_RB   9278464    // 8388608 floats ping B
#define WS_FLOATS 17667072ULL   // 70.7 MB

#define RA0 OFF_RA
#define RA1 (OFF_RA+4194304)
#define RB0 OFF_RB
#define RB1 (OFF_RB+4194304)
#define OFF_FRE RB0
#define OFF_FIM (RB0+3932160)

// ---------------- setup: DFT matrices + weight casts ----------------
__global__ __launch_bounds__(256) void k_setup(float* ws, const float* wsr, const float* wsi,
                                               const float* iw, const float* w2){
  int t = blockIdx.x*256 + threadIdx.x;
  if (t < 65536){ // TWF [n][w]
    int n=t>>8, w=t&255; float v=0.f;
    if(w<NW){
      if(n<121){ v = cosf(PI2*(float)((n*w)%NW)/(float)NW)*SC_W; }
      else if(n>=128 && n<249){ int k=n-128; v = -sinf(PI2*(float)((k*w)%NW)/(float)NW)*SC_W; }
    }
    ((ushort*)(ws+OFF_TWF))[t]=f2us(v); return;
  } t-=65536;
  if (t < 65536){ // THF
    int n=t>>8, j=t&255; float v=0.f;
    int h = j&127; bool im = (j>=128);
    if(h<NH){
      if(n<128){ int m=n; if(m<NH){ float sn,cs; sincosf(PI2*(float)((m*h)%NH)/(float)NH,&sn,&cs);
        v = (im? sn : cs)*SC_H; } }
      else { int m=n-128; if(m<NH){ float sn,cs; sincosf(PI2*(float)((m*h)%NH)/(float)NH,&sn,&cs);
        v = (im? cs : -sn)*SC_H; } }
    }
    ((ushort*)(ws+OFF_THF))[t]=f2us(v); return;
  } t-=65536;
  if (t < 65536){ // THI
    int n=t>>8, j=t&255; float v=0.f;
    int m = j&127; bool im = (j>=128);
    if(m<NH){
      if(n<128){ int h=n; if(h<NH){ float sn,cs; sincosf(PI2*(float)((h*m)%NH)/(float)NH,&sn,&cs);
        v = (im? -sn : cs)*SC_H; } }
      else { int h=n-128; if(h<NH){ float sn,cs; sincosf(PI2*(float)((h*m)%NH)/(float)NH,&sn,&cs);
        v = (im? cs : sn)*SC_H; } }
    }
    ((ushort*)(ws+OFF_THI))[t]=f2us(v); return;
  } t-=65536;
  if (t < 65536){ // TWI
    int w=t>>8, j=t&255; float v=0.f;
    if(w<NW){
      int k = j&127; bool im = (j>=128);
      if(k<121){
        float ck = (k==0||k==120)? 1.f : 2.f;
        float sn,cs; sincosf(PI2*(float)((w*k)%NW)/(float)NW,&sn,&cs);
        v = ck*(im? -sn : cs)*SC_W;
      }
    }
    ((ushort*)(ws+OFF_TWI))[t]=f2us(v); return;
  } t-=65536;
  if (t < 65536){ int o=t>>8,i=t&255; ((ushort*)(ws+OFF_WRT))[t]=f2us(wsr[i*NC+o]); return; } t-=65536;
  if (t < 65536){ int o=t>>8,i=t&255; ((ushort*)(ws+OFF_WIT))[t]=f2us(wsi[i*NC+o]); return; } t-=65536;
  if (t < 65536){ ((ushort*)(ws+OFF_IWB))[t]=f2us(iw[t]); return; } t-=65536;
  if (t < 131072){ ((ushort*)(ws+OFF_W2B))[t]=f2us(w2[t]); return; }
}

// ---------------- instance-norm stats on x ----------------
__global__ __launch_bounds__(256) void k_stats0(const float* x, const float* n0w, const float* n0b, float* ws){
  int g = blockIdx.x, c = g & (NC-1);
  const float4* xp = (const float4*)(x + (size_t)g*NHW);
  float s=0.f, q=0.f;
  for(int i=threadIdx.x;i<NHW/4;i+=256){
    float4 v=xp[i];
    s+=v.x+v.y+v.z+v.w;
    q=fmaf(v.x,v.x,fmaf(v.y,v.y,fmaf(v.z,v.z,fmaf(v.w,v.w,q))));
  }
  __shared__ float ls[4], lq[4];
  #pragma unroll
  for(int o=32;o>0;o>>=1){ s+=__shfl_down(s,o,64); q+=__shfl_down(q,o,64); }
  int lane=threadIdx.x&63, wid=threadIdx.x>>6;
  if(!lane){ ls[wid]=s; lq[wid]=q; }
  __syncthreads();
  if(!threadIdx.x){
    s=ls[0]+ls[1]+ls[2]+ls[3]; q=lq[0]+lq[1]+lq[2]+lq[3];
    float m=s*(1.f/NHW), var=q*(1.f/NHW)-m*m;
    float r=rsqrtf(var+REPS);
    float a=r*n0w[c];
    ws[OFF_A0+g]=a; ws[OFF_D0+g]=fmaf(-m,a,n0b[c]);
  }
}

// ---------------- norm+cast: x -> A1 bf16 [g][120][256] (vectorized, 512 blocks) ----------------
__global__ __launch_bounds__(256) void k_norm(const float* x, float* ws){
  int g = blockIdx.x;
  float a = ws[OFF_A0+g], d = ws[OFF_D0+g];
  const float4* xp = (const float4*)(x + (size_t)g*NHW);
  ushort* dst = ((ushort*)(ws+RA0)) + (size_t)g*30720;
  for(int i=threadIdx.x; i<7200; i+=256){          // 7200 float4 = 120 rows x 60
    float4 v = xp[i];
    int h = i/60, w4 = (i - h*60)*4;
    ushort4 o;
    o.x=f2us(fmaf(a,v.x,d)); o.y=f2us(fmaf(a,v.y,d));
    o.z=f2us(fmaf(a,v.z,d)); o.w=f2us(fmaf(a,v.w,d));
    *(ushort4*)(dst + h*256 + w4) = o;
  }
  for(int i=threadIdx.x; i<480; i+=256){           // zero pad w=240..255
    int h = i>>2, w4 = 240 + (i&3)*4;
    ushort4 z = {0,0,0,0};
    *(ushort4*)(dst + h*256 + w4) = z;
  }
}

// ---------------- x transpose: f32 [b][c][px] -> bf16 [b][px][c]  (k_tP pattern) ----------------
__global__ __launch_bounds__(256) void k_tX(const float* x, ushort* xT){
  __shared__ ushort lt[64][72];
  int b=blockIdx.z, c0=blockIdx.y*64, p0=blockIdx.x*64;
  int t=threadIdx.x;
  int cr=t>>4, p4=(t&15)*4;
  #pragma unroll
  for(int i=0;i<4;i++){
    int c = i*16 + cr;
    float4 v = *(const float4*)(x + ((size_t)(b*NC + c0 + c))*NHW + p0 + p4);
    ushort4 o; o.x=f2us(v.x); o.y=f2us(v.y); o.z=f2us(v.z); o.w=f2us(v.w);
    *(ushort4*)&lt[c][p4] = o;
  }
  __syncthreads();
  int pr=t>>2, q2=t&3;
  union { ushort s[8]; uint4 u; } o0, o1;
  #pragma unroll
  for(int e=0;e<8;e++){ o0.s[e]=lt[q2*16+e][pr]; o1.s[e]=lt[q2*16+8+e][pr]; }
  ushort* dp = xT + ((size_t)(b*NHW) + p0 + pr)*256 + c0 + q2*16;
  *(uint4*)dp = o0.u; *(uint4*)(dp+8) = o1.u;
}

// ---------------- spectral GEMM ----------------
template<int SPLIT, int EPI>
__global__ __launch_bounds__(256) void k_sgemm(const ushort* Ap0, const ushort* Ap1, const ushort* Bm,
                                               ushort* O0, ushort* O1, ushort* Ub){
  int nb = blockIdx.x*64, mb = blockIdx.y*256;
  int tid = threadIdx.x, w = tid>>6, l = tid&63, lq = l>>4, lr = l&15;
  const ushort* ar0[4]; const ushort* ar1[4]; const ushort* br[4];
  #pragma unroll
  for(int mt=0;mt<4;mt++){
    size_t r = mb + w*64 + mt*16 + lr;
    ar0[mt] = Ap0 + r*(SPLIT?128:256) + lq*8;
    ar1[mt] = SPLIT ? (Ap1 + r*128 + lq*8) : ar0[mt];
  }
  #pragma unroll
  for(int nt=0;nt<4;nt++) br[nt] = Bm + (size_t)(nb + nt*16 + lr)*256 + lq*8;
  f32x4 acc[4][4] = {};
  #pragma unroll
  for(int kk=0;kk<8;kk++){
    int k = kk*32;
    short8 af[4], bfr[4];
    #pragma unroll
    for(int mt=0;mt<4;mt++){
      const ushort* p = SPLIT ? ((k<128 ? ar0[mt] : ar1[mt]) + (k&127)) : (ar0[mt] + k);
      af[mt] = *(const short8*)p;
    }
    #pragma unroll
    for(int nt=0;nt<4;nt++) bfr[nt] = *(const short8*)(br[nt]+k);
    #pragma unroll
    for(int mt=0;mt<4;mt++)
      #pragma unroll
      for(int nt=0;nt<4;nt++)
        acc[mt][nt] = __builtin_amdgcn_mfma_f32_16x16x32_bf16(af[mt], bfr[nt], acc[mt][nt], 0,0,0);
  }
  #pragma unroll
  for(int mt=0;mt<4;mt++){
    #pragma unroll
    for(int r=0;r<4;r++){
      int m = mb + w*64 + mt*16 + lq*4 + r;
      #pragma unroll
      for(int nt=0;nt<4;nt++){
        int n = nb + nt*16 + lr;
        float v = acc[mt][nt][r];
        if (EPI==0){
          if(n<128) O0[(size_t)m*128+n] = f2us(v);
          else      O1[(size_t)m*128+n-128] = f2us(v);
        } else {
          int g = m>>7, h = m&127;
          if(h<NH && n<NW) Ub[(size_t)g*NHW + (size_t)h*NW + n] = f2us(v);
        }
      }
    }
  }
}

// ---------------- 64x64 bf16 transpose within 128-stride planes ----------------
__global__ __launch_bounds__(256) void k_t64(const ushort* src, ushort* dst, int srows, int sgstr){
  __shared__ ushort lt[64][72];
  int g=blockIdx.z, i0=blockIdx.y*64, p0=blockIdx.x*64;
  int t=threadIdx.x, r=t>>2, q=t&3;
  int row = i0 + r;
  uint4 u0=make_uint4(0,0,0,0), u1=u0;
  if(row < srows){
    const ushort* sp = src + (size_t)g*sgstr + (size_t)row*128 + p0 + q*16;
    u0=*(const uint4*)sp; u1=*(const uint4*)(sp+8);
  }
  *(uint4*)&lt[r][q*16]=u0; *(uint4*)&lt[r][q*16+8]=u1;
  __syncthreads();
  int pr=t>>2, q2=t&3;
  union { ushort s[8]; uint4 u; } o0, o1;
  #pragma unroll
  for(int e=0;e<8;e++){ o0.s[e]=lt[q2*16+e][pr]; o1.s[e]=lt[q2*16+8+e][pr]; }
  ushort* dp = dst + (size_t)g*NSP + (size_t)(p0+pr)*128 + i0 + q2*16;
  *(uint4*)dp = o0.u; *(uint4*)(dp+8) = o1.u;
}

// ---------------- pixel transpose: [b][c:256][NSP] -> [b][NSP][c] ----------------
__global__ __launch_bounds__(256) void k_tP(const ushort* src, ushort* dst){
  __shared__ ushort lt[64][72];
  int b=blockIdx.z, i0=blockIdx.y*64, p0=blockIdx.x*64;
  int t=threadIdx.x, r=t>>2, q=t&3;
  const ushort* sp = src + (size_t)(b*NC+i0+r)*NSP + p0 + q*16;
  uint4 u0=*(const uint4*)sp, u1=*(const uint4*)(sp+8);
  *(uint4*)&lt[r][q*16]=u0; *(uint4*)&lt[r][q*16+8]=u1;
  __syncthreads();
  int pr=t>>2, q2=t&3;
  union { ushort s[8]; uint4 u; } o0, o1;
  #pragma unroll
  for(int e=0;e<8;e++){ o0.s[e]=lt[q2*16+e][pr]; o1.s[e]=lt[q2*16+8+e][pr]; }
  ushort* dp = dst + ((size_t)b*NSP + p0 + pr)*NC + i0 + q2*16;
  *(uint4*)dp = o0.u; *(uint4*)(dp+8) = o1.u;
}

// ---------------- complex spectral mix via MFMA ----------------
__global__ __launch_bounds__(256) void k_mixg(float* ws){
  int b = blockIdx.z, p0 = blockIdx.x*32;
  int tid = threadIdx.x, w = tid>>6, l = tid&63, lq = l>>4, lr = l&15;
  const ushort* Wr = (const ushort*)(ws+OFF_WRT);
  const ushort* Wi = (const ushort*)(ws+OFF_WIT);
  const ushort* Gr = (const ushort*)(ws+RA0) + (size_t)b*NSP*NC;
  const ushort* Gi = (const ushort*)(ws+RA1) + (size_t)b*NSP*NC;
  const ushort *wrr[4], *wir[4], *brr[2], *bir[2];
  #pragma unroll
  for(int mt=0;mt<4;mt++){ size_t ro=(size_t)(w*64+mt*16+lr)*NC+lq*8; wrr[mt]=Wr+ro; wir[mt]=Wi+ro; }
  #pragma unroll
  for(int nt=0;nt<2;nt++){ size_t ro=(size_t)(p0+nt*16+lr)*NC+lq*8; brr[nt]=Gr+ro; bir[nt]=Gi+ro; }
  f32x4 aR[4][2]={}, aI[4][2]={};
  for(int k=0;k<256;k+=32){
    short8 fr[4], fi[4], fin[4], gr[2], gi[2];
    #pragma unroll
    for(int mt=0;mt<4;mt++){
      fr[mt]=*(const short8*)(wrr[mt]+k);
      fi[mt]=*(const short8*)(wir[mt]+k);
      union { short8 s; uint u[4]; } nv; nv.s=fi[mt];
      nv.u[0]^=0x80008000u; nv.u[1]^=0x80008000u; nv.u[2]^=0x80008000u; nv.u[3]^=0x80008000u;
      fin[mt]=nv.s;
    }
    #pragma unroll
    for(int nt=0;nt<2;nt++){ gr[nt]=*(const short8*)(brr[nt]+k); gi[nt]=*(const short8*)(bir[nt]+k); }
    #pragma unroll
    for(int mt=0;mt<4;mt++)
      #pragma unroll
      for(int nt=0;nt<2;nt++){
        aR[mt][nt]=__builtin_amdgcn_mfma_f32_16x16x32_bf16(fr[mt], gr[nt], aR[mt][nt],0,0,0);
        aR[mt][nt]=__builtin_amdgcn_mfma_f32_16x16x32_bf16(fin[mt],gi[nt], aR[mt][nt],0,0,0);
        aI[mt][nt]=__builtin_amdgcn_mfma_f32_16x16x32_bf16(fi[mt], gr[nt], aI[mt][nt],0,0,0);
        aI[mt][nt]=__builtin_amdgcn_mfma_f32_16x16x32_bf16(fr[mt], gi[nt], aI[mt][nt],0,0,0);
      }
  }
  ushort* Yre = (ushort*)(ws+RB0);
  ushort* Yim = (ushort*)(ws+RB1);
  #pragma unroll
  for(int mt=0;mt<4;mt++){
    #pragma unroll
    for(int r=0;r<4;r++){
      int m = w*64 + mt*16 + lq*4 + r;
      #pragma unroll
      for(int nt=0;nt<2;nt++){
        int n = p0 + nt*16 + lr;
        size_t ad = (size_t)(b*NC+m)*NSP + n;
        Yre[ad] = f2us(aR[mt][nt][r]);
        Yim[ad] = f2us(aI[mt][nt][r]);
      }
    }
  }
}

// ---------------- Phase A: fused inner conv + gelu + stats + U' (v6: all-async staging) ----------------
// x arrives pre-transposed (k_tX: bf16 [b][px][256] in d_out scratch) -> staged via gload16,
// chunk-swizzled (phys j = jl ^ (px&7)); B-frag reads / gelu writes / Up reads apply the same XOR.
// Removes the in-kernel x-transpose (16 f32 loads + 64 f2us + 64 8-way-conflict LDS writes /thread).
__global__ __launch_bounds__(256,2) void k_inner(float* ws, const ushort* xT, const float* ib){
  __shared__ ushort xtl[16384];   // [64 px][32 chunks][8]
  __shared__ ushort us[16384];    // [256 ch][8 chunks][8]
  int b = blockIdx.z, blk = blockIdx.x, p0 = blk*64;
  int t = threadIdx.x, w = t>>6, l = t&63, lq = l>>4, lr = l&15;
  // async-stage x^T tile -> xtl
  #pragma unroll
  for(int i=0;i<8;i++){
    int L = i*256 + t;
    int px = L>>5, j = L&31;
    gload16(xT + ((size_t)(b*NHW) + p0 + px)*256 + ((j ^ (px&7))<<3), &xtl[(i*256 + w*64)*8]);
  }
  // async-stage Usp tile -> us
  const ushort* Usp = (const ushort*)(ws+OFF_RA);
  #pragma unroll
  for(int i=0;i<8;i++){
    int L = i*256 + t;
    int row = L>>3;
    int jd = (L&7) ^ (row&7);
    gload16(Usp + (size_t)(b*NC + row)*NHW + p0 + jd*8, &us[(i*256 + w*64)*8]);
  }
  __syncthreads();
  const ushort* W = (const ushort*)(ws+OFF_IWB);
  const ushort* ar[4];
  #pragma unroll
  for(int mt=0;mt<4;mt++) ar[mt] = W + (size_t)(w*64+mt*16+lr)*256 + lq*8;
  f32x4 acc[4][4] = {};
  #pragma unroll
  for(int kk=0;kk<8;kk++){
    short8 af[4], bfr[4];
    #pragma unroll
    for(int mt=0;mt<4;mt++) af[mt] = *(const short8*)(ar[mt]+kk*32);
    #pragma unroll
    for(int nt=0;nt<4;nt++){
      int px = nt*16 + lr;
      bfr[nt] = *(const short8*)&xtl[px*256 + (((kk*4+lq) ^ (px&7))<<3)];
    }
    #pragma unroll
    for(int mt=0;mt<4;mt++)
      #pragma unroll
      for(int nt=0;nt<4;nt++)
        acc[mt][nt] = __builtin_amdgcn_mfma_f32_16x16x32_bf16(af[mt], bfr[nt], acc[mt][nt], 0,0,0);
  }
  __syncthreads();   // xtl reads done; reuse as swizzled U' transpose buffer
  float* PS = ws + OFF_PS + ((size_t)(b*NPT+blk))*512;
  #pragma unroll
  for(int mt=0;mt<4;mt++){
    #pragma unroll
    for(int r=0;r<4;r++){
      int m = w*64 + mt*16 + lq*4 + r;
      float bb = ib[m];
      int m7 = m&7, mc = m>>3, mo = m&7;
      float ss = 0.f, sq = 0.f;
      #pragma unroll
      for(int nt=0;nt<4;nt++){
        int ncol = nt*16 + lr;
        float uv = us2f(us[m*64 + (((ncol>>3) ^ m7)<<3) + (ncol&7)]);
        float g = gelu_f(acc[mt][nt][r] + bb + uv);
        xtl[ncol*256 + ((mc ^ (ncol&7))<<3) + mo] = f2us(g);
        ss += g; sq = fmaf(g,g,sq);
      }
      #pragma unroll
      for(int ofs=1; ofs<16; ofs<<=1){ ss += __shfl_xor(ss, ofs, 64); sq += __shfl_xor(sq, ofs, 64); }
      if(lr==0){ PS[m] = ss; PS[256+m] = sq; }
    }
  }
  __syncthreads();
  ushort* Up = (ushort*)(ws+OFF_RB);
  #pragma unroll
  for(int pp=0; pp<4; pp++){
    int p = pp*16 + (t>>4);
    int s = p&7;
    int j0 = (t&15)*2;
    uint4 w0  = *(uint4*)&xtl[p*256 + ((j0 ^ s)<<3)];
    uint4 w1v = *(uint4*)&xtl[p*256 + (((j0+1) ^ s)<<3)];
    ushort* dp = Up + ((size_t)(b*NHW + p0 + p))*256 + j0*8;
    *(uint4*)dp = w0; *(uint4*)(dp+8) = w1v;
  }
}

// ---------------- stats1: reduce partials -> a1,d1 (FiLM folded) ----------------
__global__ __launch_bounds__(256) void k_stats1p(const float* gamma, const float* beta,
                                                 const float* n1w, const float* n1b, float* ws){
  int g = blockIdx.x, b = g>>8, c = g&255;
  float s=0.f, q=0.f;
  for(int i=threadIdx.x;i<NPT;i+=256){
    const float* P = ws + OFF_PS + ((size_t)(b*NPT+i))*512;
    s += P[c]; q += P[256+c];
  }
  __shared__ float ls[4], lq2[4];
  #pragma unroll
  for(int o=32;o>0;o>>=1){ s+=__shfl_down(s,o,64); q+=__shfl_down(q,o,64); }
  int lane=threadIdx.x&63, wid=threadIdx.x>>6;
  if(!lane){ ls[wid]=s; lq2[wid]=q; }
  __syncthreads();
  if(!threadIdx.x){
    s=ls[0]+ls[1]+ls[2]+ls[3]; q=lq2[0]+lq2[1]+lq2[2]+lq2[3];
    float m=s*(1.f/NHW), var=q*(1.f/NHW)-m*m;
    float r=rsqrtf(var+REPS);
    float gp1 = 1.f + gamma[c];
    float wv = n1w[c];
    ws[OFF_A1c+g] = gp1*wv*r;
    ws[OFF_D1c+g] = gp1*(n1b[c] - m*r*wv) + beta[c];
  }
}

// ---------------- fold a1/d1 into W1: W1'[b]=W1*diag(a1), b1'=W1*d1+b1 ----------------
__global__ __launch_bounds__(64) void k_fold(float* ws, const float* w1, const float* b1){
  int o = blockIdx.x, b = blockIdx.y, t = threadIdx.x;
  float acc = 0.f;
  ushort* W1p = (ushort*)(ws+OFF_W1P);
  #pragma unroll
  for(int ii=0; ii<4; ii++){
    int i = ii*64 + t;
    float wv = w1[o*256+i];
    W1p[((size_t)(b*NHID+o))*256 + i] = f2us(wv * ws[OFF_A1c + b*NC + i]);
    acc = fmaf(wv, ws[OFF_D1c + b*NC + i], acc);
  }
  #pragma unroll
  for(int ofs=32; ofs; ofs>>=1) acc += __shfl_down(acc, ofs, 64);
  if(!t) ws[OFF_B1P + b*NHID + o] = acc + b1[o];
}

// ---------------- Phase C: two staged 128x128-tile GEMMs (m97 structure) ----------------
template<int KD, int EPI>
__global__ __launch_bounds__(256) void k_gemm128(const ushort* __restrict__ A, const ushort* __restrict__ B,
                                                 const float* __restrict__ bias, const float* __restrict__ xres,
                                                 ushort* __restrict__ Obf, float* __restrict__ Ofl){
  __shared__ ushort As[2][4096] __attribute__((aligned(16)));
  __shared__ ushort Bs[2][4096] __attribute__((aligned(16)));
  int t = threadIdx.x, w = t>>6, l = t&63, lq = l>>4, lr = l&15;
  int wr = w>>1, wc = w&1;
  int nb = blockIdx.x*128, mb = blockIdx.y*128;
  const ushort* Ab = A + (size_t)mb*KD;
  const ushort* Bb = B + (size_t)nb*KD;
  int srow = t>>2;
  int scg  = (t&3) ^ ((t>>3)&3);
  size_t so0 = (size_t)srow*KD + scg*8;
  size_t so1 = (size_t)(srow+64)*KD + scg*8;
  int ld0 = w*512, ld1 = 2048 + w*512;
  int swk = (lq ^ ((lr>>1)&3))*8;
  f32x4 acc[4][4] = {};
  gload16(Ab+so0, &As[0][ld0]); gload16(Ab+so1, &As[0][ld1]);
  gload16(Bb+so0, &Bs[0][ld0]); gload16(Bb+so1, &Bs[0][ld1]);
  const int NK = KD/32;
  for(int kt=0; kt<NK; kt++){
    int cur = kt&1;
    __syncthreads();
    if(kt+1 < NK){
      size_t ko = (size_t)(kt+1)*32;
      gload16(Ab+so0+ko, &As[cur^1][ld0]); gload16(Ab+so1+ko, &As[cur^1][ld1]);
      gload16(Bb+so0+ko, &Bs[cur^1][ld0]); gload16(Bb+so1+ko, &Bs[cur^1][ld1]);
    }
    short8 af[4], bfr[4];
    #pragma unroll
    for(int mt=0;mt<4;mt++) af[mt]  = *(const short8*)&As[cur][(wr*64+mt*16+lr)*32 + swk];
    #pragma unroll
    for(int nt=0;nt<4;nt++) bfr[nt] = *(const short8*)&Bs[cur][(wc*64+nt*16+lr)*32 + swk];
    #pragma unroll
    for(int mt=0;mt<4;mt++)
      #pragma unroll
      for(int nt=0;nt<4;nt++)
        acc[mt][nt] = __builtin_amdgcn_mfma_f32_16x16x32_bf16(af[mt], bfr[nt], acc[mt][nt], 0,0,0);
  }
  if (EPI==0){
    #pragma unroll
    for(int nt=0;nt<4;nt++){
      int n = nb + wc*64 + nt*16 + lr;
      float bb = bias[n];
      #pragma unroll
      for(int mt=0;mt<4;mt++)
        #pragma unroll
        for(int r=0;r<4;r++){
          int m = mb + wr*64 + mt*16 + lq*4 + r;
          Obf[(size_t)m*NHID + n] = f2us(gelu_f(acc[mt][nt][r] + bb));
        }
    }
  } else {
    #pragma unroll
    for(int mt=0;mt<4;mt++)
      #pragma unroll
      for(int r=0;r<4;r++){
        int m = mb + wr*64 + mt*16 + lq*4 + r;
        float bb = bias[m];
        #pragma unroll
        for(int nt=0;nt<4;nt++){
          int n = nb + wc*64 + nt*16 + lr;
          size_t ad = (size_t)m*NHW + n;
          Ofl[ad] = acc[mt][nt][r] + bb + xres[ad];
        }
      }
  }
}

extern "C" void kernel_launch(void* const* d_in, const int* in_sizes, int n_in,
                              void* d_out, int out_size, void* d_ws, size_t ws_size,
                              hipStream_t stream) {
  const float* x     = (const float*)d_in[0];
  const float* gamma = (const float*)d_in[1];
  const float* beta  = (const float*)d_in[2];
  const float* n0w   = (const float*)d_in[3];
  const float* n0b   = (const float*)d_in[4];
  const float* n1w   = (const float*)d_in[5];
  const float* n1b   = (const float*)d_in[6];
  const float* wsr   = (const float*)d_in[7];
  const float* wsi   = (const float*)d_in[8];
  const float* iw    = (const float*)d_in[9];
  const float* ib    = (const float*)d_in[10];
  const float* w1    = (const float*)d_in[11];
  const float* b1    = (const float*)d_in[12];
  const float* w2    = (const float*)d_in[13];
  const float* b2    = (const float*)d_in[14];
  float* ws = (float*)d_ws;
  float* out = (float*)d_out;
  if (ws_size < WS_FLOATS*4ULL) return;

  k_setup <<<dim3(2304), dim3(256), 0, stream>>>(ws, wsr, wsi, iw, w2);
  // x^T (bf16 pixel-major) into d_out scratch -- consumed by k_inner, dead before mlp2 writes out.
  ushort* xT = (ushort*)out;
  k_tX   <<<dim3(450,4,2), dim3(256), 0, stream>>>(x, xT);
  k_stats0<<<dim3(512),  dim3(256), 0, stream>>>(x, n0w, n0b, ws);
  k_norm  <<<dim3(512), dim3(256), 0, stream>>>(x, ws);
  // GEMM1: A1(RA) -> F(RB planes)
  k_sgemm<0,0><<<dim3(4,240), dim3(256), 0, stream>>>((const ushort*)(ws+RA0), (const ushort*)(ws+RA0),
      (const ushort*)(ws+OFF_TWF), (ushort*)(ws+OFF_FRE), (ushort*)(ws+OFF_FIM), nullptr);
  // T1: F(RB) -> Ft(RA)
  k_t64 <<<dim3(2,2,512), dim3(256), 0, stream>>>((const ushort*)(ws+OFF_FRE), (ushort*)(ws+RA0), NH, NH*128);
  k_t64 <<<dim3(2,2,512), dim3(256), 0, stream>>>((const ushort*)(ws+OFF_FIM), (ushort*)(ws+RA1), NH, NH*128);
  // GEMM2: Ft(RA) -> G(RB)
  k_sgemm<1,0><<<dim3(4,256), dim3(256), 0, stream>>>((const ushort*)(ws+RA0), (const ushort*)(ws+RA1),
      (const ushort*)(ws+OFF_THF), (ushort*)(ws+RB0), (ushort*)(ws+RB1), nullptr);
  // T2: G(RB) -> Gt(RA) [b][p][c]
  k_tP <<<dim3(256,4,2), dim3(256), 0, stream>>>((const ushort*)(ws+RB0), (ushort*)(ws+RA0));
  k_tP <<<dim3(256,4,2), dim3(256), 0, stream>>>((const ushort*)(ws+RB1), (ushort*)(ws+RA1));
  // mix: Gt(RA) -> Y(RB)
  k_mixg <<<dim3(512,1,2), dim3(256), 0, stream>>>(ws);
  // GEMM4: Y(RB) -> Z(RA)
  k_sgemm<1,0><<<dim3(4,256), dim3(256), 0, stream>>>((const ushort*)(ws+RB0), (const ushort*)(ws+RB1),
      (const ushort*)(ws+OFF_THI), (ushort*)(ws+RA0), (ushort*)(ws+RA1), nullptr);
  // T3: Z(RA) -> Zt(RB)
  k_t64 <<<dim3(2,2,512), dim3(256), 0, stream>>>((const ushort*)(ws+RA0), (ushort*)(ws+RB0), 128, NSP);
  k_t64 <<<dim3(2,2,512), dim3(256), 0, stream>>>((const ushort*)(ws+RA1), (ushort*)(ws+RB1), 128, NSP);
  // GEMM5: Zt(RB) -> U spectral bf16 channel-major (RA)
  k_sgemm<1,1><<<dim3(4,256), dim3(256), 0, stream>>>((const ushort*)(ws+RB0), (const ushort*)(ws+RB1),
      (const ushort*)(ws+OFF_TWI), nullptr, nullptr, (ushort*)(ws+RA0));
  // Phase A: inner conv fused (xT + Usp -> U' pixel-major bf16 in RB, + stats partials)
  k_inner <<<dim3(NPT,1,2), dim3(256), 0, stream>>>(ws, xT, ib);
  k_stats1p<<<dim3(512), dim3(256), 0, stream>>>(gamma, beta, n1w, n1b, ws);
  k_fold  <<<dim3(512,2), dim3(64), 0, stream>>>(ws, w1, b1);
  // Phase C: per-batch  mlp1 (U'*W1p^T -> gelu -> mid)  then  mlp2 (W2*mid^T + b2 + x -> out).
  ushort* mid = (ushort*)(ws+OFF_RA);
  for(int b=0;b<2;b++){
    k_gemm128<256,0><<<dim3(4,225), dim3(256), 0, stream>>>(
        (const ushort*)(ws+OFF_RB) + (size_t)b*NHW*256,
        (const ushort*)(ws+OFF_W1P) + (size_t)b*NHID*256,
        ws+OFF_B1P + b*NHID, nullptr, mid, nullptr);
    k_gemm128<512,1><<<dim3(225,2), dim3(256), 0, stream>>>(
        (const ushort*)(ws+OFF_W2B),
        mid,
        b2, x + (size_t)b*NC*NHW, nullptr, out + (size_t)b*NC*NHW);
  }
}

// Round 7
// 568.416 us; speedup vs baseline: 1.3727x; 1.1197x over previous
//
#include <hip/hip_runtime.h>
#include <hip/hip_bf16.h>

typedef __hip_bfloat16 bf16;
typedef short short8 __attribute__((ext_vector_type(8)));
typedef float f32x4 __attribute__((ext_vector_type(4)));

#define NB 2
#define NC 256
#define NH 120
#define NW 240
#define NHW (NH*NW)      // 28800
#define NSP 16384        // padded spectral pixels per image (128*128)
#define NHID 512
#define NPT 450          // pixel tiles of 64
#define REPS 1e-5f
#define SC_W 0.06454972243679028f   // 1/sqrt(240)
#define SC_H 0.09128709291752769f   // 1/sqrt(120)
#define PI2 6.283185307179586f

__device__ __forceinline__ float gelu_f(float x){ return 0.5f*x*(1.f+erff(x*0.7071067811865476f)); }
__device__ __forceinline__ float us2f(ushort u){ union{float f; uint v;} c; c.v=((uint)u)<<16; return c.f; }
__device__ __forceinline__ ushort f2us(float f){ bf16 b=__float2bfloat16(f); return *(ushort*)&b; }

// async 16B global->LDS (wave-uniform LDS base + lane*16; global addr per-lane)
typedef __attribute__((address_space(3))) void lds_void;
typedef const __attribute__((address_space(1))) void gbl_void;
__device__ __forceinline__ void gload16(const ushort* g, ushort* l){
  __builtin_amdgcn_global_load_lds((gbl_void*)g, (lds_void*)l, 16, 0, 0);
}

// ---- workspace float offsets ----
#define OFF_A0   0
#define OFF_D0   512
#define OFF_A1c  1024
#define OFF_D1c  1536
#define OFF_TWF  2048       // bf16[256][256] fwd-W DFT
#define OFF_THF  34816      // bf16[256][256] fwd-H
#define OFF_THI  67584      // bf16[256][256] inv-H
#define OFF_TWI  100352     // bf16[256][256] inv-W real
#define OFF_WRT  133120     // bf16[256][256] w_spec_r^T [o][i]
#define OFF_WIT  165888     // bf16[256][256] w_spec_i^T
#define OFF_IWB  198656     // bf16[256][256] inner_w [o][i]
#define OFF_W2B  231424     // bf16[256][512]  natural layout
#define OFF_W1P  296960     // bf16[2][512][256]  a1-folded mlp_w1
#define OFF_B1P  428032     // f32[2][512]        folded bias1
#define OFF_PS   429056     // f32[2][450][512]   stats partials (sum | sumsq)
#define OFF_RA   889856     // 8388608 floats ping A
#define OFF_RB   9278464    // 8388608 floats ping B
#define WS_FLOATS 17667072ULL   // 70.7 MB

#define RA0 OFF_RA
#define RA1 (OFF_RA+4194304)
#define RB0 OFF_RB
#define RB1 (OFF_RB+4194304)
#define OFF_FRE RB0
#define OFF_FIM (RB0+3932160)

// ---------------- setup: DFT matrices + weight casts ----------------
__global__ __launch_bounds__(256) void k_setup(float* ws, const float* wsr, const float* wsi,
                                               const float* iw, const float* w2){
  int t = blockIdx.x*256 + threadIdx.x;
  if (t < 65536){ // TWF [n][w]
    int n=t>>8, w=t&255; float v=0.f;
    if(w<NW){
      if(n<121){ v = cosf(PI2*(float)((n*w)%NW)/(float)NW)*SC_W; }
      else if(n>=128 && n<249){ int k=n-128; v = -sinf(PI2*(float)((k*w)%NW)/(float)NW)*SC_W; }
    }
    ((ushort*)(ws+OFF_TWF))[t]=f2us(v); return;
  } t-=65536;
  if (t < 65536){ // THF
    int n=t>>8, j=t&255; float v=0.f;
    int h = j&127; bool im = (j>=128);
    if(h<NH){
      if(n<128){ int m=n; if(m<NH){ float sn,cs; sincosf(PI2*(float)((m*h)%NH)/(float)NH,&sn,&cs);
        v = (im? sn : cs)*SC_H; } }
      else { int m=n-128; if(m<NH){ float sn,cs; sincosf(PI2*(float)((m*h)%NH)/(float)NH,&sn,&cs);
        v = (im? cs : -sn)*SC_H; } }
    }
    ((ushort*)(ws+OFF_THF))[t]=f2us(v); return;
  } t-=65536;
  if (t < 65536){ // THI
    int n=t>>8, j=t&255; float v=0.f;
    int m = j&127; bool im = (j>=128);
    if(m<NH){
      if(n<128){ int h=n; if(h<NH){ float sn,cs; sincosf(PI2*(float)((h*m)%NH)/(float)NH,&sn,&cs);
        v = (im? -sn : cs)*SC_H; } }
      else { int h=n-128; if(h<NH){ float sn,cs; sincosf(PI2*(float)((h*m)%NH)/(float)NH,&sn,&cs);
        v = (im? cs : sn)*SC_H; } }
    }
    ((ushort*)(ws+OFF_THI))[t]=f2us(v); return;
  } t-=65536;
  if (t < 65536){ // TWI
    int w=t>>8, j=t&255; float v=0.f;
    if(w<NW){
      int k = j&127; bool im = (j>=128);
      if(k<121){
        float ck = (k==0||k==120)? 1.f : 2.f;
        float sn,cs; sincosf(PI2*(float)((w*k)%NW)/(float)NW,&sn,&cs);
        v = ck*(im? -sn : cs)*SC_W;
      }
    }
    ((ushort*)(ws+OFF_TWI))[t]=f2us(v); return;
  } t-=65536;
  if (t < 65536){ int o=t>>8,i=t&255; ((ushort*)(ws+OFF_WRT))[t]=f2us(wsr[i*NC+o]); return; } t-=65536;
  if (t < 65536){ int o=t>>8,i=t&255; ((ushort*)(ws+OFF_WIT))[t]=f2us(wsi[i*NC+o]); return; } t-=65536;
  if (t < 65536){ ((ushort*)(ws+OFF_IWB))[t]=f2us(iw[t]); return; } t-=65536;
  if (t < 131072){ ((ushort*)(ws+OFF_W2B))[t]=f2us(w2[t]); return; }
}

// ---------------- instance-norm stats on x ----------------
__global__ __launch_bounds__(256) void k_stats0(const float* x, const float* n0w, const float* n0b, float* ws){
  int g = blockIdx.x, c = g & (NC-1);
  const float4* xp = (const float4*)(x + (size_t)g*NHW);
  float s=0.f, q=0.f;
  for(int i=threadIdx.x;i<NHW/4;i+=256){
    float4 v=xp[i];
    s+=v.x+v.y+v.z+v.w;
    q=fmaf(v.x,v.x,fmaf(v.y,v.y,fmaf(v.z,v.z,fmaf(v.w,v.w,q))));
  }
  __shared__ float ls[4], lq[4];
  #pragma unroll
  for(int o=32;o>0;o>>=1){ s+=__shfl_down(s,o,64); q+=__shfl_down(q,o,64); }
  int lane=threadIdx.x&63, wid=threadIdx.x>>6;
  if(!lane){ ls[wid]=s; lq[wid]=q; }
  __syncthreads();
  if(!threadIdx.x){
    s=ls[0]+ls[1]+ls[2]+ls[3]; q=lq[0]+lq[1]+lq[2]+lq[3];
    float m=s*(1.f/NHW), var=q*(1.f/NHW)-m*m;
    float r=rsqrtf(var+REPS);
    float a=r*n0w[c];
    ws[OFF_A0+g]=a; ws[OFF_D0+g]=fmaf(-m,a,n0b[c]);
  }
}

// ---------------- norm+cast: x -> A1 bf16 [g][120][256] (vectorized, 512 blocks) ----------------
__global__ __launch_bounds__(256) void k_norm(const float* x, float* ws){
  int g = blockIdx.x;
  float a = ws[OFF_A0+g], d = ws[OFF_D0+g];
  const float4* xp = (const float4*)(x + (size_t)g*NHW);
  ushort* dst = ((ushort*)(ws+RA0)) + (size_t)g*30720;
  for(int i=threadIdx.x; i<7200; i+=256){          // 7200 float4 = 120 rows x 60
    float4 v = xp[i];
    int h = i/60, w4 = (i - h*60)*4;
    ushort4 o;
    o.x=f2us(fmaf(a,v.x,d)); o.y=f2us(fmaf(a,v.y,d));
    o.z=f2us(fmaf(a,v.z,d)); o.w=f2us(fmaf(a,v.w,d));
    *(ushort4*)(dst + h*256 + w4) = o;
  }
  for(int i=threadIdx.x; i<480; i+=256){           // zero pad w=240..255
    int h = i>>2, w4 = 240 + (i&3)*4;
    ushort4 z = {0,0,0,0};
    *(ushort4*)(dst + h*256 + w4) = z;
  }
}

// ---------------- x transpose: f32 [b][c][px] -> bf16 [b][px][c]  (k_tP pattern) ----------------
__global__ __launch_bounds__(256) void k_tX(const float* x, ushort* xT){
  __shared__ ushort lt[64][72];
  int b=blockIdx.z, c0=blockIdx.y*64, p0=blockIdx.x*64;
  int t=threadIdx.x;
  int cr=t>>4, p4=(t&15)*4;
  #pragma unroll
  for(int i=0;i<4;i++){
    int c = i*16 + cr;
    float4 v = *(const float4*)(x + ((size_t)(b*NC + c0 + c))*NHW + p0 + p4);
    ushort4 o; o.x=f2us(v.x); o.y=f2us(v.y); o.z=f2us(v.z); o.w=f2us(v.w);
    *(ushort4*)&lt[c][p4] = o;
  }
  __syncthreads();
  int pr=t>>2, q2=t&3;
  union { ushort s[8]; uint4 u; } o0, o1;
  #pragma unroll
  for(int e=0;e<8;e++){ o0.s[e]=lt[q2*16+e][pr]; o1.s[e]=lt[q2*16+8+e][pr]; }
  ushort* dp = xT + ((size_t)(b*NHW) + p0 + pr)*256 + c0 + q2*16;
  *(uint4*)dp = o0.u; *(uint4*)(dp+8) = o1.u;
}

// ---------------- spectral GEMM (v7: B panel staged in LDS, chunk-swizzled) ----------------
template<int SPLIT, int EPI>
__global__ __launch_bounds__(256) void k_sgemm(const ushort* Ap0, const ushort* Ap1, const ushort* Bm,
                                               ushort* O0, ushort* O1, ushort* Ub){
  __shared__ ushort Bsl[16384];   // [64 rows][32 chunks][8], phys chunk = j ^ (row&7)
  int nb = blockIdx.x*64, mb = blockIdx.y*256;
  int tid = threadIdx.x, w = tid>>6, l = tid&63, lq = l>>4, lr = l&15;
  // stage B rows nb..nb+63 (all K) once
  #pragma unroll
  for(int i=0;i<8;i++){
    int L = i*256 + tid;
    int row = L>>5, j = L&31;
    gload16(Bm + (size_t)(nb+row)*256 + ((j ^ (row&7))<<3), &Bsl[(i*256 + w*64)*8]);
  }
  const ushort* ar0[4]; const ushort* ar1[4];
  #pragma unroll
  for(int mt=0;mt<4;mt++){
    size_t r = mb + w*64 + mt*16 + lr;
    ar0[mt] = Ap0 + r*(SPLIT?128:256) + lq*8;
    ar1[mt] = SPLIT ? (Ap1 + r*128 + lq*8) : ar0[mt];
  }
  __syncthreads();   // B staged (vmcnt drained pre-barrier)
  f32x4 acc[4][4] = {};
  #pragma unroll
  for(int kk=0;kk<8;kk++){
    int k = kk*32;
    short8 af[4], bfr[4];
    #pragma unroll
    for(int mt=0;mt<4;mt++){
      const ushort* p = SPLIT ? ((k<128 ? ar0[mt] : ar1[mt]) + (k&127)) : (ar0[mt] + k);
      af[mt] = *(const short8*)p;
    }
    #pragma unroll
    for(int nt=0;nt<4;nt++){
      int row = nt*16 + lr;
      bfr[nt] = *(const short8*)&Bsl[row*256 + (((kk*4+lq) ^ (row&7))<<3)];
    }
    #pragma unroll
    for(int mt=0;mt<4;mt++)
      #pragma unroll
      for(int nt=0;nt<4;nt++)
        acc[mt][nt] = __builtin_amdgcn_mfma_f32_16x16x32_bf16(af[mt], bfr[nt], acc[mt][nt], 0,0,0);
  }
  #pragma unroll
  for(int mt=0;mt<4;mt++){
    #pragma unroll
    for(int r=0;r<4;r++){
      int m = mb + w*64 + mt*16 + lq*4 + r;
      #pragma unroll
      for(int nt=0;nt<4;nt++){
        int n = nb + nt*16 + lr;
        float v = acc[mt][nt][r];
        if (EPI==0){
          if(n<128) O0[(size_t)m*128+n] = f2us(v);
          else      O1[(size_t)m*128+n-128] = f2us(v);
        } else {
          int g = m>>7, h = m&127;
          if(h<NH && n<NW) Ub[(size_t)g*NHW + (size_t)h*NW + n] = f2us(v);
        }
      }
    }
  }
}

// ---------------- 64x64 bf16 transpose within 128-stride planes ----------------
__global__ __launch_bounds__(256) void k_t64(const ushort* src, ushort* dst, int srows, int sgstr){
  __shared__ ushort lt[64][72];
  int g=blockIdx.z, i0=blockIdx.y*64, p0=blockIdx.x*64;
  int t=threadIdx.x, r=t>>2, q=t&3;
  int row = i0 + r;
  uint4 u0=make_uint4(0,0,0,0), u1=u0;
  if(row < srows){
    const ushort* sp = src + (size_t)g*sgstr + (size_t)row*128 + p0 + q*16;
    u0=*(const uint4*)sp; u1=*(const uint4*)(sp+8);
  }
  *(uint4*)&lt[r][q*16]=u0; *(uint4*)&lt[r][q*16+8]=u1;
  __syncthreads();
  int pr=t>>2, q2=t&3;
  union { ushort s[8]; uint4 u; } o0, o1;
  #pragma unroll
  for(int e=0;e<8;e++){ o0.s[e]=lt[q2*16+e][pr]; o1.s[e]=lt[q2*16+8+e][pr]; }
  ushort* dp = dst + (size_t)g*NSP + (size_t)(p0+pr)*128 + i0 + q2*16;
  *(uint4*)dp = o0.u; *(uint4*)(dp+8) = o1.u;
}

// ---------------- pixel transpose: [b][c:256][NSP] -> [b][NSP][c] ----------------
__global__ __launch_bounds__(256) void k_tP(const ushort* src, ushort* dst){
  __shared__ ushort lt[64][72];
  int b=blockIdx.z, i0=blockIdx.y*64, p0=blockIdx.x*64;
  int t=threadIdx.x, r=t>>2, q=t&3;
  const ushort* sp = src + (size_t)(b*NC+i0+r)*NSP + p0 + q*16;
  uint4 u0=*(const uint4*)sp, u1=*(const uint4*)(sp+8);
  *(uint4*)&lt[r][q*16]=u0; *(uint4*)&lt[r][q*16+8]=u1;
  __syncthreads();
  int pr=t>>2, q2=t&3;
  union { ushort s[8]; uint4 u; } o0, o1;
  #pragma unroll
  for(int e=0;e<8;e++){ o0.s[e]=lt[q2*16+e][pr]; o1.s[e]=lt[q2*16+8+e][pr]; }
  ushort* dp = dst + ((size_t)b*NSP + p0 + pr)*NC + i0 + q2*16;
  *(uint4*)dp = o0.u; *(uint4*)(dp+8) = o1.u;
}

// ---------------- complex spectral mix via MFMA ----------------
__global__ __launch_bounds__(256) void k_mixg(float* ws){
  int b = blockIdx.z, p0 = blockIdx.x*32;
  int tid = threadIdx.x, w = tid>>6, l = tid&63, lq = l>>4, lr = l&15;
  const ushort* Wr = (const ushort*)(ws+OFF_WRT);
  const ushort* Wi = (const ushort*)(ws+OFF_WIT);
  const ushort* Gr = (const ushort*)(ws+RA0) + (size_t)b*NSP*NC;
  const ushort* Gi = (const ushort*)(ws+RA1) + (size_t)b*NSP*NC;
  const ushort *wrr[4], *wir[4], *brr[2], *bir[2];
  #pragma unroll
  for(int mt=0;mt<4;mt++){ size_t ro=(size_t)(w*64+mt*16+lr)*NC+lq*8; wrr[mt]=Wr+ro; wir[mt]=Wi+ro; }
  #pragma unroll
  for(int nt=0;nt<2;nt++){ size_t ro=(size_t)(p0+nt*16+lr)*NC+lq*8; brr[nt]=Gr+ro; bir[nt]=Gi+ro; }
  f32x4 aR[4][2]={}, aI[4][2]={};
  for(int k=0;k<256;k+=32){
    short8 fr[4], fi[4], fin[4], gr[2], gi[2];
    #pragma unroll
    for(int mt=0;mt<4;mt++){
      fr[mt]=*(const short8*)(wrr[mt]+k);
      fi[mt]=*(const short8*)(wir[mt]+k);
      union { short8 s; uint u[4]; } nv; nv.s=fi[mt];
      nv.u[0]^=0x80008000u; nv.u[1]^=0x80008000u; nv.u[2]^=0x80008000u; nv.u[3]^=0x80008000u;
      fin[mt]=nv.s;
    }
    #pragma unroll
    for(int nt=0;nt<2;nt++){ gr[nt]=*(const short8*)(brr[nt]+k); gi[nt]=*(const short8*)(bir[nt]+k); }
    #pragma unroll
    for(int mt=0;mt<4;mt++)
      #pragma unroll
      for(int nt=0;nt<2;nt++){
        aR[mt][nt]=__builtin_amdgcn_mfma_f32_16x16x32_bf16(fr[mt], gr[nt], aR[mt][nt],0,0,0);
        aR[mt][nt]=__builtin_amdgcn_mfma_f32_16x16x32_bf16(fin[mt],gi[nt], aR[mt][nt],0,0,0);
        aI[mt][nt]=__builtin_amdgcn_mfma_f32_16x16x32_bf16(fi[mt], gr[nt], aI[mt][nt],0,0,0);
        aI[mt][nt]=__builtin_amdgcn_mfma_f32_16x16x32_bf16(fr[mt], gi[nt], aI[mt][nt],0,0,0);
      }
  }
  ushort* Yre = (ushort*)(ws+RB0);
  ushort* Yim = (ushort*)(ws+RB1);
  #pragma unroll
  for(int mt=0;mt<4;mt++){
    #pragma unroll
    for(int r=0;r<4;r++){
      int m = w*64 + mt*16 + lq*4 + r;
      #pragma unroll
      for(int nt=0;nt<2;nt++){
        int n = p0 + nt*16 + lr;
        size_t ad = (size_t)(b*NC+m)*NSP + n;
        Yre[ad] = f2us(aR[mt][nt][r]);
        Yim[ad] = f2us(aI[mt][nt][r]);
      }
    }
  }
}

// ---------------- Phase A: fused inner conv + gelu + stats + U' (v7: 512 threads, 16 waves/CU) ----------------
// 8 waves per block; wave owns 32 output rows (acc[2][4] = 32 AGPR). Same 64KB LDS ->
// 2 blocks x 8 waves = 16 waves/CU (2x v6 occupancy), per-thread serial work halved.
__global__ __launch_bounds__(512,4) void k_inner(float* ws, const ushort* xT, const float* ib){
  __shared__ ushort xtl[16384];   // [64 px][32 chunks][8]
  __shared__ ushort us[16384];    // [256 ch][8 chunks][8]
  int b = blockIdx.z, blk = blockIdx.x, p0 = blk*64;
  int t = threadIdx.x, w = t>>6, l = t&63, lq = l>>4, lr = l&15;
  // async-stage x^T tile -> xtl
  #pragma unroll
  for(int i=0;i<4;i++){
    int L = i*512 + t;
    int px = L>>5, j = L&31;
    gload16(xT + ((size_t)(b*NHW) + p0 + px)*256 + ((j ^ (px&7))<<3), &xtl[(i*512 + w*64)*8]);
  }
  // async-stage Usp tile -> us
  const ushort* Usp = (const ushort*)(ws+OFF_RA);
  #pragma unroll
  for(int i=0;i<4;i++){
    int L = i*512 + t;
    int row = L>>3;
    int jd = (L&7) ^ (row&7);
    gload16(Usp + (size_t)(b*NC + row)*NHW + p0 + jd*8, &us[(i*512 + w*64)*8]);
  }
  __syncthreads();
  const ushort* W = (const ushort*)(ws+OFF_IWB);
  const ushort* ar[2];
  #pragma unroll
  for(int mt=0;mt<2;mt++) ar[mt] = W + (size_t)(w*32+mt*16+lr)*256 + lq*8;
  f32x4 acc[2][4] = {};
  #pragma unroll
  for(int kk=0;kk<8;kk++){
    short8 af[2], bfr[4];
    #pragma unroll
    for(int mt=0;mt<2;mt++) af[mt] = *(const short8*)(ar[mt]+kk*32);
    #pragma unroll
    for(int nt=0;nt<4;nt++){
      int px = nt*16 + lr;
      bfr[nt] = *(const short8*)&xtl[px*256 + (((kk*4+lq) ^ (px&7))<<3)];
    }
    #pragma unroll
    for(int mt=0;mt<2;mt++)
      #pragma unroll
      for(int nt=0;nt<4;nt++)
        acc[mt][nt] = __builtin_amdgcn_mfma_f32_16x16x32_bf16(af[mt], bfr[nt], acc[mt][nt], 0,0,0);
  }
  __syncthreads();   // xtl reads done; reuse as swizzled U' transpose buffer
  float* PS = ws + OFF_PS + ((size_t)(b*NPT+blk))*512;
  #pragma unroll
  for(int mt=0;mt<2;mt++){
    #pragma unroll
    for(int r=0;r<4;r++){
      int m = w*32 + mt*16 + lq*4 + r;
      float bb = ib[m];
      int m7 = m&7, mc = m>>3, mo = m&7;
      float ss = 0.f, sq = 0.f;
      #pragma unroll
      for(int nt=0;nt<4;nt++){
        int ncol = nt*16 + lr;
        float uv = us2f(us[m*64 + (((ncol>>3) ^ m7)<<3) + (ncol&7)]);
        float g = gelu_f(acc[mt][nt][r] + bb + uv);
        xtl[ncol*256 + ((mc ^ (ncol&7))<<3) + mo] = f2us(g);
        ss += g; sq = fmaf(g,g,sq);
      }
      #pragma unroll
      for(int ofs=1; ofs<16; ofs<<=1){ ss += __shfl_xor(ss, ofs, 64); sq += __shfl_xor(sq, ofs, 64); }
      if(lr==0){ PS[m] = ss; PS[256+m] = sq; }
    }
  }
  __syncthreads();
  ushort* Up = (ushort*)(ws+OFF_RB);
  #pragma unroll
  for(int pp=0; pp<2; pp++){
    int p = pp*32 + (t>>4);
    int s = p&7;
    int j0 = (t&15)*2;
    uint4 w0  = *(uint4*)&xtl[p*256 + ((j0 ^ s)<<3)];
    uint4 w1v = *(uint4*)&xtl[p*256 + (((j0+1) ^ s)<<3)];
    ushort* dp = Up + ((size_t)(b*NHW + p0 + p))*256 + j0*8;
    *(uint4*)dp = w0; *(uint4*)(dp+8) = w1v;
  }
}

// ---------------- stats1: reduce partials -> a1,d1 (FiLM folded) ----------------
__global__ __launch_bounds__(256) void k_stats1p(const float* gamma, const float* beta,
                                                 const float* n1w, const float* n1b, float* ws){
  int g = blockIdx.x, b = g>>8, c = g&255;
  float s=0.f, q=0.f;
  for(int i=threadIdx.x;i<NPT;i+=256){
    const float* P = ws + OFF_PS + ((size_t)(b*NPT+i))*512;
    s += P[c]; q += P[256+c];
  }
  __shared__ float ls[4], lq2[4];
  #pragma unroll
  for(int o=32;o>0;o>>=1){ s+=__shfl_down(s,o,64); q+=__shfl_down(q,o,64); }
  int lane=threadIdx.x&63, wid=threadIdx.x>>6;
  if(!lane){ ls[wid]=s; lq2[wid]=q; }
  __syncthreads();
  if(!threadIdx.x){
    s=ls[0]+ls[1]+ls[2]+ls[3]; q=lq2[0]+lq2[1]+lq2[2]+lq2[3];
    float m=s*(1.f/NHW), var=q*(1.f/NHW)-m*m;
    float r=rsqrtf(var+REPS);
    float gp1 = 1.f + gamma[c];
    float wv = n1w[c];
    ws[OFF_A1c+g] = gp1*wv*r;
    ws[OFF_D1c+g] = gp1*(n1b[c] - m*r*wv) + beta[c];
  }
}

// ---------------- fold a1/d1 into W1: W1'[b]=W1*diag(a1), b1'=W1*d1+b1 ----------------
__global__ __launch_bounds__(64) void k_fold(float* ws, const float* w1, const float* b1){
  int o = blockIdx.x, b = blockIdx.y, t = threadIdx.x;
  float acc = 0.f;
  ushort* W1p = (ushort*)(ws+OFF_W1P);
  #pragma unroll
  for(int ii=0; ii<4; ii++){
    int i = ii*64 + t;
    float wv = w1[o*256+i];
    W1p[((size_t)(b*NHID+o))*256 + i] = f2us(wv * ws[OFF_A1c + b*NC + i]);
    acc = fmaf(wv, ws[OFF_D1c + b*NC + i], acc);
  }
  #pragma unroll
  for(int ofs=32; ofs; ofs>>=1) acc += __shfl_down(acc, ofs, 64);
  if(!t) ws[OFF_B1P + b*NHID + o] = acc + b1[o];
}

// ---------------- Phase C: two staged 128x128-tile GEMMs (m97 structure) ----------------
template<int KD, int EPI>
__global__ __launch_bounds__(256) void k_gemm128(const ushort* __restrict__ A, const ushort* __restrict__ B,
                                                 const float* __restrict__ bias, const float* __restrict__ xres,
                                                 ushort* __restrict__ Obf, float* __restrict__ Ofl){
  __shared__ ushort As[2][4096] __attribute__((aligned(16)));
  __shared__ ushort Bs[2][4096] __attribute__((aligned(16)));
  int t = threadIdx.x, w = t>>6, l = t&63, lq = l>>4, lr = l&15;
  int wr = w>>1, wc = w&1;
  int nb = blockIdx.x*128, mb = blockIdx.y*128;
  const ushort* Ab = A + (size_t)mb*KD;
  const ushort* Bb = B + (size_t)nb*KD;
  int srow = t>>2;
  int scg  = (t&3) ^ ((t>>3)&3);
  size_t so0 = (size_t)srow*KD + scg*8;
  size_t so1 = (size_t)(srow+64)*KD + scg*8;
  int ld0 = w*512, ld1 = 2048 + w*512;
  int swk = (lq ^ ((lr>>1)&3))*8;
  f32x4 acc[4][4] = {};
  gload16(Ab+so0, &As[0][ld0]); gload16(Ab+so1, &As[0][ld1]);
  gload16(Bb+so0, &Bs[0][ld0]); gload16(Bb+so1, &Bs[0][ld1]);
  const int NK = KD/32;
  for(int kt=0; kt<NK; kt++){
    int cur = kt&1;
    __syncthreads();
    if(kt+1 < NK){
      size_t ko = (size_t)(kt+1)*32;
      gload16(Ab+so0+ko, &As[cur^1][ld0]); gload16(Ab+so1+ko, &As[cur^1][ld1]);
      gload16(Bb+so0+ko, &Bs[cur^1][ld0]); gload16(Bb+so1+ko, &Bs[cur^1][ld1]);
    }
    short8 af[4], bfr[4];
    #pragma unroll
    for(int mt=0;mt<4;mt++) af[mt]  = *(const short8*)&As[cur][(wr*64+mt*16+lr)*32 + swk];
    #pragma unroll
    for(int nt=0;nt<4;nt++) bfr[nt] = *(const short8*)&Bs[cur][(wc*64+nt*16+lr)*32 + swk];
    #pragma unroll
    for(int mt=0;mt<4;mt++)
      #pragma unroll
      for(int nt=0;nt<4;nt++)
        acc[mt][nt] = __builtin_amdgcn_mfma_f32_16x16x32_bf16(af[mt], bfr[nt], acc[mt][nt], 0,0,0);
  }
  if (EPI==0){
    #pragma unroll
    for(int nt=0;nt<4;nt++){
      int n = nb + wc*64 + nt*16 + lr;
      float bb = bias[n];
      #pragma unroll
      for(int mt=0;mt<4;mt++)
        #pragma unroll
        for(int r=0;r<4;r++){
          int m = mb + wr*64 + mt*16 + lq*4 + r;
          Obf[(size_t)m*NHID + n] = f2us(gelu_f(acc[mt][nt][r] + bb));
        }
    }
  } else {
    #pragma unroll
    for(int mt=0;mt<4;mt++)
      #pragma unroll
      for(int r=0;r<4;r++){
        int m = mb + wr*64 + mt*16 + lq*4 + r;
        float bb = bias[m];
        #pragma unroll
        for(int nt=0;nt<4;nt++){
          int n = nb + wc*64 + nt*16 + lr;
          size_t ad = (size_t)m*NHW + n;
          Ofl[ad] = acc[mt][nt][r] + bb + xres[ad];
        }
      }
  }
}

extern "C" void kernel_launch(void* const* d_in, const int* in_sizes, int n_in,
                              void* d_out, int out_size, void* d_ws, size_t ws_size,
                              hipStream_t stream) {
  const float* x     = (const float*)d_in[0];
  const float* gamma = (const float*)d_in[1];
  const float* beta  = (const float*)d_in[2];
  const float* n0w   = (const float*)d_in[3];
  const float* n0b   = (const float*)d_in[4];
  const float* n1w   = (const float*)d_in[5];
  const float* n1b   = (const float*)d_in[6];
  const float* wsr   = (const float*)d_in[7];
  const float* wsi   = (const float*)d_in[8];
  const float* iw    = (const float*)d_in[9];
  const float* ib    = (const float*)d_in[10];
  const float* w1    = (const float*)d_in[11];
  const float* b1    = (const float*)d_in[12];
  const float* w2    = (const float*)d_in[13];
  const float* b2    = (const float*)d_in[14];
  float* ws = (float*)d_ws;
  float* out = (float*)d_out;
  if (ws_size < WS_FLOATS*4ULL) return;

  k_setup <<<dim3(2304), dim3(256), 0, stream>>>(ws, wsr, wsi, iw, w2);
  // x^T (bf16 pixel-major) into d_out scratch -- consumed by k_inner, dead before mlp2 writes out.
  ushort* xT = (ushort*)out;
  k_tX   <<<dim3(450,4,2), dim3(256), 0, stream>>>(x, xT);
  k_stats0<<<dim3(512),  dim3(256), 0, stream>>>(x, n0w, n0b, ws);
  k_norm  <<<dim3(512), dim3(256), 0, stream>>>(x, ws);
  // GEMM1: A1(RA) -> F(RB planes)
  k_sgemm<0,0><<<dim3(4,240), dim3(256), 0, stream>>>((const ushort*)(ws+RA0), (const ushort*)(ws+RA0),
      (const ushort*)(ws+OFF_TWF), (ushort*)(ws+OFF_FRE), (ushort*)(ws+OFF_FIM), nullptr);
  // T1: F(RB) -> Ft(RA)
  k_t64 <<<dim3(2,2,512), dim3(256), 0, stream>>>((const ushort*)(ws+OFF_FRE), (ushort*)(ws+RA0), NH, NH*128);
  k_t64 <<<dim3(2,2,512), dim3(256), 0, stream>>>((const ushort*)(ws+OFF_FIM), (ushort*)(ws+RA1), NH, NH*128);
  // GEMM2: Ft(RA) -> G(RB)
  k_sgemm<1,0><<<dim3(4,256), dim3(256), 0, stream>>>((const ushort*)(ws+RA0), (const ushort*)(ws+RA1),
      (const ushort*)(ws+OFF_THF), (ushort*)(ws+RB0), (ushort*)(ws+RB1), nullptr);
  // T2: G(RB) -> Gt(RA) [b][p][c]
  k_tP <<<dim3(256,4,2), dim3(256), 0, stream>>>((const ushort*)(ws+RB0), (ushort*)(ws+RA0));
  k_tP <<<dim3(256,4,2), dim3(256), 0, stream>>>((const ushort*)(ws+RB1), (ushort*)(ws+RA1));
  // mix: Gt(RA) -> Y(RB)
  k_mixg <<<dim3(512,1,2), dim3(256), 0, stream>>>(ws);
  // GEMM4: Y(RB) -> Z(RA)
  k_sgemm<1,0><<<dim3(4,256), dim3(256), 0, stream>>>((const ushort*)(ws+RB0), (const ushort*)(ws+RB1),
      (const ushort*)(ws+OFF_THI), (ushort*)(ws+RA0), (ushort*)(ws+RA1), nullptr);
  // T3: Z(RA) -> Zt(RB)
  k_t64 <<<dim3(2,2,512), dim3(256), 0, stream>>>((const ushort*)(ws+RA0), (ushort*)(ws+RB0), 128, NSP);
  k_t64 <<<dim3(2,2,512), dim3(256), 0, stream>>>((const ushort*)(ws+RA1), (ushort*)(ws+RB1), 128, NSP);
  // GEMM5: Zt(RB) -> U spectral bf16 channel-major (RA)
  k_sgemm<1,1><<<dim3(4,256), dim3(256), 0, stream>>>((const ushort*)(ws+RB0), (const ushort*)(ws+RB1),
      (const ushort*)(ws+OFF_TWI), nullptr, nullptr, (ushort*)(ws+RA0));
  // Phase A: inner conv fused (xT + Usp -> U' pixel-major bf16 in RB, + stats partials)
  k_inner <<<dim3(NPT,1,2), dim3(512), 0, stream>>>(ws, xT, ib);
  k_stats1p<<<dim3(512), dim3(256), 0, stream>>>(gamma, beta, n1w, n1b, ws);
  k_fold  <<<dim3(512,2), dim3(64), 0, stream>>>(ws, w1, b1);
  // Phase C: per-batch  mlp1 (U'*W1p^T -> gelu -> mid)  then  mlp2 (W2*mid^T + b2 + x -> out).
  ushort* mid = (ushort*)(ws+OFF_RA);
  for(int b=0;b<2;b++){
    k_gemm128<256,0><<<dim3(4,225), dim3(256), 0, stream>>>(
        (const ushort*)(ws+OFF_RB) + (size_t)b*NHW*256,
        (const ushort*)(ws+OFF_W1P) + (size_t)b*NHID*256,
        ws+OFF_B1P + b*NHID, nullptr, mid, nullptr);
    k_gemm128<512,1><<<dim3(225,2), dim3(256), 0, stream>>>(
        (const ushort*)(ws+OFF_W2B),
        mid,
        b2, x + (size_t)b*NC*NHW, nullptr, out + (size_t)b*NC*NHW);
  }
}

// Round 8
// 553.591 us; speedup vs baseline: 1.4095x; 1.0268x over previous
//
#include <hip/hip_runtime.h>
#include <hip/hip_bf16.h>

typedef __hip_bfloat16 bf16;
typedef short short8 __attribute__((ext_vector_type(8)));
typedef float f32x4 __attribute__((ext_vector_type(4)));

#define NB 2
#define NC 256
#define NH 120
#define NW 240
#define NHW (NH*NW)      // 28800
#define NSP 16384        // padded spectral pixels per image (128*128)
#define NHID 512
#define NPT 450          // pixel tiles of 64
#define REPS 1e-5f
#define SC_W 0.06454972243679028f   // 1/sqrt(240)
#define SC_H 0.09128709291752769f   // 1/sqrt(120)
#define PI2 6.283185307179586f

__device__ __forceinline__ float gelu_f(float x){ return 0.5f*x*(1.f+erff(x*0.7071067811865476f)); }
__device__ __forceinline__ float us2f(ushort u){ union{float f; uint v;} c; c.v=((uint)u)<<16; return c.f; }
__device__ __forceinline__ ushort f2us(float f){ bf16 b=__float2bfloat16(f); return *(ushort*)&b; }

// async 16B global->LDS (wave-uniform LDS base + lane*16; global addr per-lane)
typedef __attribute__((address_space(3))) void lds_void;
typedef const __attribute__((address_space(1))) void gbl_void;
__device__ __forceinline__ void gload16(const ushort* g, ushort* l){
  __builtin_amdgcn_global_load_lds((gbl_void*)g, (lds_void*)l, 16, 0, 0);
}

// ---- workspace float offsets ----
#define OFF_A0   0
#define OFF_D0   512
#define OFF_A1c  1024
#define OFF_D1c  1536
#define OFF_TWF  2048       // bf16[256][256] fwd-W DFT
#define OFF_THF  34816      // bf16[256][256] fwd-H
#define OFF_THI  67584      // bf16[256][256] inv-H
#define OFF_TWI  100352     // bf16[256][256] inv-W real
#define OFF_WRT  133120     // bf16[256][256] w_spec_r^T [o][i]
#define OFF_WIT  165888     // bf16[256][256] w_spec_i^T
#define OFF_IWB  198656     // bf16[256][256] inner_w [o][i]
#define OFF_W2B  231424     // bf16[256][512]  natural layout
#define OFF_W1P  296960     // bf16[2][512][256]  a1-folded mlp_w1
#define OFF_B1P  428032     // f32[2][512]        folded bias1
#define OFF_PS   429056     // f32[2][450][512]   stats partials (sum | sumsq)
#define OFF_RA   889856     // 8388608 floats ping A
#define OFF_RB   9278464    // 8388608 floats ping B
#define WS_FLOATS 17667072ULL   // 70.7 MB

#define RA0 OFF_RA
#define RA1 (OFF_RA+4194304)
#define RB0 OFF_RB
#define RB1 (OFF_RB+4194304)
#define OFF_FRE RB0
#define OFF_FIM (RB0+3932160)

// ---------------- setup: DFT matrices + weight casts ----------------
__global__ __launch_bounds__(256) void k_setup(float* ws, const float* wsr, const float* wsi,
                                               const float* iw, const float* w2){
  int t = blockIdx.x*256 + threadIdx.x;
  if (t < 65536){ // TWF [n][w]
    int n=t>>8, w=t&255; float v=0.f;
    if(w<NW){
      if(n<121){ v = cosf(PI2*(float)((n*w)%NW)/(float)NW)*SC_W; }
      else if(n>=128 && n<249){ int k=n-128; v = -sinf(PI2*(float)((k*w)%NW)/(float)NW)*SC_W; }
    }
    ((ushort*)(ws+OFF_TWF))[t]=f2us(v); return;
  } t-=65536;
  if (t < 65536){ // THF
    int n=t>>8, j=t&255; float v=0.f;
    int h = j&127; bool im = (j>=128);
    if(h<NH){
      if(n<128){ int m=n; if(m<NH){ float sn,cs; sincosf(PI2*(float)((m*h)%NH)/(float)NH,&sn,&cs);
        v = (im? sn : cs)*SC_H; } }
      else { int m=n-128; if(m<NH){ float sn,cs; sincosf(PI2*(float)((m*h)%NH)/(float)NH,&sn,&cs);
        v = (im? cs : -sn)*SC_H; } }
    }
    ((ushort*)(ws+OFF_THF))[t]=f2us(v); return;
  } t-=65536;
  if (t < 65536){ // THI
    int n=t>>8, j=t&255; float v=0.f;
    int m = j&127; bool im = (j>=128);
    if(m<NH){
      if(n<128){ int h=n; if(h<NH){ float sn,cs; sincosf(PI2*(float)((h*m)%NH)/(float)NH,&sn,&cs);
        v = (im? -sn : cs)*SC_H; } }
      else { int h=n-128; if(h<NH){ float sn,cs; sincosf(PI2*(float)((h*m)%NH)/(float)NH,&sn,&cs);
        v = (im? cs : sn)*SC_H; } }
    }
    ((ushort*)(ws+OFF_THI))[t]=f2us(v); return;
  } t-=65536;
  if (t < 65536){ // TWI
    int w=t>>8, j=t&255; float v=0.f;
    if(w<NW){
      int k = j&127; bool im = (j>=128);
      if(k<121){
        float ck = (k==0||k==120)? 1.f : 2.f;
        float sn,cs; sincosf(PI2*(float)((w*k)%NW)/(float)NW,&sn,&cs);
        v = ck*(im? -sn : cs)*SC_W;
      }
    }
    ((ushort*)(ws+OFF_TWI))[t]=f2us(v); return;
  } t-=65536;
  if (t < 65536){ int o=t>>8,i=t&255; ((ushort*)(ws+OFF_WRT))[t]=f2us(wsr[i*NC+o]); return; } t-=65536;
  if (t < 65536){ int o=t>>8,i=t&255; ((ushort*)(ws+OFF_WIT))[t]=f2us(wsi[i*NC+o]); return; } t-=65536;
  if (t < 65536){ ((ushort*)(ws+OFF_IWB))[t]=f2us(iw[t]); return; } t-=65536;
  if (t < 131072){ ((ushort*)(ws+OFF_W2B))[t]=f2us(w2[t]); return; }
}

// ---------------- instance-norm stats on x ----------------
__global__ __launch_bounds__(256) void k_stats0(const float* x, const float* n0w, const float* n0b, float* ws){
  int g = blockIdx.x, c = g & (NC-1);
  const float4* xp = (const float4*)(x + (size_t)g*NHW);
  float s=0.f, q=0.f;
  for(int i=threadIdx.x;i<NHW/4;i+=256){
    float4 v=xp[i];
    s+=v.x+v.y+v.z+v.w;
    q=fmaf(v.x,v.x,fmaf(v.y,v.y,fmaf(v.z,v.z,fmaf(v.w,v.w,q))));
  }
  __shared__ float ls[4], lq[4];
  #pragma unroll
  for(int o=32;o>0;o>>=1){ s+=__shfl_down(s,o,64); q+=__shfl_down(q,o,64); }
  int lane=threadIdx.x&63, wid=threadIdx.x>>6;
  if(!lane){ ls[wid]=s; lq[wid]=q; }
  __syncthreads();
  if(!threadIdx.x){
    s=ls[0]+ls[1]+ls[2]+ls[3]; q=lq[0]+lq[1]+lq[2]+lq[3];
    float m=s*(1.f/NHW), var=q*(1.f/NHW)-m*m;
    float r=rsqrtf(var+REPS);
    float a=r*n0w[c];
    ws[OFF_A0+g]=a; ws[OFF_D0+g]=fmaf(-m,a,n0b[c]);
  }
}

// ---------------- norm+cast: x -> A1 bf16 [g][120][256] (vectorized, 512 blocks) ----------------
__global__ __launch_bounds__(256) void k_norm(const float* x, float* ws){
  int g = blockIdx.x;
  float a = ws[OFF_A0+g], d = ws[OFF_D0+g];
  const float4* xp = (const float4*)(x + (size_t)g*NHW);
  ushort* dst = ((ushort*)(ws+RA0)) + (size_t)g*30720;
  for(int i=threadIdx.x; i<7200; i+=256){          // 7200 float4 = 120 rows x 60
    float4 v = xp[i];
    int h = i/60, w4 = (i - h*60)*4;
    ushort4 o;
    o.x=f2us(fmaf(a,v.x,d)); o.y=f2us(fmaf(a,v.y,d));
    o.z=f2us(fmaf(a,v.z,d)); o.w=f2us(fmaf(a,v.w,d));
    *(ushort4*)(dst + h*256 + w4) = o;
  }
  for(int i=threadIdx.x; i<480; i+=256){           // zero pad w=240..255
    int h = i>>2, w4 = 240 + (i&3)*4;
    ushort4 z = {0,0,0,0};
    *(ushort4*)(dst + h*256 + w4) = z;
  }
}

// ---------------- x transpose: f32 [b][c][px] -> bf16 [b][px][c]  (k_tP pattern) ----------------
__global__ __launch_bounds__(256) void k_tX(const float* x, ushort* xT){
  __shared__ ushort lt[64][72];
  int b=blockIdx.z, c0=blockIdx.y*64, p0=blockIdx.x*64;
  int t=threadIdx.x;
  int cr=t>>4, p4=(t&15)*4;
  #pragma unroll
  for(int i=0;i<4;i++){
    int c = i*16 + cr;
    float4 v = *(const float4*)(x + ((size_t)(b*NC + c0 + c))*NHW + p0 + p4);
    ushort4 o; o.x=f2us(v.x); o.y=f2us(v.y); o.z=f2us(v.z); o.w=f2us(v.w);
    *(ushort4*)&lt[c][p4] = o;
  }
  __syncthreads();
  int pr=t>>2, q2=t&3;
  union { ushort s[8]; uint4 u; } o0, o1;
  #pragma unroll
  for(int e=0;e<8;e++){ o0.s[e]=lt[q2*16+e][pr]; o1.s[e]=lt[q2*16+8+e][pr]; }
  ushort* dp = xT + ((size_t)(b*NHW) + p0 + pr)*256 + c0 + q2*16;
  *(uint4*)dp = o0.u; *(uint4*)(dp+8) = o1.u;
}

// ---------------- spectral GEMM (B panel staged in LDS, chunk-swizzled) ----------------
template<int SPLIT, int EPI>
__global__ __launch_bounds__(256) void k_sgemm(const ushort* Ap0, const ushort* Ap1, const ushort* Bm,
                                               ushort* O0, ushort* O1, ushort* Ub){
  __shared__ ushort Bsl[16384];   // [64 rows][32 chunks][8], phys chunk = j ^ (row&7)
  int nb = blockIdx.x*64, mb = blockIdx.y*256;
  int tid = threadIdx.x, w = tid>>6, l = tid&63, lq = l>>4, lr = l&15;
  // stage B rows nb..nb+63 (all K) once
  #pragma unroll
  for(int i=0;i<8;i++){
    int L = i*256 + tid;
    int row = L>>5, j = L&31;
    gload16(Bm + (size_t)(nb+row)*256 + ((j ^ (row&7))<<3), &Bsl[(i*256 + w*64)*8]);
  }
  const ushort* ar0[4]; const ushort* ar1[4];
  #pragma unroll
  for(int mt=0;mt<4;mt++){
    size_t r = mb + w*64 + mt*16 + lr;
    ar0[mt] = Ap0 + r*(SPLIT?128:256) + lq*8;
    ar1[mt] = SPLIT ? (Ap1 + r*128 + lq*8) : ar0[mt];
  }
  __syncthreads();   // B staged (vmcnt drained pre-barrier)
  f32x4 acc[4][4] = {};
  #pragma unroll
  for(int kk=0;kk<8;kk++){
    int k = kk*32;
    short8 af[4], bfr[4];
    #pragma unroll
    for(int mt=0;mt<4;mt++){
      const ushort* p = SPLIT ? ((k<128 ? ar0[mt] : ar1[mt]) + (k&127)) : (ar0[mt] + k);
      af[mt] = *(const short8*)p;
    }
    #pragma unroll
    for(int nt=0;nt<4;nt++){
      int row = nt*16 + lr;
      bfr[nt] = *(const short8*)&Bsl[row*256 + (((kk*4+lq) ^ (row&7))<<3)];
    }
    #pragma unroll
    for(int mt=0;mt<4;mt++)
      #pragma unroll
      for(int nt=0;nt<4;nt++)
        acc[mt][nt] = __builtin_amdgcn_mfma_f32_16x16x32_bf16(af[mt], bfr[nt], acc[mt][nt], 0,0,0);
  }
  #pragma unroll
  for(int mt=0;mt<4;mt++){
    #pragma unroll
    for(int r=0;r<4;r++){
      int m = mb + w*64 + mt*16 + lq*4 + r;
      #pragma unroll
      for(int nt=0;nt<4;nt++){
        int n = nb + nt*16 + lr;
        float v = acc[mt][nt][r];
        if (EPI==0){
          if(n<128) O0[(size_t)m*128+n] = f2us(v);
          else      O1[(size_t)m*128+n-128] = f2us(v);
        } else {
          int g = m>>7, h = m&127;
          if(h<NH && n<NW) Ub[(size_t)g*NHW + (size_t)h*NW + n] = f2us(v);
        }
      }
    }
  }
}

// ---------------- 64x64 bf16 transpose within 128-stride planes (2 planes / launch) ----------------
__global__ __launch_bounds__(256) void k_t64(const ushort* s0, const ushort* s1, ushort* d0, ushort* d1,
                                             int srows, int sgstr){
  __shared__ ushort lt[64][72];
  int pl = blockIdx.z >> 9, g = blockIdx.z & 511;
  const ushort* src = pl ? s1 : s0;
  ushort* dst = pl ? d1 : d0;
  int i0=blockIdx.y*64, p0=blockIdx.x*64;
  int t=threadIdx.x, r=t>>2, q=t&3;
  int row = i0 + r;
  uint4 u0=make_uint4(0,0,0,0), u1=u0;
  if(row < srows){
    const ushort* sp = src + (size_t)g*sgstr + (size_t)row*128 + p0 + q*16;
    u0=*(const uint4*)sp; u1=*(const uint4*)(sp+8);
  }
  *(uint4*)&lt[r][q*16]=u0; *(uint4*)&lt[r][q*16+8]=u1;
  __syncthreads();
  int pr=t>>2, q2=t&3;
  union { ushort s[8]; uint4 u; } o0, o1;
  #pragma unroll
  for(int e=0;e<8;e++){ o0.s[e]=lt[q2*16+e][pr]; o1.s[e]=lt[q2*16+8+e][pr]; }
  ushort* dp = dst + (size_t)g*NSP + (size_t)(p0+pr)*128 + i0 + q2*16;
  *(uint4*)dp = o0.u; *(uint4*)(dp+8) = o1.u;
}

// ---------------- pixel transpose: [b][c:256][NSP] -> [b][NSP][c] (2 planes / launch) ----------------
__global__ __launch_bounds__(256) void k_tP(const ushort* s0, const ushort* s1, ushort* d0, ushort* d1){
  __shared__ ushort lt[64][72];
  int b = blockIdx.z & 1, pl = blockIdx.z >> 1;
  const ushort* src = pl ? s1 : s0;
  ushort* dst = pl ? d1 : d0;
  int i0=blockIdx.y*64, p0=blockIdx.x*64;
  int t=threadIdx.x, r=t>>2, q=t&3;
  const ushort* sp = src + (size_t)(b*NC+i0+r)*NSP + p0 + q*16;
  uint4 u0=*(const uint4*)sp, u1=*(const uint4*)(sp+8);
  *(uint4*)&lt[r][q*16]=u0; *(uint4*)&lt[r][q*16+8]=u1;
  __syncthreads();
  int pr=t>>2, q2=t&3;
  union { ushort s[8]; uint4 u; } o0, o1;
  #pragma unroll
  for(int e=0;e<8;e++){ o0.s[e]=lt[q2*16+e][pr]; o1.s[e]=lt[q2*16+8+e][pr]; }
  ushort* dp = dst + ((size_t)b*NSP + p0 + pr)*NC + i0 + q2*16;
  *(uint4*)dp = o0.u; *(uint4*)(dp+8) = o1.u;
}

// ---------------- complex spectral mix via MFMA (v8: G staged in LDS) ----------------
// G fragments were loaded redundantly by all 4 waves and streamed from HBM per K-step;
// now Gr/Gi [32px][256ch] (32KB) staged once per block via gload16 (chunk-swizzle
// j^(px&7) on source and read). K-loop: 8 L2-hot W loads + 4 ds_read_b128 per step.
__global__ __launch_bounds__(256) void k_mixg(float* ws){
  __shared__ ushort gl[2][8192];   // [plane][32 px][32 chunks][8]
  int b = blockIdx.z, p0 = blockIdx.x*32;
  int tid = threadIdx.x, w = tid>>6, l = tid&63, lq = l>>4, lr = l&15;
  const ushort* Gr = (const ushort*)(ws+RA0) + (size_t)b*NSP*NC;
  const ushort* Gi = (const ushort*)(ws+RA1) + (size_t)b*NSP*NC;
  #pragma unroll
  for(int i=0;i<4;i++){
    int L = i*256 + tid;
    int px = L>>5, j = L&31;
    size_t src = (size_t)(p0+px)*NC + ((j ^ (px&7))<<3);
    gload16(Gr + src, &gl[0][(i*256 + w*64)*8]);
    gload16(Gi + src, &gl[1][(i*256 + w*64)*8]);
  }
  const ushort* Wr = (const ushort*)(ws+OFF_WRT);
  const ushort* Wi = (const ushort*)(ws+OFF_WIT);
  const ushort *wrr[4], *wir[4];
  #pragma unroll
  for(int mt=0;mt<4;mt++){ size_t ro=(size_t)(w*64+mt*16+lr)*NC+lq*8; wrr[mt]=Wr+ro; wir[mt]=Wi+ro; }
  __syncthreads();   // G staged (vmcnt drained pre-barrier)
  f32x4 aR[4][2]={}, aI[4][2]={};
  #pragma unroll
  for(int kk=0;kk<8;kk++){
    int k = kk*32;
    short8 fr[4], fi[4], fin[4], gr[2], gi[2];
    #pragma unroll
    for(int mt=0;mt<4;mt++){
      fr[mt]=*(const short8*)(wrr[mt]+k);
      fi[mt]=*(const short8*)(wir[mt]+k);
      union { short8 s; uint u[4]; } nv; nv.s=fi[mt];
      nv.u[0]^=0x80008000u; nv.u[1]^=0x80008000u; nv.u[2]^=0x80008000u; nv.u[3]^=0x80008000u;
      fin[mt]=nv.s;
    }
    #pragma unroll
    for(int nt=0;nt<2;nt++){
      int px = nt*16 + lr;
      int off = px*256 + (((kk*4+lq) ^ (px&7))<<3);
      gr[nt] = *(const short8*)&gl[0][off];
      gi[nt] = *(const short8*)&gl[1][off];
    }
    #pragma unroll
    for(int mt=0;mt<4;mt++)
      #pragma unroll
      for(int nt=0;nt<2;nt++){
        aR[mt][nt]=__builtin_amdgcn_mfma_f32_16x16x32_bf16(fr[mt], gr[nt], aR[mt][nt],0,0,0);
        aR[mt][nt]=__builtin_amdgcn_mfma_f32_16x16x32_bf16(fin[mt],gi[nt], aR[mt][nt],0,0,0);
        aI[mt][nt]=__builtin_amdgcn_mfma_f32_16x16x32_bf16(fi[mt], gr[nt], aI[mt][nt],0,0,0);
        aI[mt][nt]=__builtin_amdgcn_mfma_f32_16x16x32_bf16(fr[mt], gi[nt], aI[mt][nt],0,0,0);
      }
  }
  ushort* Yre = (ushort*)(ws+RB0);
  ushort* Yim = (ushort*)(ws+RB1);
  #pragma unroll
  for(int mt=0;mt<4;mt++){
    #pragma unroll
    for(int r=0;r<4;r++){
      int m = w*64 + mt*16 + lq*4 + r;
      #pragma unroll
      for(int nt=0;nt<2;nt++){
        int n = p0 + nt*16 + lr;
        size_t ad = (size_t)(b*NC+m)*NSP + n;
        Yre[ad] = f2us(aR[mt][nt][r]);
        Yim[ad] = f2us(aI[mt][nt][r]);
      }
    }
  }
}

// ---------------- Phase A: fused inner conv + gelu + stats + U' (512 threads, 16 waves/CU) ----------------
__global__ __launch_bounds__(512,4) void k_inner(float* ws, const ushort* xT, const float* ib){
  __shared__ ushort xtl[16384];   // [64 px][32 chunks][8]
  __shared__ ushort us[16384];    // [256 ch][8 chunks][8]
  int b = blockIdx.z, blk = blockIdx.x, p0 = blk*64;
  int t = threadIdx.x, w = t>>6, l = t&63, lq = l>>4, lr = l&15;
  // async-stage x^T tile -> xtl
  #pragma unroll
  for(int i=0;i<4;i++){
    int L = i*512 + t;
    int px = L>>5, j = L&31;
    gload16(xT + ((size_t)(b*NHW) + p0 + px)*256 + ((j ^ (px&7))<<3), &xtl[(i*512 + w*64)*8]);
  }
  // async-stage Usp tile -> us
  const ushort* Usp = (const ushort*)(ws+OFF_RA);
  #pragma unroll
  for(int i=0;i<4;i++){
    int L = i*512 + t;
    int row = L>>3;
    int jd = (L&7) ^ (row&7);
    gload16(Usp + (size_t)(b*NC + row)*NHW + p0 + jd*8, &us[(i*512 + w*64)*8]);
  }
  __syncthreads();
  const ushort* W = (const ushort*)(ws+OFF_IWB);
  const ushort* ar[2];
  #pragma unroll
  for(int mt=0;mt<2;mt++) ar[mt] = W + (size_t)(w*32+mt*16+lr)*256 + lq*8;
  f32x4 acc[2][4] = {};
  #pragma unroll
  for(int kk=0;kk<8;kk++){
    short8 af[2], bfr[4];
    #pragma unroll
    for(int mt=0;mt<2;mt++) af[mt] = *(const short8*)(ar[mt]+kk*32);
    #pragma unroll
    for(int nt=0;nt<4;nt++){
      int px = nt*16 + lr;
      bfr[nt] = *(const short8*)&xtl[px*256 + (((kk*4+lq) ^ (px&7))<<3)];
    }
    #pragma unroll
    for(int mt=0;mt<2;mt++)
      #pragma unroll
      for(int nt=0;nt<4;nt++)
        acc[mt][nt] = __builtin_amdgcn_mfma_f32_16x16x32_bf16(af[mt], bfr[nt], acc[mt][nt], 0,0,0);
  }
  __syncthreads();   // xtl reads done; reuse as swizzled U' transpose buffer
  float* PS = ws + OFF_PS + ((size_t)(b*NPT+blk))*512;
  #pragma unroll
  for(int mt=0;mt<2;mt++){
    #pragma unroll
    for(int r=0;r<4;r++){
      int m = w*32 + mt*16 + lq*4 + r;
      float bb = ib[m];
      int m7 = m&7, mc = m>>3, mo = m&7;
      float ss = 0.f, sq = 0.f;
      #pragma unroll
      for(int nt=0;nt<4;nt++){
        int ncol = nt*16 + lr;
        float uv = us2f(us[m*64 + (((ncol>>3) ^ m7)<<3) + (ncol&7)]);
        float g = gelu_f(acc[mt][nt][r] + bb + uv);
        xtl[ncol*256 + ((mc ^ (ncol&7))<<3) + mo] = f2us(g);
        ss += g; sq = fmaf(g,g,sq);
      }
      #pragma unroll
      for(int ofs=1; ofs<16; ofs<<=1){ ss += __shfl_xor(ss, ofs, 64); sq += __shfl_xor(sq, ofs, 64); }
      if(lr==0){ PS[m] = ss; PS[256+m] = sq; }
    }
  }
  __syncthreads();
  ushort* Up = (ushort*)(ws+OFF_RB);
  #pragma unroll
  for(int pp=0; pp<2; pp++){
    int p = pp*32 + (t>>4);
    int s = p&7;
    int j0 = (t&15)*2;
    uint4 w0  = *(uint4*)&xtl[p*256 + ((j0 ^ s)<<3)];
    uint4 w1v = *(uint4*)&xtl[p*256 + (((j0+1) ^ s)<<3)];
    ushort* dp = Up + ((size_t)(b*NHW + p0 + p))*256 + j0*8;
    *(uint4*)dp = w0; *(uint4*)(dp+8) = w1v;
  }
}

// ---------------- stats1: reduce partials -> a1,d1 (FiLM folded) ----------------
__global__ __launch_bounds__(256) void k_stats1p(const float* gamma, const float* beta,
                                                 const float* n1w, const float* n1b, float* ws){
  int g = blockIdx.x, b = g>>8, c = g&255;
  float s=0.f, q=0.f;
  for(int i=threadIdx.x;i<NPT;i+=256){
    const float* P = ws + OFF_PS + ((size_t)(b*NPT+i))*512;
    s += P[c]; q += P[256+c];
  }
  __shared__ float ls[4], lq2[4];
  #pragma unroll
  for(int o=32;o>0;o>>=1){ s+=__shfl_down(s,o,64); q+=__shfl_down(q,o,64); }
  int lane=threadIdx.x&63, wid=threadIdx.x>>6;
  if(!lane){ ls[wid]=s; lq2[wid]=q; }
  __syncthreads();
  if(!threadIdx.x){
    s=ls[0]+ls[1]+ls[2]+ls[3]; q=lq2[0]+lq2[1]+lq2[2]+lq2[3];
    float m=s*(1.f/NHW), var=q*(1.f/NHW)-m*m;
    float r=rsqrtf(var+REPS);
    float gp1 = 1.f + gamma[c];
    float wv = n1w[c];
    ws[OFF_A1c+g] = gp1*wv*r;
    ws[OFF_D1c+g] = gp1*(n1b[c] - m*r*wv) + beta[c];
  }
}

// ---------------- fold a1/d1 into W1: W1'[b]=W1*diag(a1), b1'=W1*d1+b1 ----------------
__global__ __launch_bounds__(64) void k_fold(float* ws, const float* w1, const float* b1){
  int o = blockIdx.x, b = blockIdx.y, t = threadIdx.x;
  float acc = 0.f;
  ushort* W1p = (ushort*)(ws+OFF_W1P);
  #pragma unroll
  for(int ii=0; ii<4; ii++){
    int i = ii*64 + t;
    float wv = w1[o*256+i];
    W1p[((size_t)(b*NHID+o))*256 + i] = f2us(wv * ws[OFF_A1c + b*NC + i]);
    acc = fmaf(wv, ws[OFF_D1c + b*NC + i], acc);
  }
  #pragma unroll
  for(int ofs=32; ofs; ofs>>=1) acc += __shfl_down(acc, ofs, 64);
  if(!t) ws[OFF_B1P + b*NHID + o] = acc + b1[o];
}

// ---------------- Phase C: two staged 128x128-tile GEMMs (m97 structure) ----------------
template<int KD, int EPI>
__global__ __launch_bounds__(256) void k_gemm128(const ushort* __restrict__ A, const ushort* __restrict__ B,
                                                 const float* __restrict__ bias, const float* __restrict__ xres,
                                                 ushort* __restrict__ Obf, float* __restrict__ Ofl){
  __shared__ ushort As[2][4096] __attribute__((aligned(16)));
  __shared__ ushort Bs[2][4096] __attribute__((aligned(16)));
  int t = threadIdx.x, w = t>>6, l = t&63, lq = l>>4, lr = l&15;
  int wr = w>>1, wc = w&1;
  int nb = blockIdx.x*128, mb = blockIdx.y*128;
  const ushort* Ab = A + (size_t)mb*KD;
  const ushort* Bb = B + (size_t)nb*KD;
  int srow = t>>2;
  int scg  = (t&3) ^ ((t>>3)&3);
  size_t so0 = (size_t)srow*KD + scg*8;
  size_t so1 = (size_t)(srow+64)*KD + scg*8;
  int ld0 = w*512, ld1 = 2048 + w*512;
  int swk = (lq ^ ((lr>>1)&3))*8;
  f32x4 acc[4][4] = {};
  gload16(Ab+so0, &As[0][ld0]); gload16(Ab+so1, &As[0][ld1]);
  gload16(Bb+so0, &Bs[0][ld0]); gload16(Bb+so1, &Bs[0][ld1]);
  const int NK = KD/32;
  for(int kt=0; kt<NK; kt++){
    int cur = kt&1;
    __syncthreads();
    if(kt+1 < NK){
      size_t ko = (size_t)(kt+1)*32;
      gload16(Ab+so0+ko, &As[cur^1][ld0]); gload16(Ab+so1+ko, &As[cur^1][ld1]);
      gload16(Bb+so0+ko, &Bs[cur^1][ld0]); gload16(Bb+so1+ko, &Bs[cur^1][ld1]);
    }
    short8 af[4], bfr[4];
    #pragma unroll
    for(int mt=0;mt<4;mt++) af[mt]  = *(const short8*)&As[cur][(wr*64+mt*16+lr)*32 + swk];
    #pragma unroll
    for(int nt=0;nt<4;nt++) bfr[nt] = *(const short8*)&Bs[cur][(wc*64+nt*16+lr)*32 + swk];
    #pragma unroll
    for(int mt=0;mt<4;mt++)
      #pragma unroll
      for(int nt=0;nt<4;nt++)
        acc[mt][nt] = __builtin_amdgcn_mfma_f32_16x16x32_bf16(af[mt], bfr[nt], acc[mt][nt], 0,0,0);
  }
  if (EPI==0){
    #pragma unroll
    for(int nt=0;nt<4;nt++){
      int n = nb + wc*64 + nt*16 + lr;
      float bb = bias[n];
      #pragma unroll
      for(int mt=0;mt<4;mt++)
        #pragma unroll
        for(int r=0;r<4;r++){
          int m = mb + wr*64 + mt*16 + lq*4 + r;
          Obf[(size_t)m*NHID + n] = f2us(gelu_f(acc[mt][nt][r] + bb));
        }
    }
  } else {
    #pragma unroll
    for(int mt=0;mt<4;mt++)
      #pragma unroll
      for(int r=0;r<4;r++){
        int m = mb + wr*64 + mt*16 + lq*4 + r;
        float bb = bias[m];
        #pragma unroll
        for(int nt=0;nt<4;nt++){
          int n = nb + wc*64 + nt*16 + lr;
          size_t ad = (size_t)m*NHW + n;
          Ofl[ad] = acc[mt][nt][r] + bb + xres[ad];
        }
      }
  }
}

extern "C" void kernel_launch(void* const* d_in, const int* in_sizes, int n_in,
                              void* d_out, int out_size, void* d_ws, size_t ws_size,
                              hipStream_t stream) {
  const float* x     = (const float*)d_in[0];
  const float* gamma = (const float*)d_in[1];
  const float* beta  = (const float*)d_in[2];
  const float* n0w   = (const float*)d_in[3];
  const float* n0b   = (const float*)d_in[4];
  const float* n1w   = (const float*)d_in[5];
  const float* n1b   = (const float*)d_in[6];
  const float* wsr   = (const float*)d_in[7];
  const float* wsi   = (const float*)d_in[8];
  const float* iw    = (const float*)d_in[9];
  const float* ib    = (const float*)d_in[10];
  const float* w1    = (const float*)d_in[11];
  const float* b1    = (const float*)d_in[12];
  const float* w2    = (const float*)d_in[13];
  const float* b2    = (const float*)d_in[14];
  float* ws = (float*)d_ws;
  float* out = (float*)d_out;
  if (ws_size < WS_FLOATS*4ULL) return;

  k_setup <<<dim3(2304), dim3(256), 0, stream>>>(ws, wsr, wsi, iw, w2);
  // x^T (bf16 pixel-major) into d_out scratch -- consumed by k_inner, dead before mlp2 writes out.
  ushort* xT = (ushort*)out;
  k_tX   <<<dim3(450,4,2), dim3(256), 0, stream>>>(x, xT);
  k_stats0<<<dim3(512),  dim3(256), 0, stream>>>(x, n0w, n0b, ws);
  k_norm  <<<dim3(512), dim3(256), 0, stream>>>(x, ws);
  // GEMM1: A1(RA) -> F(RB planes)
  k_sgemm<0,0><<<dim3(4,240), dim3(256), 0, stream>>>((const ushort*)(ws+RA0), (const ushort*)(ws+RA0),
      (const ushort*)(ws+OFF_TWF), (ushort*)(ws+OFF_FRE), (ushort*)(ws+OFF_FIM), nullptr);
  // T1: F(RB) -> Ft(RA), both planes in one launch
  k_t64 <<<dim3(2,2,1024), dim3(256), 0, stream>>>((const ushort*)(ws+OFF_FRE), (const ushort*)(ws+OFF_FIM),
      (ushort*)(ws+RA0), (ushort*)(ws+RA1), NH, NH*128);
  // GEMM2: Ft(RA) -> G(RB)
  k_sgemm<1,0><<<dim3(4,256), dim3(256), 0, stream>>>((const ushort*)(ws+RA0), (const ushort*)(ws+RA1),
      (const ushort*)(ws+OFF_THF), (ushort*)(ws+RB0), (ushort*)(ws+RB1), nullptr);
  // T2: G(RB) -> Gt(RA) [b][p][c], both planes in one launch
  k_tP <<<dim3(256,4,4), dim3(256), 0, stream>>>((const ushort*)(ws+RB0), (const ushort*)(ws+RB1),
      (ushort*)(ws+RA0), (ushort*)(ws+RA1));
  // mix: Gt(RA) -> Y(RB)
  k_mixg <<<dim3(512,1,2), dim3(256), 0, stream>>>(ws);
  // GEMM4: Y(RB) -> Z(RA)
  k_sgemm<1,0><<<dim3(4,256), dim3(256), 0, stream>>>((const ushort*)(ws+RB0), (const ushort*)(ws+RB1),
      (const ushort*)(ws+OFF_THI), (ushort*)(ws+RA0), (ushort*)(ws+RA1), nullptr);
  // T3: Z(RA) -> Zt(RB), both planes in one launch
  k_t64 <<<dim3(2,2,1024), dim3(256), 0, stream>>>((const ushort*)(ws+RA0), (const ushort*)(ws+RA1),
      (ushort*)(ws+RB0), (ushort*)(ws+RB1), 128, NSP);
  // GEMM5: Zt(RB) -> U spectral bf16 channel-major (RA)
  k_sgemm<1,1><<<dim3(4,256), dim3(256), 0, stream>>>((const ushort*)(ws+RB0), (const ushort*)(ws+RB1),
      (const ushort*)(ws+OFF_TWI), nullptr, nullptr, (ushort*)(ws+RA0));
  // Phase A: inner conv fused (xT + Usp -> U' pixel-major bf16 in RB, + stats partials)
  k_inner <<<dim3(NPT,1,2), dim3(512), 0, stream>>>(ws, xT, ib);
  k_stats1p<<<dim3(512), dim3(256), 0, stream>>>(gamma, beta, n1w, n1b, ws);
  k_fold  <<<dim3(512,2), dim3(64), 0, stream>>>(ws, w1, b1);
  // Phase C: per-batch  mlp1 (U'*W1p^T -> gelu -> mid)  then  mlp2 (W2*mid^T + b2 + x -> out).
  ushort* mid = (ushort*)(ws+OFF_RA);
  for(int b=0;b<2;b++){
    k_gemm128<256,0><<<dim3(4,225), dim3(256), 0, stream>>>(
        (const ushort*)(ws+OFF_RB) + (size_t)b*NHW*256,
        (const ushort*)(ws+OFF_W1P) + (size_t)b*NHID*256,
        ws+OFF_B1P + b*NHID, nullptr, mid, nullptr);
    k_gemm128<512,1><<<dim3(225,2), dim3(256), 0, stream>>>(
        (const ushort*)(ws+OFF_W2B),
        mid,
        b2, x + (size_t)b*NC*NHW, nullptr, out + (size_t)b*NC*NHW);
  }
}